// Round 2
// baseline (1403.060 us; speedup 1.0000x reference)
//
#include <hip/hip_runtime.h>

typedef unsigned short u16;
typedef unsigned int u32;
using short8 = __attribute__((ext_vector_type(8))) short;
using f32x4  = __attribute__((ext_vector_type(4))) float;

constexpr int Bb = 64, Ss = 1000, Dd = 128, Hh = 512;
constexpr int NN = Bb * Ss;           // 64000 nodes
constexpr int NSRC = Ss - 2;          // 998 kNN source nodes per batch

// ---------- helpers ----------
__device__ __forceinline__ float bf2f(u16 h) {
    u32 u = ((u32)h) << 16;
    return __builtin_bit_cast(float, u);
}
__device__ __forceinline__ u16 f2bf(float v) {  // RNE, finite inputs only
    u32 u = __builtin_bit_cast(u32, v);
    u32 r = (u + 0x7FFFu + ((u >> 16) & 1u)) >> 16;
    return (u16)r;
}
__device__ __forceinline__ void split2(float v, u16& h, u16& l) {
    h = f2bf(v);
    float fh = bf2f(h);
    l = f2bf(v - fh);
}

// ---------- 1) kNN build: top-7 per non-depot node, exact fp32 op mirror ----------
__global__ __launch_bounds__(256) void knn_kernel(const float* __restrict__ inputs,
                                                  u16* __restrict__ knn,
                                                  int* __restrict__ indeg) {
    __shared__ float2 pts[Ss];
    int b = blockIdx.x;
    const float* base = inputs + (size_t)b * Ss * 2;
    for (int t = threadIdx.x; t < Ss; t += 256) {
        float2 p;
        p.x = base[2 * t];
        p.y = base[2 * t + 1];
        pts[t] = p;
    }
    __syncthreads();
    if (threadIdx.x >= 250) return;
    int i = 2 + blockIdx.y * 250 + threadIdx.x;
    if (i >= Ss) return;

    float xi = pts[i].x, yi = pts[i].y;
    float bd[7];
    int   bi[7];
#pragma unroll
    for (int k = 0; k < 7; ++k) { bd[k] = __builtin_inff(); bi[k] = -1; }

    for (int j = 0; j < Ss; ++j) {
        if (j == i) continue;
        float dx = __fsub_rn(xi, pts[j].x);  // fp32 RN (mirror numpy, no FMA)
        float dy = __fsub_rn(yi, pts[j].y);
        float d = __fsqrt_rn(__fadd_rn(__fmul_rn(dx, dx), __fmul_rn(dy, dy)));
        if (d < bd[6]) {                     // strict <: stable, lower index wins ties
            int pos = 0;
#pragma unroll
            for (int k = 0; k < 7; ++k) pos += (bd[k] <= d) ? 1 : 0;
#pragma unroll
            for (int k = 6; k > 0; --k) {
                bool sh = (k > pos);
                bd[k] = sh ? bd[k - 1] : bd[k];
                bi[k] = sh ? bi[k - 1] : bi[k];
            }
#pragma unroll
            for (int k = 0; k < 7; ++k)
                if (k == pos) { bd[k] = d; bi[k] = j; }
        }
    }
    u16* kp = knn + ((size_t)b * NSRC + (i - 2)) * 7;
#pragma unroll
    for (int k = 0; k < 7; ++k) {
        kp[k] = (u16)bi[k];
        if (bi[k] >= 2) atomicAdd(&indeg[b * Ss + bi[k]], 1);
    }
}

// ---------- 2) degree -> dinv ----------
__global__ void deg_dinv_kernel(const int* __restrict__ indeg, float* __restrict__ dinv) {
    int n = blockIdx.x * 256 + threadIdx.x;
    if (n >= NN) return;
    int i = n % Ss;
    float deg = (i == 0) ? 1.0f : (i == 1) ? (float)(Ss - 1) : (float)(indeg[n] + 2);
    dinv[n] = 1.0f / __fsqrt_rn(deg);
}

// ---------- 3) exclusive scan of indeg -> CSR offsets (single block) ----------
__global__ __launch_bounds__(1024) void scan_kernel(const int* __restrict__ indeg,
                                                    int* __restrict__ offs) {
    __shared__ int part[1024];
    int t = threadIdx.x;
    const int CH = 63;                       // 1024*63 >= 64000
    int lo = t * CH;
    int hi = lo + CH; if (hi > NN) hi = NN;
    int s = 0;
    for (int k = lo; k < hi; ++k) s += indeg[k];
    part[t] = s;
    __syncthreads();
    for (int off = 1; off < 1024; off <<= 1) {
        int v = (t >= off) ? part[t - off] : 0;
        __syncthreads();
        part[t] += v;
        __syncthreads();
    }
    int run = part[t] - s;                   // exclusive prefix
    for (int k = lo; k < hi; ++k) { offs[k] = run; run += indeg[k]; }
    if (t == 1023) offs[NN] = part[1023];
}

// ---------- 4) scatter reverse adjacency (src local index per dst) ----------
__global__ __launch_bounds__(256) void fill_rev_kernel(const u16* __restrict__ knn,
                                                       const int* __restrict__ offs,
                                                       int* __restrict__ cursor,
                                                       u16* __restrict__ rev) {
    if (threadIdx.x >= 250) return;
    int b = blockIdx.x;
    int i = 2 + blockIdx.y * 250 + threadIdx.x;
    if (i >= Ss) return;
    const u16* kp = knn + ((size_t)b * NSRC + (i - 2)) * 7;
#pragma unroll
    for (int k = 0; k < 7; ++k) {
        int d = kp[k];
        if (d >= 2) {
            int n = b * Ss + d;
            int p = atomicAdd(&cursor[n], 1);
            rev[offs[n] + p] = (u16)i;       // store local src index
        }
    }
}

// ---------- 5) embedding: x = inputs@Wc+bc + scor@Ws+bs, split hi/lo bf16 ----------
__global__ __launch_bounds__(256) void embed_kernel(const float* __restrict__ inputs,
                                                    const float* __restrict__ scor,
                                                    const float* __restrict__ Wc,
                                                    const float* __restrict__ bc,
                                                    const float* __restrict__ Ws,
                                                    const float* __restrict__ bs,
                                                    u16* __restrict__ xhi,
                                                    u16* __restrict__ xlo) {
    int gid = blockIdx.x * 256 + threadIdx.x;
    if (gid >= NN * Dd) return;
    int n = gid >> 7, c = gid & 127;
    float i0 = inputs[2 * n], i1 = inputs[2 * n + 1], sc = scor[n];
    float t1 = i0 * Wc[c] + i1 * Wc[Dd + c] + bc[c];
    float t2 = sc * Ws[c] + bs[c];
    float v = t1 + t2;
    u16 h, l;
    split2(v, h, l);
    xhi[gid] = h;
    xlo[gid] = l;
}

// ---------- 6) weight transpose + split: Wt{hi,lo}[n][k] = split(W[k][n]) ----------
__global__ void transp_split_kernel(const float* __restrict__ src,
                                    u16* __restrict__ dhi, u16* __restrict__ dlo,
                                    int R, int C) {
    int gid = blockIdx.x * 256 + threadIdx.x;
    if (gid >= R * C) return;
    int r = gid / C, c = gid - r * C;
    u16 h, l;
    split2(src[gid], h, l);
    dhi[c * R + r] = h;
    dlo[c * R + r] = l;
}

// ---------- 7) split-bf16 MFMA GEMM: C = A @ W, 3-MFMA scheme ----------
// A = ahi+alo [M][K], W^T = whi+wlo [Ncols][K]. 128x128 tile, BK=64, 4 waves 64x64.
__global__ __launch_bounds__(256) void gemm_kernel(const u16* __restrict__ Ahi,
                                                   const u16* __restrict__ Alo,
                                                   const u16* __restrict__ Whi,
                                                   const u16* __restrict__ Wlo,
                                                   float* __restrict__ C,
                                                   int K, int Ncols) {
    __shared__ __align__(16) u16 lAhi[128][64];
    __shared__ __align__(16) u16 lAlo[128][64];
    __shared__ __align__(16) u16 lWh[128][64];
    __shared__ __align__(16) u16 lWl[128][64];

    int row0 = blockIdx.x * 128;
    int col0 = blockIdx.y * 128;
    int tid = threadIdx.x;
    int lane = tid & 63, wid = tid >> 6;
    int wm = (wid >> 1) * 64, wn = (wid & 1) * 64;
    int lanelo = lane & 15, quad = lane >> 4;

    f32x4 acc[4][4] = {};

    int scb = tid & 7;          // col-block (8 bf16 each) 0..7
    int sr  = tid >> 3;         // 0..31

    for (int k0 = 0; k0 < K; k0 += 64) {
#pragma unroll
        for (int rr = 0; rr < 4; ++rr) {
            int r = sr + rr * 32;
            size_t gofs = (size_t)(row0 + r) * K + k0 + scb * 8;
            uint4 vh = *(const uint4*)(Ahi + gofs);
            uint4 vl = *(const uint4*)(Alo + gofs);
            int cc = (scb ^ (r & 7)) * 8;   // XOR swizzle
            *(uint4*)&lAhi[r][cc] = vh;
            *(uint4*)&lAlo[r][cc] = vl;
        }
#pragma unroll
        for (int rr = 0; rr < 4; ++rr) {
            int r = sr + rr * 32;
            size_t gofs = (size_t)(col0 + r) * K + k0 + scb * 8;
            uint4 vh = *(const uint4*)(Whi + gofs);
            uint4 vl = *(const uint4*)(Wlo + gofs);
            int cc = (scb ^ (r & 7)) * 8;
            *(uint4*)&lWh[r][cc] = vh;
            *(uint4*)&lWl[r][cc] = vl;
        }
        __syncthreads();

#pragma unroll
        for (int kk = 0; kk < 64; kk += 32) {
            short8 ah[4], al[4], bh[4], bl[4];
            int cbb = (kk >> 3) + quad;
#pragma unroll
            for (int mt = 0; mt < 4; ++mt) {
                int r = wm + mt * 16 + lanelo;
                int cc = (cbb ^ (r & 7)) * 8;
                ah[mt] = *(const short8*)&lAhi[r][cc];
                al[mt] = *(const short8*)&lAlo[r][cc];
            }
#pragma unroll
            for (int nt = 0; nt < 4; ++nt) {
                int r = wn + nt * 16 + lanelo;
                int cc = (cbb ^ (r & 7)) * 8;
                bh[nt] = *(const short8*)&lWh[r][cc];
                bl[nt] = *(const short8*)&lWl[r][cc];
            }
#pragma unroll
            for (int mt = 0; mt < 4; ++mt)
#pragma unroll
                for (int nt = 0; nt < 4; ++nt) {
                    acc[mt][nt] = __builtin_amdgcn_mfma_f32_16x16x32_bf16(
                        ah[mt], bh[nt], acc[mt][nt], 0, 0, 0);
                    acc[mt][nt] = __builtin_amdgcn_mfma_f32_16x16x32_bf16(
                        al[mt], bh[nt], acc[mt][nt], 0, 0, 0);
                    acc[mt][nt] = __builtin_amdgcn_mfma_f32_16x16x32_bf16(
                        ah[mt], bl[nt], acc[mt][nt], 0, 0, 0);
                }
        }
        __syncthreads();
    }

#pragma unroll
    for (int mt = 0; mt < 4; ++mt)
#pragma unroll
        for (int nt = 0; nt < 4; ++nt)
#pragma unroll
            for (int r = 0; r < 4; ++r) {
                int row = row0 + wm + mt * 16 + quad * 4 + r;
                int col = col0 + wn + nt * 16 + lanelo;
                C[(size_t)row * Ncols + col] = acc[mt][nt][r];
            }
}

// ---------- 8) aggregation M=512 + bias + relu -> split bf16 ----------
__global__ __launch_bounds__(128) void agg512_kernel(const float* __restrict__ y,
                                                     const float* __restrict__ dinv,
                                                     const int* __restrict__ offs,
                                                     const int* __restrict__ indeg,
                                                     const u16* __restrict__ rev,
                                                     const float* __restrict__ bias,
                                                     u16* __restrict__ oHi,
                                                     u16* __restrict__ oLo) {
    int n = blockIdx.x;
    int i = n % Ss;
    int nb = n - i;
    int c = threadIdx.x * 4;
    float a0 = 0.f, a1 = 0.f, a2 = 0.f, a3 = 0.f;

    if (i >= 2) {
        float w = dinv[nb];  // depot 0 weight == 1.0
        float4 v = *(const float4*)(y + (size_t)nb * 512 + c);
        a0 = v.x * w; a1 = v.y * w; a2 = v.z * w; a3 = v.w * w;
        int cnt = indeg[n];
        int o = offs[n];
        for (int e = 0; e < cnt; ++e) {
            int s = rev[o + e];
            float ws_ = dinv[nb + s];
            float4 u = *(const float4*)(y + (size_t)(nb + s) * 512 + c);
            a0 += u.x * ws_; a1 += u.y * ws_; a2 += u.z * ws_; a3 += u.w * ws_;
        }
    } else if (i == 1) {
        for (int j = 2; j < Ss; ++j) {
            float ws_ = dinv[nb + j];
            float4 u = *(const float4*)(y + (size_t)(nb + j) * 512 + c);
            a0 += u.x * ws_; a1 += u.y * ws_; a2 += u.z * ws_; a3 += u.w * ws_;
        }
    }
    float dn = dinv[n], sn = dn * dn;
    float4 vs = *(const float4*)(y + (size_t)n * 512 + c);
    float z0 = a0 * dn + vs.x * sn + bias[c];
    float z1 = a1 * dn + vs.y * sn + bias[c + 1];
    float z2 = a2 * dn + vs.z * sn + bias[c + 2];
    float z3 = a3 * dn + vs.w * sn + bias[c + 3];
    z0 = fmaxf(z0, 0.f); z1 = fmaxf(z1, 0.f); z2 = fmaxf(z2, 0.f); z3 = fmaxf(z3, 0.f);
    u16 h0, l0, h1, l1, h2, l2, h3, l3;
    split2(z0, h0, l0); split2(z1, h1, l1); split2(z2, h2, l2); split2(z3, h3, l3);
    ushort4 hv; hv.x = h0; hv.y = h1; hv.z = h2; hv.w = h3;
    ushort4 lv; lv.x = l0; lv.y = l1; lv.z = l2; lv.w = l3;
    *(ushort4*)(oHi + (size_t)n * 512 + c) = hv;
    *(ushort4*)(oLo + (size_t)n * 512 + c) = lv;
}

// ---------- 9) final aggregation M=128, no relu, fp32 out ----------
__global__ __launch_bounds__(128) void agg128f_kernel(const float* __restrict__ y,
                                                      const float* __restrict__ dinv,
                                                      const int* __restrict__ offs,
                                                      const int* __restrict__ indeg,
                                                      const u16* __restrict__ rev,
                                                      const float* __restrict__ bias,
                                                      float* __restrict__ out) {
    int n = blockIdx.x;
    int i = n % Ss;
    int nb = n - i;
    int c = threadIdx.x;
    float a = 0.f;
    if (i >= 2) {
        a = y[(size_t)nb * 128 + c] * dinv[nb];
        int cnt = indeg[n];
        int o = offs[n];
        for (int e = 0; e < cnt; ++e) {
            int s = rev[o + e];
            a += y[(size_t)(nb + s) * 128 + c] * dinv[nb + s];
        }
    } else if (i == 1) {
        for (int j = 2; j < Ss; ++j)
            a += y[(size_t)(nb + j) * 128 + c] * dinv[nb + j];
    }
    float dn = dinv[n];
    out[(size_t)n * 128 + c] = a * dn + y[(size_t)n * 128 + c] * (dn * dn) + bias[c];
}

// ---------- workspace layout (bytes); total 266,528,768 < proven-safe 267.5 MB ----------
constexpr size_t O_INDEG  = 0;                       // 64000*4 = 256000
constexpr size_t O_CURSOR = 256000;                  // 256000 (adjacent: one memset)
constexpr size_t O_OFFS   = 512000;                  // 64004*4 = 256016
constexpr size_t O_DINV   = 768256;                  // 256000
constexpr size_t O_KNN    = 1024256;                 // u16: 64*998*7*2 = 893824
constexpr size_t O_REV    = 1918080;                 // u16: 893824
constexpr size_t O_WT0H   = 2811904;                 // 512*128*2 = 131072
constexpr size_t O_WT0L   = 2942976;
constexpr size_t O_WT1H   = 3074048;                 // 512*512*2 = 524288
constexpr size_t O_WT1L   = 3598336;
constexpr size_t O_WT2H   = 4122624;                 // 128*512*2 = 131072
constexpr size_t O_WT2L   = 4253696;
constexpr size_t O_AHI    = 4384768;                 // 64000*512*2 = 65536000
constexpr size_t O_ALO    = 69920768;                // 65536000
constexpr size_t O_Y      = 135456768;               // 64000*512*4 = 131072000

extern "C" void kernel_launch(void* const* d_in, const int* in_sizes, int n_in,
                              void* d_out, int out_size, void* d_ws, size_t ws_size,
                              hipStream_t stream) {
    const float* inputs = (const float*)d_in[0];
    const float* scor   = (const float*)d_in[1];
    const float* Wc     = (const float*)d_in[2];
    const float* bc     = (const float*)d_in[3];
    const float* Ws     = (const float*)d_in[4];
    const float* bs     = (const float*)d_in[5];
    const float* W0     = (const float*)d_in[6];
    const float* b0     = (const float*)d_in[7];
    const float* W1     = (const float*)d_in[8];
    const float* b1     = (const float*)d_in[9];
    const float* W2     = (const float*)d_in[10];
    const float* b2     = (const float*)d_in[11];

    char* w = (char*)d_ws;
    int*   indeg  = (int*)(w + O_INDEG);
    int*   cursor = (int*)(w + O_CURSOR);
    int*   offs   = (int*)(w + O_OFFS);
    float* dinv   = (float*)(w + O_DINV);
    u16*   knn    = (u16*)(w + O_KNN);
    u16*   rev    = (u16*)(w + O_REV);
    u16*   wt0h   = (u16*)(w + O_WT0H);
    u16*   wt0l   = (u16*)(w + O_WT0L);
    u16*   wt1h   = (u16*)(w + O_WT1H);
    u16*   wt1l   = (u16*)(w + O_WT1L);
    u16*   wt2h   = (u16*)(w + O_WT2H);
    u16*   wt2l   = (u16*)(w + O_WT2L);
    u16*   ahi    = (u16*)(w + O_AHI);
    u16*   alo    = (u16*)(w + O_ALO);
    float* y      = (float*)(w + O_Y);

    hipMemsetAsync(w + O_INDEG, 0, 512000, stream);  // indeg + cursor

    knn_kernel<<<dim3(Bb, 4), 256, 0, stream>>>(inputs, knn, indeg);
    deg_dinv_kernel<<<250, 256, 0, stream>>>(indeg, dinv);
    scan_kernel<<<1, 1024, 0, stream>>>(indeg, offs);
    fill_rev_kernel<<<dim3(Bb, 4), 256, 0, stream>>>(knn, offs, cursor, rev);

    embed_kernel<<<NN * Dd / 256, 256, 0, stream>>>(inputs, scor, Wc, bc, Ws, bs, ahi, alo);

    transp_split_kernel<<<(Dd * Hh + 255) / 256, 256, 0, stream>>>(W0, wt0h, wt0l, Dd, Hh);
    transp_split_kernel<<<(Hh * Hh + 255) / 256, 256, 0, stream>>>(W1, wt1h, wt1l, Hh, Hh);
    transp_split_kernel<<<(Hh * Dd + 255) / 256, 256, 0, stream>>>(W2, wt2h, wt2l, Hh, Dd);

    // layer 0: [N,128] @ [128,512]
    gemm_kernel<<<dim3(NN / 128, Hh / 128), 256, 0, stream>>>(ahi, alo, wt0h, wt0l, y, Dd, Hh);
    agg512_kernel<<<NN, 128, 0, stream>>>(y, dinv, offs, indeg, rev, b0, ahi, alo);
    // layer 1: [N,512] @ [512,512]
    gemm_kernel<<<dim3(NN / 128, Hh / 128), 256, 0, stream>>>(ahi, alo, wt1h, wt1l, y, Hh, Hh);
    agg512_kernel<<<NN, 128, 0, stream>>>(y, dinv, offs, indeg, rev, b1, ahi, alo);
    // layer 2: [N,512] @ [512,128]
    gemm_kernel<<<dim3(NN / 128, Dd / 128), 256, 0, stream>>>(ahi, alo, wt2h, wt2l, y, Hh, Dd);
    agg128f_kernel<<<NN, 128, 0, stream>>>(y, dinv, offs, indeg, rev, b2, (float*)d_out);
}

// Round 3
// 829.714 us; speedup vs baseline: 1.6910x; 1.6910x over previous
//
#include <hip/hip_runtime.h>

typedef unsigned short u16;
typedef unsigned int u32;
using short8 = __attribute__((ext_vector_type(8))) short;
using f32x4  = __attribute__((ext_vector_type(4))) float;

constexpr int Bb = 64, Ss = 1000, Dd = 128, Hh = 512;
constexpr int NN = Bb * Ss;           // 64000 nodes
constexpr int NSRC = Ss - 2;          // 998 kNN source nodes per batch

// ---------- helpers ----------
__device__ __forceinline__ float bf2f(u16 h) {
    u32 u = ((u32)h) << 16;
    return __builtin_bit_cast(float, u);
}
__device__ __forceinline__ u16 f2bf(float v) {  // RNE, finite inputs only
    u32 u = __builtin_bit_cast(u32, v);
    u32 r = (u + 0x7FFFu + ((u >> 16) & 1u)) >> 16;
    return (u16)r;
}
__device__ __forceinline__ void split2(float v, u16& h, u16& l) {
    h = f2bf(v);
    float fh = bf2f(h);
    l = f2bf(v - fh);
}

// ---------- 1) kNN build: top-7 per non-depot node, exact fp32 op mirror ----------
__global__ __launch_bounds__(256) void knn_kernel(const float* __restrict__ inputs,
                                                  u16* __restrict__ knn,
                                                  int* __restrict__ indeg) {
    __shared__ float2 pts[Ss];
    int b = blockIdx.x;
    const float* base = inputs + (size_t)b * Ss * 2;
    for (int t = threadIdx.x; t < Ss; t += 256) {
        float2 p;
        p.x = base[2 * t];
        p.y = base[2 * t + 1];
        pts[t] = p;
    }
    __syncthreads();
    if (threadIdx.x >= 250) return;
    int i = 2 + blockIdx.y * 250 + threadIdx.x;
    if (i >= Ss) return;

    float xi = pts[i].x, yi = pts[i].y;
    float bd[7];
    int   bi[7];
#pragma unroll
    for (int k = 0; k < 7; ++k) { bd[k] = __builtin_inff(); bi[k] = -1; }

    for (int j = 0; j < Ss; ++j) {
        if (j == i) continue;
        float dx = __fsub_rn(xi, pts[j].x);  // fp32 RN (mirror numpy, no FMA)
        float dy = __fsub_rn(yi, pts[j].y);
        float d = __fsqrt_rn(__fadd_rn(__fmul_rn(dx, dx), __fmul_rn(dy, dy)));
        if (d < bd[6]) {                     // strict <: stable, lower index wins ties
            int pos = 0;
#pragma unroll
            for (int k = 0; k < 7; ++k) pos += (bd[k] <= d) ? 1 : 0;
#pragma unroll
            for (int k = 6; k > 0; --k) {
                bool sh = (k > pos);
                bd[k] = sh ? bd[k - 1] : bd[k];
                bi[k] = sh ? bi[k - 1] : bi[k];
            }
#pragma unroll
            for (int k = 0; k < 7; ++k)
                if (k == pos) { bd[k] = d; bi[k] = j; }
        }
    }
    u16* kp = knn + ((size_t)b * NSRC + (i - 2)) * 7;
#pragma unroll
    for (int k = 0; k < 7; ++k) {
        kp[k] = (u16)bi[k];
        if (bi[k] >= 2) atomicAdd(&indeg[b * Ss + bi[k]], 1);
    }
}

// ---------- 2) degree -> dinv ----------
__global__ void deg_dinv_kernel(const int* __restrict__ indeg, float* __restrict__ dinv) {
    int n = blockIdx.x * 256 + threadIdx.x;
    if (n >= NN) return;
    int i = n % Ss;
    float deg = (i == 0) ? 1.0f : (i == 1) ? (float)(Ss - 1) : (float)(indeg[n] + 2);
    dinv[n] = 1.0f / __fsqrt_rn(deg);
}

// ---------- 3) exclusive scan of indeg -> CSR offsets (single block) ----------
__global__ __launch_bounds__(1024) void scan_kernel(const int* __restrict__ indeg,
                                                    int* __restrict__ offs) {
    __shared__ int part[1024];
    int t = threadIdx.x;
    const int CH = 63;                       // 1024*63 >= 64000
    int lo = t * CH;
    int hi = lo + CH; if (hi > NN) hi = NN;
    int s = 0;
    for (int k = lo; k < hi; ++k) s += indeg[k];
    part[t] = s;
    __syncthreads();
    for (int off = 1; off < 1024; off <<= 1) {
        int v = (t >= off) ? part[t - off] : 0;
        __syncthreads();
        part[t] += v;
        __syncthreads();
    }
    int run = part[t] - s;                   // exclusive prefix
    for (int k = lo; k < hi; ++k) { offs[k] = run; run += indeg[k]; }
    if (t == 1023) offs[NN] = part[1023];
}

// ---------- 4) scatter reverse adjacency (src local index per dst) ----------
__global__ __launch_bounds__(256) void fill_rev_kernel(const u16* __restrict__ knn,
                                                       const int* __restrict__ offs,
                                                       int* __restrict__ cursor,
                                                       u16* __restrict__ rev) {
    if (threadIdx.x >= 250) return;
    int b = blockIdx.x;
    int i = 2 + blockIdx.y * 250 + threadIdx.x;
    if (i >= Ss) return;
    const u16* kp = knn + ((size_t)b * NSRC + (i - 2)) * 7;
#pragma unroll
    for (int k = 0; k < 7; ++k) {
        int d = kp[k];
        if (d >= 2) {
            int n = b * Ss + d;
            int p = atomicAdd(&cursor[n], 1);
            rev[offs[n] + p] = (u16)i;       // store local src index
        }
    }
}

// ---------- 5) embedding: x = inputs@Wc+bc + scor@Ws+bs, split hi/lo bf16 ----------
__global__ __launch_bounds__(256) void embed_kernel(const float* __restrict__ inputs,
                                                    const float* __restrict__ scor,
                                                    const float* __restrict__ Wc,
                                                    const float* __restrict__ bc,
                                                    const float* __restrict__ Ws,
                                                    const float* __restrict__ bs,
                                                    u16* __restrict__ xhi,
                                                    u16* __restrict__ xlo) {
    int gid = blockIdx.x * 256 + threadIdx.x;
    if (gid >= NN * Dd) return;
    int n = gid >> 7, c = gid & 127;
    float i0 = inputs[2 * n], i1 = inputs[2 * n + 1], sc = scor[n];
    float t1 = i0 * Wc[c] + i1 * Wc[Dd + c] + bc[c];
    float t2 = sc * Ws[c] + bs[c];
    float v = t1 + t2;
    u16 h, l;
    split2(v, h, l);
    xhi[gid] = h;
    xlo[gid] = l;
}

// ---------- 6) weight transpose + split ----------
__global__ void transp_split_kernel(const float* __restrict__ src,
                                    u16* __restrict__ dhi, u16* __restrict__ dlo,
                                    int R, int C) {
    int gid = blockIdx.x * 256 + threadIdx.x;
    if (gid >= R * C) return;
    int r = gid / C, c = gid - r * C;
    u16 h, l;
    split2(src[gid], h, l);
    dhi[c * R + r] = h;
    dlo[c * R + r] = l;
}

// ---------- 7) split-bf16 MFMA GEMM: C = A @ W, 3-MFMA scheme ----------
// grid: (Ncols/128, M/128) — col fastest so A-tile reuse is temporally adjacent.
__global__ __launch_bounds__(256) void gemm_kernel(const u16* __restrict__ Ahi,
                                                   const u16* __restrict__ Alo,
                                                   const u16* __restrict__ Whi,
                                                   const u16* __restrict__ Wlo,
                                                   float* __restrict__ C,
                                                   int K, int Ncols) {
    __shared__ __align__(16) u16 lAhi[128][64];
    __shared__ __align__(16) u16 lAlo[128][64];
    __shared__ __align__(16) u16 lWh[128][64];
    __shared__ __align__(16) u16 lWl[128][64];

    int row0 = blockIdx.y * 128;
    int col0 = blockIdx.x * 128;
    int tid = threadIdx.x;
    int lane = tid & 63, wid = tid >> 6;
    int wm = (wid >> 1) * 64, wn = (wid & 1) * 64;
    int lanelo = lane & 15, quad = lane >> 4;

    f32x4 acc[4][4] = {};

    int scb = tid & 7;          // col-block (8 bf16 each) 0..7
    int sr  = tid >> 3;         // 0..31

    for (int k0 = 0; k0 < K; k0 += 64) {
#pragma unroll
        for (int rr = 0; rr < 4; ++rr) {
            int r = sr + rr * 32;
            size_t gofs = (size_t)(row0 + r) * K + k0 + scb * 8;
            uint4 vh = *(const uint4*)(Ahi + gofs);
            uint4 vl = *(const uint4*)(Alo + gofs);
            int cc = (scb ^ (r & 7)) * 8;   // XOR swizzle
            *(uint4*)&lAhi[r][cc] = vh;
            *(uint4*)&lAlo[r][cc] = vl;
        }
#pragma unroll
        for (int rr = 0; rr < 4; ++rr) {
            int r = sr + rr * 32;
            size_t gofs = (size_t)(col0 + r) * K + k0 + scb * 8;
            uint4 vh = *(const uint4*)(Whi + gofs);
            uint4 vl = *(const uint4*)(Wlo + gofs);
            int cc = (scb ^ (r & 7)) * 8;
            *(uint4*)&lWh[r][cc] = vh;
            *(uint4*)&lWl[r][cc] = vl;
        }
        __syncthreads();

#pragma unroll
        for (int kk = 0; kk < 64; kk += 32) {
            short8 ah[4], al[4], bh[4], bl[4];
            int cbb = (kk >> 3) + quad;
#pragma unroll
            for (int mt = 0; mt < 4; ++mt) {
                int r = wm + mt * 16 + lanelo;
                int cc = (cbb ^ (r & 7)) * 8;
                ah[mt] = *(const short8*)&lAhi[r][cc];
                al[mt] = *(const short8*)&lAlo[r][cc];
            }
#pragma unroll
            for (int nt = 0; nt < 4; ++nt) {
                int r = wn + nt * 16 + lanelo;
                int cc = (cbb ^ (r & 7)) * 8;
                bh[nt] = *(const short8*)&lWh[r][cc];
                bl[nt] = *(const short8*)&lWl[r][cc];
            }
#pragma unroll
            for (int mt = 0; mt < 4; ++mt)
#pragma unroll
                for (int nt = 0; nt < 4; ++nt) {
                    acc[mt][nt] = __builtin_amdgcn_mfma_f32_16x16x32_bf16(
                        ah[mt], bh[nt], acc[mt][nt], 0, 0, 0);
                    acc[mt][nt] = __builtin_amdgcn_mfma_f32_16x16x32_bf16(
                        al[mt], bh[nt], acc[mt][nt], 0, 0, 0);
                    acc[mt][nt] = __builtin_amdgcn_mfma_f32_16x16x32_bf16(
                        ah[mt], bl[nt], acc[mt][nt], 0, 0, 0);
                }
        }
        __syncthreads();
    }

#pragma unroll
    for (int mt = 0; mt < 4; ++mt)
#pragma unroll
        for (int nt = 0; nt < 4; ++nt)
#pragma unroll
            for (int r = 0; r < 4; ++r) {
                int row = row0 + wm + mt * 16 + quad * 4 + r;
                int col = col0 + wn + nt * 16 + lanelo;
                C[(size_t)row * Ncols + col] = acc[mt][nt][r];
            }
}

// ---------- 7b) depot-1 batch sum: out[b][c] = sum_{j>=2} y[b,j,c]*dinv[b,j] ----------
// grid (64, M/128), block 1024: 32 quad-channels x 32 edge-slots + LDS tree reduce.
__global__ __launch_bounds__(1024) void dep1_kernel(const float* __restrict__ y,
                                                    const float* __restrict__ dinv,
                                                    float* __restrict__ outb,
                                                    int M) {
    int b = blockIdx.x;
    int co = blockIdx.y * 128;
    int tid = threadIdx.x;
    int c4 = tid & 31;       // quad-channel 0..31 (128 channels)
    int es = tid >> 5;       // edge slot 0..31
    const float* yb = y + (size_t)b * Ss * M + co + c4 * 4;
    const float* dv = dinv + b * Ss;
    float a0 = 0.f, a1 = 0.f, a2 = 0.f, a3 = 0.f;
    for (int j = 2 + es; j < Ss; j += 32) {
        float w = dv[j];
        const float* p = yb + (size_t)j * M;
        float4 u = *(const float4*)p;
        a0 += u.x * w; a1 += u.y * w; a2 += u.z * w; a3 += u.w * w;
    }
    __shared__ float4 red[1024];
    float4 mv; mv.x = a0; mv.y = a1; mv.z = a2; mv.w = a3;
    red[tid] = mv;
    __syncthreads();
#pragma unroll
    for (int s = 16; s > 0; s >>= 1) {
        if (es < s) {
            float4 o = red[tid + (s << 5)];
            float4 m = red[tid];
            m.x += o.x; m.y += o.y; m.z += o.z; m.w += o.w;
            red[tid] = m;
        }
        __syncthreads();
    }
    if (es == 0) *(float4*)(outb + (size_t)b * M + co + c4 * 4) = red[c4];
}

// ---------- 8) aggregation M=512 + bias + relu -> split bf16 ----------
// XCD-swizzled: all nodes of one batch on one XCD (blockIdx%8 round-robin heuristic).
__global__ __launch_bounds__(128) void agg512_kernel(const float* __restrict__ y,
                                                     const float* __restrict__ dinv,
                                                     const int* __restrict__ offs,
                                                     const int* __restrict__ indeg,
                                                     const u16* __restrict__ rev,
                                                     const float* __restrict__ bias,
                                                     const float* __restrict__ dep1,
                                                     u16* __restrict__ oHi,
                                                     u16* __restrict__ oLo) {
    int bx = blockIdx.x;
    int x = bx & 7, q = bx >> 3;
    int bb = q / 1000;
    int i = q - bb * 1000;
    int b = x + (bb << 3);
    int n = b * Ss + i;
    int nb = n - i;
    int tid = threadIdx.x, c = tid * 4;

    __shared__ int   sidx[128];
    __shared__ float sw[128];
    int cnt = 0, o = 0;
    if (i >= 2) { cnt = indeg[n]; o = offs[n]; }
    int cl = cnt < 128 ? cnt : 128;
    if (tid < cl) {
        int s = rev[o + tid];
        sidx[tid] = s;
        sw[tid] = dinv[nb + s];
    }
    __syncthreads();

    float a0 = 0.f, a1 = 0.f, a2 = 0.f, a3 = 0.f;
    if (i >= 2) {
        float w = dinv[nb];  // == 1.0 (deg[0]=1)
        float4 v = *(const float4*)(y + (size_t)nb * 512 + c);
        a0 = v.x * w; a1 = v.y * w; a2 = v.z * w; a3 = v.w * w;
        int e = 0;
        for (; e + 4 <= cl; e += 4) {
            int s0 = sidx[e], s1 = sidx[e + 1], s2 = sidx[e + 2], s3 = sidx[e + 3];
            float w0 = sw[e], w1 = sw[e + 1], w2 = sw[e + 2], w3 = sw[e + 3];
            float4 u0 = *(const float4*)(y + (size_t)(nb + s0) * 512 + c);
            float4 u1 = *(const float4*)(y + (size_t)(nb + s1) * 512 + c);
            float4 u2 = *(const float4*)(y + (size_t)(nb + s2) * 512 + c);
            float4 u3 = *(const float4*)(y + (size_t)(nb + s3) * 512 + c);
            a0 += u0.x * w0 + u1.x * w1 + u2.x * w2 + u3.x * w3;
            a1 += u0.y * w0 + u1.y * w1 + u2.y * w2 + u3.y * w3;
            a2 += u0.z * w0 + u1.z * w1 + u2.z * w2 + u3.z * w3;
            a3 += u0.w * w0 + u1.w * w1 + u2.w * w2 + u3.w * w3;
        }
        for (; e < cl; ++e) {
            int s = sidx[e]; float ww = sw[e];
            float4 u = *(const float4*)(y + (size_t)(nb + s) * 512 + c);
            a0 += u.x * ww; a1 += u.y * ww; a2 += u.z * ww; a3 += u.w * ww;
        }
        for (int e2 = 128; e2 < cnt; ++e2) {   // safety fallback (never in practice)
            int s = rev[o + e2]; float ww = dinv[nb + s];
            float4 u = *(const float4*)(y + (size_t)(nb + s) * 512 + c);
            a0 += u.x * ww; a1 += u.y * ww; a2 += u.z * ww; a3 += u.w * ww;
        }
    } else if (i == 1) {
        float4 v = *(const float4*)(dep1 + (size_t)b * 512 + c);
        a0 = v.x; a1 = v.y; a2 = v.z; a3 = v.w;
    }
    float dn = dinv[n], sn = dn * dn;
    float4 vs = *(const float4*)(y + (size_t)n * 512 + c);
    float z0 = a0 * dn + vs.x * sn + bias[c];
    float z1 = a1 * dn + vs.y * sn + bias[c + 1];
    float z2 = a2 * dn + vs.z * sn + bias[c + 2];
    float z3 = a3 * dn + vs.w * sn + bias[c + 3];
    z0 = fmaxf(z0, 0.f); z1 = fmaxf(z1, 0.f); z2 = fmaxf(z2, 0.f); z3 = fmaxf(z3, 0.f);
    u16 h0, l0, h1, l1, h2, l2, h3, l3;
    split2(z0, h0, l0); split2(z1, h1, l1); split2(z2, h2, l2); split2(z3, h3, l3);
    ushort4 hv; hv.x = h0; hv.y = h1; hv.z = h2; hv.w = h3;
    ushort4 lv; lv.x = l0; lv.y = l1; lv.z = l2; lv.w = l3;
    *(ushort4*)(oHi + (size_t)n * 512 + c) = hv;
    *(ushort4*)(oLo + (size_t)n * 512 + c) = lv;
}

// ---------- 9) final aggregation M=128, no relu, fp32 out ----------
__global__ __launch_bounds__(128) void agg128f_kernel(const float* __restrict__ y,
                                                      const float* __restrict__ dinv,
                                                      const int* __restrict__ offs,
                                                      const int* __restrict__ indeg,
                                                      const u16* __restrict__ rev,
                                                      const float* __restrict__ bias,
                                                      const float* __restrict__ dep1,
                                                      float* __restrict__ out) {
    int bx = blockIdx.x;
    int x = bx & 7, q = bx >> 3;
    int bb = q / 1000;
    int i = q - bb * 1000;
    int b = x + (bb << 3);
    int n = b * Ss + i;
    int nb = n - i;
    int tid = threadIdx.x, c = tid;

    __shared__ int   sidx[128];
    __shared__ float sw[128];
    int cnt = 0, o = 0;
    if (i >= 2) { cnt = indeg[n]; o = offs[n]; }
    int cl = cnt < 128 ? cnt : 128;
    if (tid < cl) {
        int s = rev[o + tid];
        sidx[tid] = s;
        sw[tid] = dinv[nb + s];
    }
    __syncthreads();

    float a = 0.f;
    if (i >= 2) {
        a = y[(size_t)nb * 128 + c] * dinv[nb];
        int e = 0;
        for (; e + 4 <= cl; e += 4) {
            int s0 = sidx[e], s1 = sidx[e + 1], s2 = sidx[e + 2], s3 = sidx[e + 3];
            float w0 = sw[e], w1 = sw[e + 1], w2 = sw[e + 2], w3 = sw[e + 3];
            float u0 = y[(size_t)(nb + s0) * 128 + c];
            float u1 = y[(size_t)(nb + s1) * 128 + c];
            float u2 = y[(size_t)(nb + s2) * 128 + c];
            float u3 = y[(size_t)(nb + s3) * 128 + c];
            a += u0 * w0 + u1 * w1 + u2 * w2 + u3 * w3;
        }
        for (; e < cl; ++e) a += y[(size_t)(nb + sidx[e]) * 128 + c] * sw[e];
        for (int e2 = 128; e2 < cnt; ++e2) {
            int s = rev[o + e2];
            a += y[(size_t)(nb + s) * 128 + c] * dinv[nb + s];
        }
    } else if (i == 1) {
        a = dep1[(size_t)b * 128 + c];
    }
    float dn = dinv[n];
    out[(size_t)n * 128 + c] = a * dn + y[(size_t)n * 128 + c] * (dn * dn) + bias[c];
}

// ---------- workspace layout (bytes); total 266,528,768 ----------
constexpr size_t O_INDEG  = 0;                       // 256000
constexpr size_t O_CURSOR = 256000;                  // 256000; reused post-fill_rev:
constexpr size_t O_DEP1A  = 256000;                  //   64*512*4 = 131072
constexpr size_t O_DEP1B  = 387072;                  //   64*128*4 = 32768
constexpr size_t O_OFFS   = 512000;                  // 256016
constexpr size_t O_DINV   = 768256;                  // 256000
constexpr size_t O_KNN    = 1024256;                 // 893824
constexpr size_t O_REV    = 1918080;                 // 893824
constexpr size_t O_WT0H   = 2811904;                 // 131072
constexpr size_t O_WT0L   = 2942976;
constexpr size_t O_WT1H   = 3074048;                 // 524288
constexpr size_t O_WT1L   = 3598336;
constexpr size_t O_WT2H   = 4122624;                 // 131072
constexpr size_t O_WT2L   = 4253696;
constexpr size_t O_AHI    = 4384768;                 // 65536000
constexpr size_t O_ALO    = 69920768;                // 65536000
constexpr size_t O_Y      = 135456768;               // 131072000

extern "C" void kernel_launch(void* const* d_in, const int* in_sizes, int n_in,
                              void* d_out, int out_size, void* d_ws, size_t ws_size,
                              hipStream_t stream) {
    const float* inputs = (const float*)d_in[0];
    const float* scor   = (const float*)d_in[1];
    const float* Wc     = (const float*)d_in[2];
    const float* bc     = (const float*)d_in[3];
    const float* Ws     = (const float*)d_in[4];
    const float* bs     = (const float*)d_in[5];
    const float* W0     = (const float*)d_in[6];
    const float* b0     = (const float*)d_in[7];
    const float* W1     = (const float*)d_in[8];
    const float* b1     = (const float*)d_in[9];
    const float* W2     = (const float*)d_in[10];
    const float* b2     = (const float*)d_in[11];

    char* w = (char*)d_ws;
    int*   indeg  = (int*)(w + O_INDEG);
    int*   cursor = (int*)(w + O_CURSOR);
    float* dep1a  = (float*)(w + O_DEP1A);
    float* dep1b  = (float*)(w + O_DEP1B);
    int*   offs   = (int*)(w + O_OFFS);
    float* dinv   = (float*)(w + O_DINV);
    u16*   knn    = (u16*)(w + O_KNN);
    u16*   rev    = (u16*)(w + O_REV);
    u16*   wt0h   = (u16*)(w + O_WT0H);
    u16*   wt0l   = (u16*)(w + O_WT0L);
    u16*   wt1h   = (u16*)(w + O_WT1H);
    u16*   wt1l   = (u16*)(w + O_WT1L);
    u16*   wt2h   = (u16*)(w + O_WT2H);
    u16*   wt2l   = (u16*)(w + O_WT2L);
    u16*   ahi    = (u16*)(w + O_AHI);
    u16*   alo    = (u16*)(w + O_ALO);
    float* y      = (float*)(w + O_Y);

    hipMemsetAsync(w + O_INDEG, 0, 512000, stream);  // indeg + cursor

    knn_kernel<<<dim3(Bb, 4), 256, 0, stream>>>(inputs, knn, indeg);
    deg_dinv_kernel<<<250, 256, 0, stream>>>(indeg, dinv);
    scan_kernel<<<1, 1024, 0, stream>>>(indeg, offs);
    fill_rev_kernel<<<dim3(Bb, 4), 256, 0, stream>>>(knn, offs, cursor, rev);

    embed_kernel<<<NN * Dd / 256, 256, 0, stream>>>(inputs, scor, Wc, bc, Ws, bs, ahi, alo);

    transp_split_kernel<<<(Dd * Hh + 255) / 256, 256, 0, stream>>>(W0, wt0h, wt0l, Dd, Hh);
    transp_split_kernel<<<(Hh * Hh + 255) / 256, 256, 0, stream>>>(W1, wt1h, wt1l, Hh, Hh);
    transp_split_kernel<<<(Hh * Dd + 255) / 256, 256, 0, stream>>>(W2, wt2h, wt2l, Hh, Dd);

    // layer 0: [N,128] @ [128,512]
    gemm_kernel<<<dim3(Hh / 128, NN / 128), 256, 0, stream>>>(ahi, alo, wt0h, wt0l, y, Dd, Hh);
    dep1_kernel<<<dim3(Bb, 4), 1024, 0, stream>>>(y, dinv, dep1a, Hh);
    agg512_kernel<<<NN, 128, 0, stream>>>(y, dinv, offs, indeg, rev, b0, dep1a, ahi, alo);
    // layer 1: [N,512] @ [512,512]
    gemm_kernel<<<dim3(Hh / 128, NN / 128), 256, 0, stream>>>(ahi, alo, wt1h, wt1l, y, Hh, Hh);
    dep1_kernel<<<dim3(Bb, 4), 1024, 0, stream>>>(y, dinv, dep1a, Hh);
    agg512_kernel<<<NN, 128, 0, stream>>>(y, dinv, offs, indeg, rev, b1, dep1a, ahi, alo);
    // layer 2: [N,512] @ [512,128]
    gemm_kernel<<<dim3(Dd / 128, NN / 128), 256, 0, stream>>>(ahi, alo, wt2h, wt2l, y, Hh, Dd);
    dep1_kernel<<<dim3(Bb, 1), 1024, 0, stream>>>(y, dinv, dep1b, Dd);
    agg128f_kernel<<<NN, 128, 0, stream>>>(y, dinv, offs, indeg, rev, b2, dep1b, (float*)d_out);
}

// Round 4
// 731.699 us; speedup vs baseline: 1.9175x; 1.1340x over previous
//
#include <hip/hip_runtime.h>

typedef unsigned short u16;
typedef unsigned int u32;
typedef unsigned long long u64;
using short8 = __attribute__((ext_vector_type(8))) short;
using f32x4  = __attribute__((ext_vector_type(4))) float;

constexpr int Bb = 64, Ss = 1000, Dd = 128, Hh = 512;
constexpr int NN = Bb * Ss;           // 64000 nodes
constexpr int NSRC = Ss - 2;          // 998 kNN source nodes per batch

// ---------- helpers ----------
__device__ __forceinline__ float bf2f(u16 h) {
    u32 u = ((u32)h) << 16;
    return __builtin_bit_cast(float, u);
}
__device__ __forceinline__ u16 f2bf(float v) {  // RNE, finite inputs only
    u32 u = __builtin_bit_cast(u32, v);
    u32 r = (u + 0x7FFFu + ((u >> 16) & 1u)) >> 16;
    return (u16)r;
}
__device__ __forceinline__ void split2(float v, u16& h, u16& l) {
    h = f2bf(v);
    float fh = bf2f(h);
    l = f2bf(v - fh);
}

// ---------- 1) kNN build: 4 threads per node, local top-7 + stable merge ----------
// Tie-break == jax.lax.top_k: ascending (d, j) lexicographic via packed u64 key.
__global__ __launch_bounds__(256) void knn_kernel(const float* __restrict__ inputs,
                                                  u16* __restrict__ knn,
                                                  int* __restrict__ indeg) {
    __shared__ float2 pts[Ss];
    __shared__ u64 keys[64][28];
    int b = blockIdx.x;
    const float* base = inputs + (size_t)b * Ss * 2;
    for (int t = threadIdx.x; t < Ss; t += 256) {
        float2 p;
        p.x = base[2 * t];
        p.y = base[2 * t + 1];
        pts[t] = p;
    }
    __syncthreads();

    int tid = threadIdx.x;
    int ln = tid >> 2;                  // local node 0..63
    int part = tid & 3;                 // candidate quarter 0..3
    int i = 2 + blockIdx.y * 64 + ln;
    if (i < Ss) {
        float xi = pts[i].x, yi = pts[i].y;
        float bd[7];
        int   bi[7];
#pragma unroll
        for (int k = 0; k < 7; ++k) { bd[k] = __builtin_inff(); bi[k] = -1; }

        int j0 = part * 250, j1 = j0 + 250;
        for (int j = j0; j < j1; ++j) {
            if (j == i) continue;
            float dx = __fsub_rn(xi, pts[j].x);   // fp32 RN (mirror numpy, no FMA)
            float dy = __fsub_rn(yi, pts[j].y);
            float d = __fsqrt_rn(__fadd_rn(__fmul_rn(dx, dx), __fmul_rn(dy, dy)));
            if (d < bd[6]) {                      // strict <: stable within thread
                int pos = 0;
#pragma unroll
                for (int k = 0; k < 7; ++k) pos += (bd[k] <= d) ? 1 : 0;
#pragma unroll
                for (int k = 6; k > 0; --k) {
                    bool sh = (k > pos);
                    bd[k] = sh ? bd[k - 1] : bd[k];
                    bi[k] = sh ? bi[k - 1] : bi[k];
                }
#pragma unroll
                for (int k = 0; k < 7; ++k)
                    if (k == pos) { bd[k] = d; bi[k] = j; }
            }
        }
#pragma unroll
        for (int k = 0; k < 7; ++k) {
            u32 db = __builtin_bit_cast(u32, bd[k]);   // d>=0: bits monotone
            keys[ln][part * 7 + k] = (((u64)db) << 32) | (u32)bi[k];
        }
    }
    __syncthreads();

    if (part == 0 && i < Ss) {
        int p0 = 0, p1 = 0, p2 = 0, p3 = 0;
        u16* kp = knn + ((size_t)b * NSRC + (i - 2)) * 7;
#pragma unroll
        for (int k = 0; k < 7; ++k) {
            u64 k0 = (p0 < 7) ? keys[ln][p0]      : ~0ULL;
            u64 k1 = (p1 < 7) ? keys[ln][7 + p1]  : ~0ULL;
            u64 k2 = (p2 < 7) ? keys[ln][14 + p2] : ~0ULL;
            u64 k3 = (p3 < 7) ? keys[ln][21 + p3] : ~0ULL;
            u64 m01 = k0 < k1 ? k0 : k1;
            u64 m23 = k2 < k3 ? k2 : k3;
            u64 m = m01 < m23 ? m01 : m23;
            p0 += (m == k0);
            p1 += (m == k1) & (m != k0);
            p2 += (m == k2) & (m != k0) & (m != k1);
            p3 += (m == k3) & (m != k0) & (m != k1) & (m != k2);
            int j = (int)(u32)m;
            kp[k] = (u16)j;
            if (j >= 2) atomicAdd(&indeg[b * Ss + j], 1);
        }
    }
}

// ---------- 2) degree -> dinv ----------
__global__ void deg_dinv_kernel(const int* __restrict__ indeg, float* __restrict__ dinv) {
    int n = blockIdx.x * 256 + threadIdx.x;
    if (n >= NN) return;
    int i = n % Ss;
    float deg = (i == 0) ? 1.0f : (i == 1) ? (float)(Ss - 1) : (float)(indeg[n] + 2);
    dinv[n] = 1.0f / __fsqrt_rn(deg);
}

// ---------- 3) exclusive scan of indeg -> CSR offsets (single block) ----------
__global__ __launch_bounds__(1024) void scan_kernel(const int* __restrict__ indeg,
                                                    int* __restrict__ offs) {
    __shared__ int part[1024];
    int t = threadIdx.x;
    const int CH = 63;                       // 1024*63 >= 64000
    int lo = t * CH;
    int hi = lo + CH; if (hi > NN) hi = NN;
    int s = 0;
    for (int k = lo; k < hi; ++k) s += indeg[k];
    part[t] = s;
    __syncthreads();
    for (int off = 1; off < 1024; off <<= 1) {
        int v = (t >= off) ? part[t - off] : 0;
        __syncthreads();
        part[t] += v;
        __syncthreads();
    }
    int run = part[t] - s;                   // exclusive prefix
    for (int k = lo; k < hi; ++k) { offs[k] = run; run += indeg[k]; }
    if (t == 1023) offs[NN] = part[1023];
}

// ---------- 4) scatter reverse adjacency (src local index per dst) ----------
__global__ __launch_bounds__(256) void fill_rev_kernel(const u16* __restrict__ knn,
                                                       const int* __restrict__ offs,
                                                       int* __restrict__ cursor,
                                                       u16* __restrict__ rev) {
    if (threadIdx.x >= 250) return;
    int b = blockIdx.x;
    int i = 2 + blockIdx.y * 250 + threadIdx.x;
    if (i >= Ss) return;
    const u16* kp = knn + ((size_t)b * NSRC + (i - 2)) * 7;
#pragma unroll
    for (int k = 0; k < 7; ++k) {
        int d = kp[k];
        if (d >= 2) {
            int n = b * Ss + d;
            int p = atomicAdd(&cursor[n], 1);
            rev[offs[n] + p] = (u16)i;       // store local src index
        }
    }
}

// ---------- 5) embedding: x = inputs@Wc+bc + scor@Ws+bs, split hi/lo bf16 ----------
__global__ __launch_bounds__(256) void embed_kernel(const float* __restrict__ inputs,
                                                    const float* __restrict__ scor,
                                                    const float* __restrict__ Wc,
                                                    const float* __restrict__ bc,
                                                    const float* __restrict__ Ws,
                                                    const float* __restrict__ bs,
                                                    u16* __restrict__ xhi,
                                                    u16* __restrict__ xlo) {
    int gid = blockIdx.x * 256 + threadIdx.x;
    if (gid >= NN * Dd) return;
    int n = gid >> 7, c = gid & 127;
    float i0 = inputs[2 * n], i1 = inputs[2 * n + 1], sc = scor[n];
    float t1 = i0 * Wc[c] + i1 * Wc[Dd + c] + bc[c];
    float t2 = sc * Ws[c] + bs[c];
    float v = t1 + t2;
    u16 h, l;
    split2(v, h, l);
    xhi[gid] = h;
    xlo[gid] = l;
}

// ---------- 6) weight transpose + split ----------
__global__ void transp_split_kernel(const float* __restrict__ src,
                                    u16* __restrict__ dhi, u16* __restrict__ dlo,
                                    int R, int C) {
    int gid = blockIdx.x * 256 + threadIdx.x;
    if (gid >= R * C) return;
    int r = gid / C, c = gid - r * C;
    u16 h, l;
    split2(src[gid], h, l);
    dhi[c * R + r] = h;
    dlo[c * R + r] = l;
}

// ---------- 7) split-bf16 MFMA GEMM: C = A @ W, 3-MFMA scheme ----------
// grid: (Ncols/128, M/128) — col fastest so A-tile reuse is temporally adjacent.
__global__ __launch_bounds__(256) void gemm_kernel(const u16* __restrict__ Ahi,
                                                   const u16* __restrict__ Alo,
                                                   const u16* __restrict__ Whi,
                                                   const u16* __restrict__ Wlo,
                                                   float* __restrict__ C,
                                                   int K, int Ncols) {
    __shared__ __align__(16) u16 lAhi[128][64];
    __shared__ __align__(16) u16 lAlo[128][64];
    __shared__ __align__(16) u16 lWh[128][64];
    __shared__ __align__(16) u16 lWl[128][64];

    int row0 = blockIdx.y * 128;
    int col0 = blockIdx.x * 128;
    int tid = threadIdx.x;
    int lane = tid & 63, wid = tid >> 6;
    int wm = (wid >> 1) * 64, wn = (wid & 1) * 64;
    int lanelo = lane & 15, quad = lane >> 4;

    f32x4 acc[4][4] = {};

    int scb = tid & 7;          // col-block (8 bf16 each) 0..7
    int sr  = tid >> 3;         // 0..31

    for (int k0 = 0; k0 < K; k0 += 64) {
#pragma unroll
        for (int rr = 0; rr < 4; ++rr) {
            int r = sr + rr * 32;
            size_t gofs = (size_t)(row0 + r) * K + k0 + scb * 8;
            uint4 vh = *(const uint4*)(Ahi + gofs);
            uint4 vl = *(const uint4*)(Alo + gofs);
            int cc = (scb ^ (r & 7)) * 8;   // XOR swizzle
            *(uint4*)&lAhi[r][cc] = vh;
            *(uint4*)&lAlo[r][cc] = vl;
        }
#pragma unroll
        for (int rr = 0; rr < 4; ++rr) {
            int r = sr + rr * 32;
            size_t gofs = (size_t)(col0 + r) * K + k0 + scb * 8;
            uint4 vh = *(const uint4*)(Whi + gofs);
            uint4 vl = *(const uint4*)(Wlo + gofs);
            int cc = (scb ^ (r & 7)) * 8;
            *(uint4*)&lWh[r][cc] = vh;
            *(uint4*)&lWl[r][cc] = vl;
        }
        __syncthreads();

#pragma unroll
        for (int kk = 0; kk < 64; kk += 32) {
            short8 ah[4], al[4], bh[4], bl[4];
            int cbb = (kk >> 3) + quad;
#pragma unroll
            for (int mt = 0; mt < 4; ++mt) {
                int r = wm + mt * 16 + lanelo;
                int cc = (cbb ^ (r & 7)) * 8;
                ah[mt] = *(const short8*)&lAhi[r][cc];
                al[mt] = *(const short8*)&lAlo[r][cc];
            }
#pragma unroll
            for (int nt = 0; nt < 4; ++nt) {
                int r = wn + nt * 16 + lanelo;
                int cc = (cbb ^ (r & 7)) * 8;
                bh[nt] = *(const short8*)&lWh[r][cc];
                bl[nt] = *(const short8*)&lWl[r][cc];
            }
#pragma unroll
            for (int mt = 0; mt < 4; ++mt)
#pragma unroll
                for (int nt = 0; nt < 4; ++nt) {
                    acc[mt][nt] = __builtin_amdgcn_mfma_f32_16x16x32_bf16(
                        ah[mt], bh[nt], acc[mt][nt], 0, 0, 0);
                    acc[mt][nt] = __builtin_amdgcn_mfma_f32_16x16x32_bf16(
                        al[mt], bh[nt], acc[mt][nt], 0, 0, 0);
                    acc[mt][nt] = __builtin_amdgcn_mfma_f32_16x16x32_bf16(
                        ah[mt], bl[nt], acc[mt][nt], 0, 0, 0);
                }
        }
        __syncthreads();
    }

#pragma unroll
    for (int mt = 0; mt < 4; ++mt)
#pragma unroll
        for (int nt = 0; nt < 4; ++nt)
#pragma unroll
            for (int r = 0; r < 4; ++r) {
                int row = row0 + wm + mt * 16 + quad * 4 + r;
                int col = col0 + wn + nt * 16 + lanelo;
                C[(size_t)row * Ncols + col] = acc[mt][nt][r];
            }
}

// ---------- 7b) depot-1 batch sum: out[b][c] = sum_{j>=2} y[b,j,c]*dinv[b,j] ----------
__global__ __launch_bounds__(1024) void dep1_kernel(const float* __restrict__ y,
                                                    const float* __restrict__ dinv,
                                                    float* __restrict__ outb,
                                                    int M) {
    int b = blockIdx.x;
    int co = blockIdx.y * 128;
    int tid = threadIdx.x;
    int c4 = tid & 31;       // quad-channel 0..31 (128 channels)
    int es = tid >> 5;       // edge slot 0..31
    const float* yb = y + (size_t)b * Ss * M + co + c4 * 4;
    const float* dv = dinv + b * Ss;
    float a0 = 0.f, a1 = 0.f, a2 = 0.f, a3 = 0.f;
    for (int j = 2 + es; j < Ss; j += 32) {
        float w = dv[j];
        const float* p = yb + (size_t)j * M;
        float4 u = *(const float4*)p;
        a0 += u.x * w; a1 += u.y * w; a2 += u.z * w; a3 += u.w * w;
    }
    __shared__ float4 red[1024];
    float4 mv; mv.x = a0; mv.y = a1; mv.z = a2; mv.w = a3;
    red[tid] = mv;
    __syncthreads();
#pragma unroll
    for (int s = 16; s > 0; s >>= 1) {
        if (es < s) {
            float4 o = red[tid + (s << 5)];
            float4 m = red[tid];
            m.x += o.x; m.y += o.y; m.z += o.z; m.w += o.w;
            red[tid] = m;
        }
        __syncthreads();
    }
    if (es == 0) *(float4*)(outb + (size_t)b * M + co + c4 * 4) = red[c4];
}

// ---------- 8) aggregation M=512 + bias + relu -> split bf16 ----------
__global__ __launch_bounds__(128) void agg512_kernel(const float* __restrict__ y,
                                                     const float* __restrict__ dinv,
                                                     const int* __restrict__ offs,
                                                     const int* __restrict__ indeg,
                                                     const u16* __restrict__ rev,
                                                     const float* __restrict__ bias,
                                                     const float* __restrict__ dep1,
                                                     u16* __restrict__ oHi,
                                                     u16* __restrict__ oLo) {
    int bx = blockIdx.x;
    int x = bx & 7, q = bx >> 3;
    int bb = q / 1000;
    int i = q - bb * 1000;
    int b = x + (bb << 3);
    int n = b * Ss + i;
    int nb = n - i;
    int tid = threadIdx.x, c = tid * 4;

    __shared__ int   sidx[128];
    __shared__ float sw[128];
    int cnt = 0, o = 0;
    if (i >= 2) { cnt = indeg[n]; o = offs[n]; }
    int cl = cnt < 128 ? cnt : 128;
    if (tid < cl) {
        int s = rev[o + tid];
        sidx[tid] = s;
        sw[tid] = dinv[nb + s];
    }
    __syncthreads();

    float a0 = 0.f, a1 = 0.f, a2 = 0.f, a3 = 0.f;
    if (i >= 2) {
        float w = dinv[nb];  // == 1.0 (deg[0]=1)
        float4 v = *(const float4*)(y + (size_t)nb * 512 + c);
        a0 = v.x * w; a1 = v.y * w; a2 = v.z * w; a3 = v.w * w;
        int e = 0;
        for (; e + 4 <= cl; e += 4) {
            int s0 = sidx[e], s1 = sidx[e + 1], s2 = sidx[e + 2], s3 = sidx[e + 3];
            float w0 = sw[e], w1 = sw[e + 1], w2 = sw[e + 2], w3 = sw[e + 3];
            float4 u0 = *(const float4*)(y + (size_t)(nb + s0) * 512 + c);
            float4 u1 = *(const float4*)(y + (size_t)(nb + s1) * 512 + c);
            float4 u2 = *(const float4*)(y + (size_t)(nb + s2) * 512 + c);
            float4 u3 = *(const float4*)(y + (size_t)(nb + s3) * 512 + c);
            a0 += u0.x * w0 + u1.x * w1 + u2.x * w2 + u3.x * w3;
            a1 += u0.y * w0 + u1.y * w1 + u2.y * w2 + u3.y * w3;
            a2 += u0.z * w0 + u1.z * w1 + u2.z * w2 + u3.z * w3;
            a3 += u0.w * w0 + u1.w * w1 + u2.w * w2 + u3.w * w3;
        }
        for (; e < cl; ++e) {
            int s = sidx[e]; float ww = sw[e];
            float4 u = *(const float4*)(y + (size_t)(nb + s) * 512 + c);
            a0 += u.x * ww; a1 += u.y * ww; a2 += u.z * ww; a3 += u.w * ww;
        }
        for (int e2 = 128; e2 < cnt; ++e2) {   // safety fallback (never in practice)
            int s = rev[o + e2]; float ww = dinv[nb + s];
            float4 u = *(const float4*)(y + (size_t)(nb + s) * 512 + c);
            a0 += u.x * ww; a1 += u.y * ww; a2 += u.z * ww; a3 += u.w * ww;
        }
    } else if (i == 1) {
        float4 v = *(const float4*)(dep1 + (size_t)b * 512 + c);
        a0 = v.x; a1 = v.y; a2 = v.z; a3 = v.w;
    }
    float dn = dinv[n], sn = dn * dn;
    float4 vs = *(const float4*)(y + (size_t)n * 512 + c);
    float z0 = a0 * dn + vs.x * sn + bias[c];
    float z1 = a1 * dn + vs.y * sn + bias[c + 1];
    float z2 = a2 * dn + vs.z * sn + bias[c + 2];
    float z3 = a3 * dn + vs.w * sn + bias[c + 3];
    z0 = fmaxf(z0, 0.f); z1 = fmaxf(z1, 0.f); z2 = fmaxf(z2, 0.f); z3 = fmaxf(z3, 0.f);
    u16 h0, l0, h1, l1, h2, l2, h3, l3;
    split2(z0, h0, l0); split2(z1, h1, l1); split2(z2, h2, l2); split2(z3, h3, l3);
    ushort4 hv; hv.x = h0; hv.y = h1; hv.z = h2; hv.w = h3;
    ushort4 lv; lv.x = l0; lv.y = l1; lv.z = l2; lv.w = l3;
    *(ushort4*)(oHi + (size_t)n * 512 + c) = hv;
    *(ushort4*)(oLo + (size_t)n * 512 + c) = lv;
}

// ---------- 9) final aggregation M=128, no relu, fp32 out ----------
__global__ __launch_bounds__(128) void agg128f_kernel(const float* __restrict__ y,
                                                      const float* __restrict__ dinv,
                                                      const int* __restrict__ offs,
                                                      const int* __restrict__ indeg,
                                                      const u16* __restrict__ rev,
                                                      const float* __restrict__ bias,
                                                      const float* __restrict__ dep1,
                                                      float* __restrict__ out) {
    int bx = blockIdx.x;
    int x = bx & 7, q = bx >> 3;
    int bb = q / 1000;
    int i = q - bb * 1000;
    int b = x + (bb << 3);
    int n = b * Ss + i;
    int nb = n - i;
    int tid = threadIdx.x, c = tid;

    __shared__ int   sidx[128];
    __shared__ float sw[128];
    int cnt = 0, o = 0;
    if (i >= 2) { cnt = indeg[n]; o = offs[n]; }
    int cl = cnt < 128 ? cnt : 128;
    if (tid < cl) {
        int s = rev[o + tid];
        sidx[tid] = s;
        sw[tid] = dinv[nb + s];
    }
    __syncthreads();

    float a = 0.f;
    if (i >= 2) {
        a = y[(size_t)nb * 128 + c] * dinv[nb];
        int e = 0;
        for (; e + 4 <= cl; e += 4) {
            int s0 = sidx[e], s1 = sidx[e + 1], s2 = sidx[e + 2], s3 = sidx[e + 3];
            float w0 = sw[e], w1 = sw[e + 1], w2 = sw[e + 2], w3 = sw[e + 3];
            float u0 = y[(size_t)(nb + s0) * 128 + c];
            float u1 = y[(size_t)(nb + s1) * 128 + c];
            float u2 = y[(size_t)(nb + s2) * 128 + c];
            float u3 = y[(size_t)(nb + s3) * 128 + c];
            a += u0 * w0 + u1 * w1 + u2 * w2 + u3 * w3;
        }
        for (; e < cl; ++e) a += y[(size_t)(nb + sidx[e]) * 128 + c] * sw[e];
        for (int e2 = 128; e2 < cnt; ++e2) {
            int s = rev[o + e2];
            a += y[(size_t)(nb + s) * 128 + c] * dinv[nb + s];
        }
    } else if (i == 1) {
        a = dep1[(size_t)b * 128 + c];
    }
    float dn = dinv[n];
    out[(size_t)n * 128 + c] = a * dn + y[(size_t)n * 128 + c] * (dn * dn) + bias[c];
}

// ---------- workspace layout (bytes); total 266,528,768 ----------
constexpr size_t O_INDEG  = 0;                       // 256000
constexpr size_t O_CURSOR = 256000;                  // 256000; reused post-fill_rev:
constexpr size_t O_DEP1A  = 256000;                  //   64*512*4 = 131072
constexpr size_t O_DEP1B  = 387072;                  //   64*128*4 = 32768
constexpr size_t O_OFFS   = 512000;                  // 256016
constexpr size_t O_DINV   = 768256;                  // 256000
constexpr size_t O_KNN    = 1024256;                 // 893824
constexpr size_t O_REV    = 1918080;                 // 893824
constexpr size_t O_WT0H   = 2811904;                 // 131072
constexpr size_t O_WT0L   = 2942976;
constexpr size_t O_WT1H   = 3074048;                 // 524288
constexpr size_t O_WT1L   = 3598336;
constexpr size_t O_WT2H   = 4122624;                 // 131072
constexpr size_t O_WT2L   = 4253696;
constexpr size_t O_AHI    = 4384768;                 // 65536000
constexpr size_t O_ALO    = 69920768;                // 65536000
constexpr size_t O_Y      = 135456768;               // 131072000

extern "C" void kernel_launch(void* const* d_in, const int* in_sizes, int n_in,
                              void* d_out, int out_size, void* d_ws, size_t ws_size,
                              hipStream_t stream) {
    const float* inputs = (const float*)d_in[0];
    const float* scor   = (const float*)d_in[1];
    const float* Wc     = (const float*)d_in[2];
    const float* bc     = (const float*)d_in[3];
    const float* Ws     = (const float*)d_in[4];
    const float* bs     = (const float*)d_in[5];
    const float* W0     = (const float*)d_in[6];
    const float* b0     = (const float*)d_in[7];
    const float* W1     = (const float*)d_in[8];
    const float* b1     = (const float*)d_in[9];
    const float* W2     = (const float*)d_in[10];
    const float* b2     = (const float*)d_in[11];

    char* w = (char*)d_ws;
    int*   indeg  = (int*)(w + O_INDEG);
    int*   cursor = (int*)(w + O_CURSOR);
    float* dep1a  = (float*)(w + O_DEP1A);
    float* dep1b  = (float*)(w + O_DEP1B);
    int*   offs   = (int*)(w + O_OFFS);
    float* dinv   = (float*)(w + O_DINV);
    u16*   knn    = (u16*)(w + O_KNN);
    u16*   rev    = (u16*)(w + O_REV);
    u16*   wt0h   = (u16*)(w + O_WT0H);
    u16*   wt0l   = (u16*)(w + O_WT0L);
    u16*   wt1h   = (u16*)(w + O_WT1H);
    u16*   wt1l   = (u16*)(w + O_WT1L);
    u16*   wt2h   = (u16*)(w + O_WT2H);
    u16*   wt2l   = (u16*)(w + O_WT2L);
    u16*   ahi    = (u16*)(w + O_AHI);
    u16*   alo    = (u16*)(w + O_ALO);
    float* y      = (float*)(w + O_Y);

    hipMemsetAsync(w + O_INDEG, 0, 512000, stream);  // indeg + cursor

    knn_kernel<<<dim3(Bb, 16), 256, 0, stream>>>(inputs, knn, indeg);
    deg_dinv_kernel<<<250, 256, 0, stream>>>(indeg, dinv);
    scan_kernel<<<1, 1024, 0, stream>>>(indeg, offs);
    fill_rev_kernel<<<dim3(Bb, 4), 256, 0, stream>>>(knn, offs, cursor, rev);

    embed_kernel<<<NN * Dd / 256, 256, 0, stream>>>(inputs, scor, Wc, bc, Ws, bs, ahi, alo);

    transp_split_kernel<<<(Dd * Hh + 255) / 256, 256, 0, stream>>>(W0, wt0h, wt0l, Dd, Hh);
    transp_split_kernel<<<(Hh * Hh + 255) / 256, 256, 0, stream>>>(W1, wt1h, wt1l, Hh, Hh);
    transp_split_kernel<<<(Hh * Dd + 255) / 256, 256, 0, stream>>>(W2, wt2h, wt2l, Hh, Dd);

    // layer 0: [N,128] @ [128,512]
    gemm_kernel<<<dim3(Hh / 128, NN / 128), 256, 0, stream>>>(ahi, alo, wt0h, wt0l, y, Dd, Hh);
    dep1_kernel<<<dim3(Bb, 4), 1024, 0, stream>>>(y, dinv, dep1a, Hh);
    agg512_kernel<<<NN, 128, 0, stream>>>(y, dinv, offs, indeg, rev, b0, dep1a, ahi, alo);
    // layer 1: [N,512] @ [512,512]
    gemm_kernel<<<dim3(Hh / 128, NN / 128), 256, 0, stream>>>(ahi, alo, wt1h, wt1l, y, Hh, Hh);
    dep1_kernel<<<dim3(Bb, 4), 1024, 0, stream>>>(y, dinv, dep1a, Hh);
    agg512_kernel<<<NN, 128, 0, stream>>>(y, dinv, offs, indeg, rev, b1, dep1a, ahi, alo);
    // layer 2: [N,512] @ [512,128]
    gemm_kernel<<<dim3(Dd / 128, NN / 128), 256, 0, stream>>>(ahi, alo, wt2h, wt2l, y, Hh, Dd);
    dep1_kernel<<<dim3(Bb, 1), 1024, 0, stream>>>(y, dinv, dep1b, Dd);
    agg128f_kernel<<<NN, 128, 0, stream>>>(y, dinv, offs, indeg, rev, b2, dep1b, (float*)d_out);
}

// Round 5
// 697.785 us; speedup vs baseline: 2.0107x; 1.0486x over previous
//
#include <hip/hip_runtime.h>

typedef unsigned short u16;
typedef unsigned int u32;
typedef unsigned long long u64;
using short8 = __attribute__((ext_vector_type(8))) short;
using f32x4  = __attribute__((ext_vector_type(4))) float;

constexpr int Bb = 64, Ss = 1000, Dd = 128, Hh = 512;
constexpr int NN = Bb * Ss;           // 64000 nodes
constexpr int NSRC = Ss - 2;          // 998 kNN source nodes per batch

// ---------- helpers ----------
__device__ __forceinline__ float bf2f(u16 h) {
    u32 u = ((u32)h) << 16;
    return __builtin_bit_cast(float, u);
}
__device__ __forceinline__ u16 f2bf(float v) {  // RNE, finite inputs only
    u32 u = __builtin_bit_cast(u32, v);
    u32 r = (u + 0x7FFFu + ((u >> 16) & 1u)) >> 16;
    return (u16)r;
}
__device__ __forceinline__ void split2(float v, u16& h, u16& l) {
    h = f2bf(v);
    float fh = bf2f(h);
    l = f2bf(v - fh);
}

// ---------- 1) kNN: two-phase, branchless d^2 chain + exact (d,j) re-rank ----------
// Phase 1: per-thread 7-smallest d^2 via unconditional min/max chain (no sqrt, no idx).
// Merge -> tau2 (7th smallest d^2) -> T2max = largest x with sqrt_rn(x) <= sqrt_rn(tau2).
// Phase 2: collect all j with d2 <= T2max as (sqrt(d2), j) u64 keys; pick 7 smallest.
// This reproduces jax.lax.top_k's stable ascending-(d, j) order bit-exactly.
__global__ __launch_bounds__(256) void knn_kernel(const float* __restrict__ inputs,
                                                  u16* __restrict__ knn,
                                                  int* __restrict__ indeg) {
    __shared__ float2 pts[Ss];
    __shared__ float  mg[64][28];
    __shared__ u64    lst[64][24];
    __shared__ int    cnt[64];
    __shared__ float  t2max[64];

    int b = blockIdx.x;
    const float* base = inputs + (size_t)b * Ss * 2;
    for (int t = threadIdx.x; t < Ss; t += 256) {
        float2 p;
        p.x = base[2 * t];
        p.y = base[2 * t + 1];
        pts[t] = p;
    }
    __syncthreads();

    int tid = threadIdx.x;
    int ln = tid >> 2;                  // local node 0..63
    int part = tid & 3;                 // candidate quarter 0..3
    int i = 2 + blockIdx.y * 64 + ln;
    bool valid = (i < Ss);
    int j0 = part * 250, j1 = j0 + 250;
    float xi = 0.f, yi = 0.f;
    if (valid) { xi = pts[i].x; yi = pts[i].y; }
    const float INF = __builtin_inff();

    // ---- phase 1: branchless sorted-7 chain on d^2 ----
    if (valid) {
        float bd[7];
#pragma unroll
        for (int k = 0; k < 7; ++k) bd[k] = INF;
        for (int j = j0; j < j1; ++j) {
            float2 p = pts[j];
            float dx = __fsub_rn(xi, p.x);            // exact fp32 RN mirror
            float dy = __fsub_rn(yi, p.y);
            float d2 = __fadd_rn(__fmul_rn(dx, dx), __fmul_rn(dy, dy));
            d2 = (j == i) ? INF : d2;                 // exclude self
            float v = d2;
#pragma unroll
            for (int k = 0; k < 7; ++k) {             // insert, eject old max
                float lo = fminf(v, bd[k]);
                float hi = fmaxf(v, bd[k]);
                bd[k] = lo;
                v = hi;
            }
        }
#pragma unroll
        for (int k = 0; k < 7; ++k) mg[ln][part * 7 + k] = bd[k];
    }
    __syncthreads();

    // ---- merge 28 -> tau2; derive T2max; reset count ----
    if (part == 0 && valid) {
        float m[7];
#pragma unroll
        for (int k = 0; k < 7; ++k) m[k] = INF;
        for (int t = 0; t < 28; ++t) {
            float v = mg[ln][t];
#pragma unroll
            for (int k = 0; k < 7; ++k) {
                float lo = fminf(v, m[k]);
                float hi = fmaxf(v, m[k]);
                m[k] = lo;
                v = hi;
            }
        }
        float tau2 = m[6];
        float tau = __fsqrt_rn(tau2);
        float g = tau2;                                // sqrt_rn(g) == tau by construction
        for (int it = 0; it < 8; ++it) {               // widen to sqrt-collision boundary
            float gn = __builtin_bit_cast(float, __builtin_bit_cast(u32, g) + 1u);
            if (__fsqrt_rn(gn) <= tau) g = gn; else break;
        }
        t2max[ln] = g;
        cnt[ln] = 0;
    }
    __syncthreads();

    // ---- phase 2: threshold rescan, collect (d, j) keys ----
    if (valid) {
        float T = t2max[ln];
        for (int j = j0; j < j1; ++j) {
            float2 p = pts[j];
            float dx = __fsub_rn(xi, p.x);
            float dy = __fsub_rn(yi, p.y);
            float d2 = __fadd_rn(__fmul_rn(dx, dx), __fmul_rn(dy, dy));
            d2 = (j == i) ? INF : d2;
            if (d2 <= T) {
                float d = __fsqrt_rn(d2);
                u64 key = (((u64)__builtin_bit_cast(u32, d)) << 32) | (u32)j;
                int p2 = atomicAdd(&cnt[ln], 1);
                if (p2 < 24) lst[ln][p2] = key;
            }
        }
    }
    __syncthreads();

    // ---- final: select 7 smallest (d, j) keys -> knn + indeg ----
    if (part == 0 && valid) {
        int c = cnt[ln]; if (c > 24) c = 24;           // c >= 7 by construction
        u16* kp = knn + ((size_t)b * NSRC + (i - 2)) * 7;
#pragma unroll
        for (int k = 0; k < 7; ++k) {
            u64 best = ~0ULL; int bp = -1;
            for (int t = 0; t < c; ++t) {
                u64 v = lst[ln][t];
                if (v < best) { best = v; bp = t; }
            }
            int j = 0;
            if (bp >= 0) { lst[ln][bp] = ~0ULL; j = (int)(u32)best; }
            kp[k] = (u16)j;
            if (j >= 2) atomicAdd(&indeg[b * Ss + j], 1);
        }
    }
}

// ---------- 2) degree -> dinv ----------
__global__ void deg_dinv_kernel(const int* __restrict__ indeg, float* __restrict__ dinv) {
    int n = blockIdx.x * 256 + threadIdx.x;
    if (n >= NN) return;
    int i = n % Ss;
    float deg = (i == 0) ? 1.0f : (i == 1) ? (float)(Ss - 1) : (float)(indeg[n] + 2);
    dinv[n] = 1.0f / __fsqrt_rn(deg);
}

// ---------- 3) exclusive scan of indeg -> CSR offsets (single block) ----------
__global__ __launch_bounds__(1024) void scan_kernel(const int* __restrict__ indeg,
                                                    int* __restrict__ offs) {
    __shared__ int part[1024];
    int t = threadIdx.x;
    const int CH = 63;                       // 1024*63 >= 64000
    int lo = t * CH;
    int hi = lo + CH; if (hi > NN) hi = NN;
    int s = 0;
    for (int k = lo; k < hi; ++k) s += indeg[k];
    part[t] = s;
    __syncthreads();
    for (int off = 1; off < 1024; off <<= 1) {
        int v = (t >= off) ? part[t - off] : 0;
        __syncthreads();
        part[t] += v;
        __syncthreads();
    }
    int run = part[t] - s;                   // exclusive prefix
    for (int k = lo; k < hi; ++k) { offs[k] = run; run += indeg[k]; }
    if (t == 1023) offs[NN] = part[1023];
}

// ---------- 4) scatter reverse adjacency (src local index per dst) ----------
__global__ __launch_bounds__(256) void fill_rev_kernel(const u16* __restrict__ knn,
                                                       const int* __restrict__ offs,
                                                       int* __restrict__ cursor,
                                                       u16* __restrict__ rev) {
    if (threadIdx.x >= 250) return;
    int b = blockIdx.x;
    int i = 2 + blockIdx.y * 250 + threadIdx.x;
    if (i >= Ss) return;
    const u16* kp = knn + ((size_t)b * NSRC + (i - 2)) * 7;
#pragma unroll
    for (int k = 0; k < 7; ++k) {
        int d = kp[k];
        if (d >= 2) {
            int n = b * Ss + d;
            int p = atomicAdd(&cursor[n], 1);
            rev[offs[n] + p] = (u16)i;       // store local src index
        }
    }
}

// ---------- 5) embedding: x = inputs@Wc+bc + scor@Ws+bs, split hi/lo bf16 ----------
__global__ __launch_bounds__(256) void embed_kernel(const float* __restrict__ inputs,
                                                    const float* __restrict__ scor,
                                                    const float* __restrict__ Wc,
                                                    const float* __restrict__ bc,
                                                    const float* __restrict__ Ws,
                                                    const float* __restrict__ bs,
                                                    u16* __restrict__ xhi,
                                                    u16* __restrict__ xlo) {
    int gid = blockIdx.x * 256 + threadIdx.x;
    if (gid >= NN * Dd) return;
    int n = gid >> 7, c = gid & 127;
    float i0 = inputs[2 * n], i1 = inputs[2 * n + 1], sc = scor[n];
    float t1 = i0 * Wc[c] + i1 * Wc[Dd + c] + bc[c];
    float t2 = sc * Ws[c] + bs[c];
    float v = t1 + t2;
    u16 h, l;
    split2(v, h, l);
    xhi[gid] = h;
    xlo[gid] = l;
}

// ---------- 6) weight transpose + split ----------
__global__ void transp_split_kernel(const float* __restrict__ src,
                                    u16* __restrict__ dhi, u16* __restrict__ dlo,
                                    int R, int C) {
    int gid = blockIdx.x * 256 + threadIdx.x;
    if (gid >= R * C) return;
    int r = gid / C, c = gid - r * C;
    u16 h, l;
    split2(src[gid], h, l);
    dhi[c * R + r] = h;
    dlo[c * R + r] = l;
}

// ---------- 7) split-bf16 MFMA GEMM: C = A @ W, 3-MFMA scheme ----------
// grid: (Ncols/128, M/128) — col fastest so A-tile reuse is temporally adjacent.
__global__ __launch_bounds__(256) void gemm_kernel(const u16* __restrict__ Ahi,
                                                   const u16* __restrict__ Alo,
                                                   const u16* __restrict__ Whi,
                                                   const u16* __restrict__ Wlo,
                                                   float* __restrict__ C,
                                                   int K, int Ncols) {
    __shared__ __align__(16) u16 lAhi[128][64];
    __shared__ __align__(16) u16 lAlo[128][64];
    __shared__ __align__(16) u16 lWh[128][64];
    __shared__ __align__(16) u16 lWl[128][64];

    int row0 = blockIdx.y * 128;
    int col0 = blockIdx.x * 128;
    int tid = threadIdx.x;
    int lane = tid & 63, wid = tid >> 6;
    int wm = (wid >> 1) * 64, wn = (wid & 1) * 64;
    int lanelo = lane & 15, quad = lane >> 4;

    f32x4 acc[4][4] = {};

    int scb = tid & 7;          // col-block (8 bf16 each) 0..7
    int sr  = tid >> 3;         // 0..31

    for (int k0 = 0; k0 < K; k0 += 64) {
#pragma unroll
        for (int rr = 0; rr < 4; ++rr) {
            int r = sr + rr * 32;
            size_t gofs = (size_t)(row0 + r) * K + k0 + scb * 8;
            uint4 vh = *(const uint4*)(Ahi + gofs);
            uint4 vl = *(const uint4*)(Alo + gofs);
            int cc = (scb ^ (r & 7)) * 8;   // XOR swizzle
            *(uint4*)&lAhi[r][cc] = vh;
            *(uint4*)&lAlo[r][cc] = vl;
        }
#pragma unroll
        for (int rr = 0; rr < 4; ++rr) {
            int r = sr + rr * 32;
            size_t gofs = (size_t)(col0 + r) * K + k0 + scb * 8;
            uint4 vh = *(const uint4*)(Whi + gofs);
            uint4 vl = *(const uint4*)(Wlo + gofs);
            int cc = (scb ^ (r & 7)) * 8;
            *(uint4*)&lWh[r][cc] = vh;
            *(uint4*)&lWl[r][cc] = vl;
        }
        __syncthreads();

#pragma unroll
        for (int kk = 0; kk < 64; kk += 32) {
            short8 ah[4], al[4], bh[4], bl[4];
            int cbb = (kk >> 3) + quad;
#pragma unroll
            for (int mt = 0; mt < 4; ++mt) {
                int r = wm + mt * 16 + lanelo;
                int cc = (cbb ^ (r & 7)) * 8;
                ah[mt] = *(const short8*)&lAhi[r][cc];
                al[mt] = *(const short8*)&lAlo[r][cc];
            }
#pragma unroll
            for (int nt = 0; nt < 4; ++nt) {
                int r = wn + nt * 16 + lanelo;
                int cc = (cbb ^ (r & 7)) * 8;
                bh[nt] = *(const short8*)&lWh[r][cc];
                bl[nt] = *(const short8*)&lWl[r][cc];
            }
#pragma unroll
            for (int mt = 0; mt < 4; ++mt)
#pragma unroll
                for (int nt = 0; nt < 4; ++nt) {
                    acc[mt][nt] = __builtin_amdgcn_mfma_f32_16x16x32_bf16(
                        ah[mt], bh[nt], acc[mt][nt], 0, 0, 0);
                    acc[mt][nt] = __builtin_amdgcn_mfma_f32_16x16x32_bf16(
                        al[mt], bh[nt], acc[mt][nt], 0, 0, 0);
                    acc[mt][nt] = __builtin_amdgcn_mfma_f32_16x16x32_bf16(
                        ah[mt], bl[nt], acc[mt][nt], 0, 0, 0);
                }
        }
        __syncthreads();
    }

#pragma unroll
    for (int mt = 0; mt < 4; ++mt)
#pragma unroll
        for (int nt = 0; nt < 4; ++nt)
#pragma unroll
            for (int r = 0; r < 4; ++r) {
                int row = row0 + wm + mt * 16 + quad * 4 + r;
                int col = col0 + wn + nt * 16 + lanelo;
                C[(size_t)row * Ncols + col] = acc[mt][nt][r];
            }
}

// ---------- 7b) depot-1 batch sum: out[b][c] = sum_{j>=2} y[b,j,c]*dinv[b,j] ----------
__global__ __launch_bounds__(1024) void dep1_kernel(const float* __restrict__ y,
                                                    const float* __restrict__ dinv,
                                                    float* __restrict__ outb,
                                                    int M) {
    int b = blockIdx.x;
    int co = blockIdx.y * 128;
    int tid = threadIdx.x;
    int c4 = tid & 31;       // quad-channel 0..31 (128 channels)
    int es = tid >> 5;       // edge slot 0..31
    const float* yb = y + (size_t)b * Ss * M + co + c4 * 4;
    const float* dv = dinv + b * Ss;
    float a0 = 0.f, a1 = 0.f, a2 = 0.f, a3 = 0.f;
    for (int j = 2 + es; j < Ss; j += 32) {
        float w = dv[j];
        const float* p = yb + (size_t)j * M;
        float4 u = *(const float4*)p;
        a0 += u.x * w; a1 += u.y * w; a2 += u.z * w; a3 += u.w * w;
    }
    __shared__ float4 red[1024];
    float4 mv; mv.x = a0; mv.y = a1; mv.z = a2; mv.w = a3;
    red[tid] = mv;
    __syncthreads();
#pragma unroll
    for (int s = 16; s > 0; s >>= 1) {
        if (es < s) {
            float4 o = red[tid + (s << 5)];
            float4 m = red[tid];
            m.x += o.x; m.y += o.y; m.z += o.z; m.w += o.w;
            red[tid] = m;
        }
        __syncthreads();
    }
    if (es == 0) *(float4*)(outb + (size_t)b * M + co + c4 * 4) = red[c4];
}

// ---------- 8) aggregation M=512 + bias + relu -> split bf16 ----------
__global__ __launch_bounds__(128) void agg512_kernel(const float* __restrict__ y,
                                                     const float* __restrict__ dinv,
                                                     const int* __restrict__ offs,
                                                     const int* __restrict__ indeg,
                                                     const u16* __restrict__ rev,
                                                     const float* __restrict__ bias,
                                                     const float* __restrict__ dep1,
                                                     u16* __restrict__ oHi,
                                                     u16* __restrict__ oLo) {
    int bx = blockIdx.x;
    int x = bx & 7, q = bx >> 3;
    int bb = q / 1000;
    int i = q - bb * 1000;
    int b = x + (bb << 3);
    int n = b * Ss + i;
    int nb = n - i;
    int tid = threadIdx.x, c = tid * 4;

    __shared__ int   sidx[128];
    __shared__ float sw[128];
    int cnt = 0, o = 0;
    if (i >= 2) { cnt = indeg[n]; o = offs[n]; }
    int cl = cnt < 128 ? cnt : 128;
    if (tid < cl) {
        int s = rev[o + tid];
        sidx[tid] = s;
        sw[tid] = dinv[nb + s];
    }
    __syncthreads();

    float a0 = 0.f, a1 = 0.f, a2 = 0.f, a3 = 0.f;
    if (i >= 2) {
        float w = dinv[nb];  // == 1.0 (deg[0]=1)
        float4 v = *(const float4*)(y + (size_t)nb * 512 + c);
        a0 = v.x * w; a1 = v.y * w; a2 = v.z * w; a3 = v.w * w;
        int e = 0;
        for (; e + 4 <= cl; e += 4) {
            int s0 = sidx[e], s1 = sidx[e + 1], s2 = sidx[e + 2], s3 = sidx[e + 3];
            float w0 = sw[e], w1 = sw[e + 1], w2 = sw[e + 2], w3 = sw[e + 3];
            float4 u0 = *(const float4*)(y + (size_t)(nb + s0) * 512 + c);
            float4 u1 = *(const float4*)(y + (size_t)(nb + s1) * 512 + c);
            float4 u2 = *(const float4*)(y + (size_t)(nb + s2) * 512 + c);
            float4 u3 = *(const float4*)(y + (size_t)(nb + s3) * 512 + c);
            a0 += u0.x * w0 + u1.x * w1 + u2.x * w2 + u3.x * w3;
            a1 += u0.y * w0 + u1.y * w1 + u2.y * w2 + u3.y * w3;
            a2 += u0.z * w0 + u1.z * w1 + u2.z * w2 + u3.z * w3;
            a3 += u0.w * w0 + u1.w * w1 + u2.w * w2 + u3.w * w3;
        }
        for (; e < cl; ++e) {
            int s = sidx[e]; float ww = sw[e];
            float4 u = *(const float4*)(y + (size_t)(nb + s) * 512 + c);
            a0 += u.x * ww; a1 += u.y * ww; a2 += u.z * ww; a3 += u.w * ww;
        }
        for (int e2 = 128; e2 < cnt; ++e2) {   // safety fallback (never in practice)
            int s = rev[o + e2]; float ww = dinv[nb + s];
            float4 u = *(const float4*)(y + (size_t)(nb + s) * 512 + c);
            a0 += u.x * ww; a1 += u.y * ww; a2 += u.z * ww; a3 += u.w * ww;
        }
    } else if (i == 1) {
        float4 v = *(const float4*)(dep1 + (size_t)b * 512 + c);
        a0 = v.x; a1 = v.y; a2 = v.z; a3 = v.w;
    }
    float dn = dinv[n], sn = dn * dn;
    float4 vs = *(const float4*)(y + (size_t)n * 512 + c);
    float z0 = a0 * dn + vs.x * sn + bias[c];
    float z1 = a1 * dn + vs.y * sn + bias[c + 1];
    float z2 = a2 * dn + vs.z * sn + bias[c + 2];
    float z3 = a3 * dn + vs.w * sn + bias[c + 3];
    z0 = fmaxf(z0, 0.f); z1 = fmaxf(z1, 0.f); z2 = fmaxf(z2, 0.f); z3 = fmaxf(z3, 0.f);
    u16 h0, l0, h1, l1, h2, l2, h3, l3;
    split2(z0, h0, l0); split2(z1, h1, l1); split2(z2, h2, l2); split2(z3, h3, l3);
    ushort4 hv; hv.x = h0; hv.y = h1; hv.z = h2; hv.w = h3;
    ushort4 lv; lv.x = l0; lv.y = l1; lv.z = l2; lv.w = l3;
    *(ushort4*)(oHi + (size_t)n * 512 + c) = hv;
    *(ushort4*)(oLo + (size_t)n * 512 + c) = lv;
}

// ---------- 9) final aggregation M=128, no relu, fp32 out ----------
__global__ __launch_bounds__(128) void agg128f_kernel(const float* __restrict__ y,
                                                      const float* __restrict__ dinv,
                                                      const int* __restrict__ offs,
                                                      const int* __restrict__ indeg,
                                                      const u16* __restrict__ rev,
                                                      const float* __restrict__ bias,
                                                      const float* __restrict__ dep1,
                                                      float* __restrict__ out) {
    int bx = blockIdx.x;
    int x = bx & 7, q = bx >> 3;
    int bb = q / 1000;
    int i = q - bb * 1000;
    int b = x + (bb << 3);
    int n = b * Ss + i;
    int nb = n - i;
    int tid = threadIdx.x, c = tid;

    __shared__ int   sidx[128];
    __shared__ float sw[128];
    int cnt = 0, o = 0;
    if (i >= 2) { cnt = indeg[n]; o = offs[n]; }
    int cl = cnt < 128 ? cnt : 128;
    if (tid < cl) {
        int s = rev[o + tid];
        sidx[tid] = s;
        sw[tid] = dinv[nb + s];
    }
    __syncthreads();

    float a = 0.f;
    if (i >= 2) {
        a = y[(size_t)nb * 128 + c] * dinv[nb];
        int e = 0;
        for (; e + 4 <= cl; e += 4) {
            int s0 = sidx[e], s1 = sidx[e + 1], s2 = sidx[e + 2], s3 = sidx[e + 3];
            float w0 = sw[e], w1 = sw[e + 1], w2 = sw[e + 2], w3 = sw[e + 3];
            float u0 = y[(size_t)(nb + s0) * 128 + c];
            float u1 = y[(size_t)(nb + s1) * 128 + c];
            float u2 = y[(size_t)(nb + s2) * 128 + c];
            float u3 = y[(size_t)(nb + s3) * 128 + c];
            a += u0 * w0 + u1 * w1 + u2 * w2 + u3 * w3;
        }
        for (; e < cl; ++e) a += y[(size_t)(nb + sidx[e]) * 128 + c] * sw[e];
        for (int e2 = 128; e2 < cnt; ++e2) {
            int s = rev[o + e2];
            a += y[(size_t)(nb + s) * 128 + c] * dinv[nb + s];
        }
    } else if (i == 1) {
        a = dep1[(size_t)b * 128 + c];
    }
    float dn = dinv[n];
    out[(size_t)n * 128 + c] = a * dn + y[(size_t)n * 128 + c] * (dn * dn) + bias[c];
}

// ---------- workspace layout (bytes); total 266,528,768 ----------
constexpr size_t O_INDEG  = 0;                       // 256000
constexpr size_t O_CURSOR = 256000;                  // 256000; reused post-fill_rev:
constexpr size_t O_DEP1A  = 256000;                  //   64*512*4 = 131072
constexpr size_t O_DEP1B  = 387072;                  //   64*128*4 = 32768
constexpr size_t O_OFFS   = 512000;                  // 256016
constexpr size_t O_DINV   = 768256;                  // 256000
constexpr size_t O_KNN    = 1024256;                 // 893824
constexpr size_t O_REV    = 1918080;                 // 893824
constexpr size_t O_WT0H   = 2811904;                 // 131072
constexpr size_t O_WT0L   = 2942976;
constexpr size_t O_WT1H   = 3074048;                 // 524288
constexpr size_t O_WT1L   = 3598336;
constexpr size_t O_WT2H   = 4122624;                 // 131072
constexpr size_t O_WT2L   = 4253696;
constexpr size_t O_AHI    = 4384768;                 // 65536000
constexpr size_t O_ALO    = 69920768;                // 65536000
constexpr size_t O_Y      = 135456768;               // 131072000

extern "C" void kernel_launch(void* const* d_in, const int* in_sizes, int n_in,
                              void* d_out, int out_size, void* d_ws, size_t ws_size,
                              hipStream_t stream) {
    const float* inputs = (const float*)d_in[0];
    const float* scor   = (const float*)d_in[1];
    const float* Wc     = (const float*)d_in[2];
    const float* bc     = (const float*)d_in[3];
    const float* Ws     = (const float*)d_in[4];
    const float* bs     = (const float*)d_in[5];
    const float* W0     = (const float*)d_in[6];
    const float* b0     = (const float*)d_in[7];
    const float* W1     = (const float*)d_in[8];
    const float* b1     = (const float*)d_in[9];
    const float* W2     = (const float*)d_in[10];
    const float* b2     = (const float*)d_in[11];

    char* w = (char*)d_ws;
    int*   indeg  = (int*)(w + O_INDEG);
    int*   cursor = (int*)(w + O_CURSOR);
    float* dep1a  = (float*)(w + O_DEP1A);
    float* dep1b  = (float*)(w + O_DEP1B);
    int*   offs   = (int*)(w + O_OFFS);
    float* dinv   = (float*)(w + O_DINV);
    u16*   knn    = (u16*)(w + O_KNN);
    u16*   rev    = (u16*)(w + O_REV);
    u16*   wt0h   = (u16*)(w + O_WT0H);
    u16*   wt0l   = (u16*)(w + O_WT0L);
    u16*   wt1h   = (u16*)(w + O_WT1H);
    u16*   wt1l   = (u16*)(w + O_WT1L);
    u16*   wt2h   = (u16*)(w + O_WT2H);
    u16*   wt2l   = (u16*)(w + O_WT2L);
    u16*   ahi    = (u16*)(w + O_AHI);
    u16*   alo    = (u16*)(w + O_ALO);
    float* y      = (float*)(w + O_Y);

    hipMemsetAsync(w + O_INDEG, 0, 512000, stream);  // indeg + cursor

    knn_kernel<<<dim3(Bb, 16), 256, 0, stream>>>(inputs, knn, indeg);
    deg_dinv_kernel<<<250, 256, 0, stream>>>(indeg, dinv);
    scan_kernel<<<1, 1024, 0, stream>>>(indeg, offs);
    fill_rev_kernel<<<dim3(Bb, 4), 256, 0, stream>>>(knn, offs, cursor, rev);

    embed_kernel<<<NN * Dd / 256, 256, 0, stream>>>(inputs, scor, Wc, bc, Ws, bs, ahi, alo);

    transp_split_kernel<<<(Dd * Hh + 255) / 256, 256, 0, stream>>>(W0, wt0h, wt0l, Dd, Hh);
    transp_split_kernel<<<(Hh * Hh + 255) / 256, 256, 0, stream>>>(W1, wt1h, wt1l, Hh, Hh);
    transp_split_kernel<<<(Hh * Dd + 255) / 256, 256, 0, stream>>>(W2, wt2h, wt2l, Hh, Dd);

    // layer 0: [N,128] @ [128,512]
    gemm_kernel<<<dim3(Hh / 128, NN / 128), 256, 0, stream>>>(ahi, alo, wt0h, wt0l, y, Dd, Hh);
    dep1_kernel<<<dim3(Bb, 4), 1024, 0, stream>>>(y, dinv, dep1a, Hh);
    agg512_kernel<<<NN, 128, 0, stream>>>(y, dinv, offs, indeg, rev, b0, dep1a, ahi, alo);
    // layer 1: [N,512] @ [512,512]
    gemm_kernel<<<dim3(Hh / 128, NN / 128), 256, 0, stream>>>(ahi, alo, wt1h, wt1l, y, Hh, Hh);
    dep1_kernel<<<dim3(Bb, 4), 1024, 0, stream>>>(y, dinv, dep1a, Hh);
    agg512_kernel<<<NN, 128, 0, stream>>>(y, dinv, offs, indeg, rev, b1, dep1a, ahi, alo);
    // layer 2: [N,512] @ [512,128]
    gemm_kernel<<<dim3(Dd / 128, NN / 128), 256, 0, stream>>>(ahi, alo, wt2h, wt2l, y, Hh, Dd);
    dep1_kernel<<<dim3(Bb, 1), 1024, 0, stream>>>(y, dinv, dep1b, Dd);
    agg128f_kernel<<<NN, 128, 0, stream>>>(y, dinv, offs, indeg, rev, b2, dep1b, (float*)d_out);
}

// Round 6
// 628.693 us; speedup vs baseline: 2.2317x; 1.1099x over previous
//
#include <hip/hip_runtime.h>

typedef unsigned short u16;
typedef unsigned int u32;
typedef unsigned long long u64;
using short8 = __attribute__((ext_vector_type(8))) short;
using f32x4  = __attribute__((ext_vector_type(4))) float;

constexpr int Bb = 64, Ss = 1000, Dd = 128, Hh = 512;
constexpr int NN = Bb * Ss;           // 64000 nodes
constexpr int NSRC = Ss - 2;          // 998 kNN source nodes per batch

// ---------- helpers ----------
__device__ __forceinline__ float bf2f(u16 h) {
    u32 u = ((u32)h) << 16;
    return __builtin_bit_cast(float, u);
}
__device__ __forceinline__ u16 f2bf(float v) {  // RNE, finite inputs only
    u32 u = __builtin_bit_cast(u32, v);
    u32 r = (u + 0x7FFFu + ((u >> 16) & 1u)) >> 16;
    return (u16)r;
}
__device__ __forceinline__ void split2(float v, u16& h, u16& l) {
    h = f2bf(v);
    float fh = bf2f(h);
    l = f2bf(v - fh);
}

// ---------- 1) kNN: two-phase, branchless d^2 chain + exact (d,j) re-rank ----------
__global__ __launch_bounds__(256) void knn_kernel(const float* __restrict__ inputs,
                                                  u16* __restrict__ knn,
                                                  int* __restrict__ indeg) {
    __shared__ float2 pts[Ss];
    __shared__ float  mg[64][28];
    __shared__ u64    lst[64][24];
    __shared__ int    cnt[64];
    __shared__ float  t2max[64];

    int b = blockIdx.x;
    const float* base = inputs + (size_t)b * Ss * 2;
    for (int t = threadIdx.x; t < Ss; t += 256) {
        float2 p;
        p.x = base[2 * t];
        p.y = base[2 * t + 1];
        pts[t] = p;
    }
    __syncthreads();

    int tid = threadIdx.x;
    int ln = tid >> 2;                  // local node 0..63
    int part = tid & 3;                 // candidate quarter 0..3
    int i = 2 + blockIdx.y * 64 + ln;
    bool valid = (i < Ss);
    int j0 = part * 250, j1 = j0 + 250;
    float xi = 0.f, yi = 0.f;
    if (valid) { xi = pts[i].x; yi = pts[i].y; }
    const float INF = __builtin_inff();

    // ---- phase 1: branchless sorted-7 chain on d^2 ----
    if (valid) {
        float bd[7];
#pragma unroll
        for (int k = 0; k < 7; ++k) bd[k] = INF;
        for (int j = j0; j < j1; ++j) {
            float2 p = pts[j];
            float dx = __fsub_rn(xi, p.x);            // exact fp32 RN mirror
            float dy = __fsub_rn(yi, p.y);
            float d2 = __fadd_rn(__fmul_rn(dx, dx), __fmul_rn(dy, dy));
            d2 = (j == i) ? INF : d2;                 // exclude self
            float v = d2;
#pragma unroll
            for (int k = 0; k < 7; ++k) {             // insert, eject old max
                float lo = fminf(v, bd[k]);
                float hi = fmaxf(v, bd[k]);
                bd[k] = lo;
                v = hi;
            }
        }
#pragma unroll
        for (int k = 0; k < 7; ++k) mg[ln][part * 7 + k] = bd[k];
    }
    __syncthreads();

    // ---- merge 28 -> tau2; derive T2max; reset count ----
    if (part == 0 && valid) {
        float m[7];
#pragma unroll
        for (int k = 0; k < 7; ++k) m[k] = INF;
        for (int t = 0; t < 28; ++t) {
            float v = mg[ln][t];
#pragma unroll
            for (int k = 0; k < 7; ++k) {
                float lo = fminf(v, m[k]);
                float hi = fmaxf(v, m[k]);
                m[k] = lo;
                v = hi;
            }
        }
        float tau2 = m[6];
        float tau = __fsqrt_rn(tau2);
        float g = tau2;                                // sqrt_rn(g) == tau by construction
        for (int it = 0; it < 8; ++it) {               // widen to sqrt-collision boundary
            float gn = __builtin_bit_cast(float, __builtin_bit_cast(u32, g) + 1u);
            if (__fsqrt_rn(gn) <= tau) g = gn; else break;
        }
        t2max[ln] = g;
        cnt[ln] = 0;
    }
    __syncthreads();

    // ---- phase 2: threshold rescan, collect (d, j) keys ----
    if (valid) {
        float T = t2max[ln];
        for (int j = j0; j < j1; ++j) {
            float2 p = pts[j];
            float dx = __fsub_rn(xi, p.x);
            float dy = __fsub_rn(yi, p.y);
            float d2 = __fadd_rn(__fmul_rn(dx, dx), __fmul_rn(dy, dy));
            d2 = (j == i) ? INF : d2;
            if (d2 <= T) {
                float d = __fsqrt_rn(d2);
                u64 key = (((u64)__builtin_bit_cast(u32, d)) << 32) | (u32)j;
                int p2 = atomicAdd(&cnt[ln], 1);
                if (p2 < 24) lst[ln][p2] = key;
            }
        }
    }
    __syncthreads();

    // ---- final: select 7 smallest (d, j) keys -> knn + indeg ----
    if (part == 0 && valid) {
        int c = cnt[ln]; if (c > 24) c = 24;           // c >= 7 by construction
        u16* kp = knn + ((size_t)b * NSRC + (i - 2)) * 7;
#pragma unroll
        for (int k = 0; k < 7; ++k) {
            u64 best = ~0ULL; int bp = -1;
            for (int t = 0; t < c; ++t) {
                u64 v = lst[ln][t];
                if (v < best) { best = v; bp = t; }
            }
            int j = 0;
            if (bp >= 0) { lst[ln][bp] = ~0ULL; j = (int)(u32)best; }
            kp[k] = (u16)j;
            if (j >= 2) atomicAdd(&indeg[b * Ss + j], 1);
        }
    }
}

// ---------- 2) degree -> dinv ----------
__global__ void deg_dinv_kernel(const int* __restrict__ indeg, float* __restrict__ dinv) {
    int n = blockIdx.x * 256 + threadIdx.x;
    if (n >= NN) return;
    int i = n % Ss;
    float deg = (i == 0) ? 1.0f : (i == 1) ? (float)(Ss - 1) : (float)(indeg[n] + 2);
    dinv[n] = 1.0f / __fsqrt_rn(deg);
}

// ---------- 3) exclusive scan of indeg -> CSR offsets (single block) ----------
__global__ __launch_bounds__(1024) void scan_kernel(const int* __restrict__ indeg,
                                                    int* __restrict__ offs) {
    __shared__ int part[1024];
    int t = threadIdx.x;
    const int CH = 63;                       // 1024*63 >= 64000
    int lo = t * CH;
    int hi = lo + CH; if (hi > NN) hi = NN;
    int s = 0;
    for (int k = lo; k < hi; ++k) s += indeg[k];
    part[t] = s;
    __syncthreads();
    for (int off = 1; off < 1024; off <<= 1) {
        int v = (t >= off) ? part[t - off] : 0;
        __syncthreads();
        part[t] += v;
        __syncthreads();
    }
    int run = part[t] - s;                   // exclusive prefix
    for (int k = lo; k < hi; ++k) { offs[k] = run; run += indeg[k]; }
    if (t == 1023) offs[NN] = part[1023];
}

// ---------- 4) scatter reverse adjacency (src local index per dst) ----------
__global__ __launch_bounds__(256) void fill_rev_kernel(const u16* __restrict__ knn,
                                                       const int* __restrict__ offs,
                                                       int* __restrict__ cursor,
                                                       u16* __restrict__ rev) {
    if (threadIdx.x >= 250) return;
    int b = blockIdx.x;
    int i = 2 + blockIdx.y * 250 + threadIdx.x;
    if (i >= Ss) return;
    const u16* kp = knn + ((size_t)b * NSRC + (i - 2)) * 7;
#pragma unroll
    for (int k = 0; k < 7; ++k) {
        int d = kp[k];
        if (d >= 2) {
            int n = b * Ss + d;
            int p = atomicAdd(&cursor[n], 1);
            rev[offs[n] + p] = (u16)i;       // store local src index
        }
    }
}

// ---------- 5) embedding: x = inputs@Wc+bc + scor@Ws+bs -> single bf16 ----------
__global__ __launch_bounds__(256) void embed_kernel(const float* __restrict__ inputs,
                                                    const float* __restrict__ scor,
                                                    const float* __restrict__ Wc,
                                                    const float* __restrict__ bc,
                                                    const float* __restrict__ Ws,
                                                    const float* __restrict__ bs,
                                                    u16* __restrict__ xbf) {
    int gid = blockIdx.x * 256 + threadIdx.x;
    if (gid >= NN * Dd) return;
    int n = gid >> 7, c = gid & 127;
    float i0 = inputs[2 * n], i1 = inputs[2 * n + 1], sc = scor[n];
    float t1 = i0 * Wc[c] + i1 * Wc[Dd + c] + bc[c];
    float t2 = sc * Ws[c] + bs[c];
    xbf[gid] = f2bf(t1 + t2);
}

// ---------- 6) weight transpose + split (weights stay hi+lo) ----------
__global__ void transp_split_kernel(const float* __restrict__ src,
                                    u16* __restrict__ dhi, u16* __restrict__ dlo,
                                    int R, int C) {
    int gid = blockIdx.x * 256 + threadIdx.x;
    if (gid >= R * C) return;
    int r = gid / C, c = gid - r * C;
    u16 h, l;
    split2(src[gid], h, l);
    dhi[c * R + r] = h;
    dlo[c * R + r] = l;
}

// ---------- 7) MFMA GEMM: C = A(bf16) @ (Whi+Wlo), 2-MFMA scheme ----------
// LDS 48 KB -> 3 blocks/CU. grid: (Ncols/128, M/128).
__global__ __launch_bounds__(256) void gemm_kernel(const u16* __restrict__ A,
                                                   const u16* __restrict__ Whi,
                                                   const u16* __restrict__ Wlo,
                                                   float* __restrict__ C,
                                                   int K, int Ncols) {
    __shared__ __align__(16) u16 lA[128][64];
    __shared__ __align__(16) u16 lWh[128][64];
    __shared__ __align__(16) u16 lWl[128][64];

    int row0 = blockIdx.y * 128;
    int col0 = blockIdx.x * 128;
    int tid = threadIdx.x;
    int lane = tid & 63, wid = tid >> 6;
    int wm = (wid >> 1) * 64, wn = (wid & 1) * 64;
    int lanelo = lane & 15, quad = lane >> 4;

    f32x4 acc[4][4] = {};

    int scb = tid & 7;          // col-block (8 bf16 each) 0..7
    int sr  = tid >> 3;         // 0..31

    for (int k0 = 0; k0 < K; k0 += 64) {
#pragma unroll
        for (int rr = 0; rr < 4; ++rr) {
            int r = sr + rr * 32;
            uint4 va = *(const uint4*)(A + (size_t)(row0 + r) * K + k0 + scb * 8);
            *(uint4*)&lA[r][(scb ^ (r & 7)) * 8] = va;   // XOR swizzle
        }
#pragma unroll
        for (int rr = 0; rr < 4; ++rr) {
            int r = sr + rr * 32;
            size_t gofs = (size_t)(col0 + r) * K + k0 + scb * 8;
            uint4 vh = *(const uint4*)(Whi + gofs);
            uint4 vl = *(const uint4*)(Wlo + gofs);
            int cc = (scb ^ (r & 7)) * 8;
            *(uint4*)&lWh[r][cc] = vh;
            *(uint4*)&lWl[r][cc] = vl;
        }
        __syncthreads();

#pragma unroll
        for (int kk = 0; kk < 64; kk += 32) {
            short8 af[4], bh[4], bl[4];
            int cbb = (kk >> 3) + quad;
#pragma unroll
            for (int mt = 0; mt < 4; ++mt) {
                int r = wm + mt * 16 + lanelo;
                af[mt] = *(const short8*)&lA[r][((cbb ^ (r & 7))) * 8];
            }
#pragma unroll
            for (int nt = 0; nt < 4; ++nt) {
                int r = wn + nt * 16 + lanelo;
                int cc = (cbb ^ (r & 7)) * 8;
                bh[nt] = *(const short8*)&lWh[r][cc];
                bl[nt] = *(const short8*)&lWl[r][cc];
            }
#pragma unroll
            for (int mt = 0; mt < 4; ++mt)
#pragma unroll
                for (int nt = 0; nt < 4; ++nt) {
                    acc[mt][nt] = __builtin_amdgcn_mfma_f32_16x16x32_bf16(
                        af[mt], bh[nt], acc[mt][nt], 0, 0, 0);
                    acc[mt][nt] = __builtin_amdgcn_mfma_f32_16x16x32_bf16(
                        af[mt], bl[nt], acc[mt][nt], 0, 0, 0);
                }
        }
        __syncthreads();
    }

#pragma unroll
    for (int mt = 0; mt < 4; ++mt)
#pragma unroll
        for (int nt = 0; nt < 4; ++nt)
#pragma unroll
            for (int r = 0; r < 4; ++r) {
                int row = row0 + wm + mt * 16 + quad * 4 + r;
                int col = col0 + wn + nt * 16 + lanelo;
                C[(size_t)row * Ncols + col] = acc[mt][nt][r];
            }
}

// ---------- 7b) depot-1 batch sum: out[b][c] = sum_{j>=2} y[b,j,c]*dinv[b,j] ----------
__global__ __launch_bounds__(1024) void dep1_kernel(const float* __restrict__ y,
                                                    const float* __restrict__ dinv,
                                                    float* __restrict__ outb,
                                                    int M) {
    int b = blockIdx.x;
    int co = blockIdx.y * 128;
    int tid = threadIdx.x;
    int c4 = tid & 31;       // quad-channel 0..31 (128 channels)
    int es = tid >> 5;       // edge slot 0..31
    const float* yb = y + (size_t)b * Ss * M + co + c4 * 4;
    const float* dv = dinv + b * Ss;
    float a0 = 0.f, a1 = 0.f, a2 = 0.f, a3 = 0.f;
    for (int j = 2 + es; j < Ss; j += 32) {
        float w = dv[j];
        const float* p = yb + (size_t)j * M;
        float4 u = *(const float4*)p;
        a0 += u.x * w; a1 += u.y * w; a2 += u.z * w; a3 += u.w * w;
    }
    __shared__ float4 red[1024];
    float4 mv; mv.x = a0; mv.y = a1; mv.z = a2; mv.w = a3;
    red[tid] = mv;
    __syncthreads();
#pragma unroll
    for (int s = 16; s > 0; s >>= 1) {
        if (es < s) {
            float4 o = red[tid + (s << 5)];
            float4 m = red[tid];
            m.x += o.x; m.y += o.y; m.z += o.z; m.w += o.w;
            red[tid] = m;
        }
        __syncthreads();
    }
    if (es == 0) *(float4*)(outb + (size_t)b * M + co + c4 * 4) = red[c4];
}

// ---------- 8) aggregation M=512 + bias + relu -> single bf16 ----------
__global__ __launch_bounds__(128) void agg512_kernel(const float* __restrict__ y,
                                                     const float* __restrict__ dinv,
                                                     const int* __restrict__ offs,
                                                     const int* __restrict__ indeg,
                                                     const u16* __restrict__ rev,
                                                     const float* __restrict__ bias,
                                                     const float* __restrict__ dep1,
                                                     u16* __restrict__ oX) {
    int bx = blockIdx.x;
    int x = bx & 7, q = bx >> 3;
    int bb = q / 1000;
    int i = q - bb * 1000;
    int b = x + (bb << 3);
    int n = b * Ss + i;
    int nb = n - i;
    int tid = threadIdx.x, c = tid * 4;

    __shared__ int   sidx[128];
    __shared__ float sw[128];
    int cnt = 0, o = 0;
    if (i >= 2) { cnt = indeg[n]; o = offs[n]; }
    int cl = cnt < 128 ? cnt : 128;
    if (tid < cl) {
        int s = rev[o + tid];
        sidx[tid] = s;
        sw[tid] = dinv[nb + s];
    }
    __syncthreads();

    float a0 = 0.f, a1 = 0.f, a2 = 0.f, a3 = 0.f;
    if (i >= 2) {
        float w = dinv[nb];  // == 1.0 (deg[0]=1)
        float4 v = *(const float4*)(y + (size_t)nb * 512 + c);
        a0 = v.x * w; a1 = v.y * w; a2 = v.z * w; a3 = v.w * w;
        int e = 0;
        for (; e + 4 <= cl; e += 4) {
            int s0 = sidx[e], s1 = sidx[e + 1], s2 = sidx[e + 2], s3 = sidx[e + 3];
            float w0 = sw[e], w1 = sw[e + 1], w2 = sw[e + 2], w3 = sw[e + 3];
            float4 u0 = *(const float4*)(y + (size_t)(nb + s0) * 512 + c);
            float4 u1 = *(const float4*)(y + (size_t)(nb + s1) * 512 + c);
            float4 u2 = *(const float4*)(y + (size_t)(nb + s2) * 512 + c);
            float4 u3 = *(const float4*)(y + (size_t)(nb + s3) * 512 + c);
            a0 += u0.x * w0 + u1.x * w1 + u2.x * w2 + u3.x * w3;
            a1 += u0.y * w0 + u1.y * w1 + u2.y * w2 + u3.y * w3;
            a2 += u0.z * w0 + u1.z * w1 + u2.z * w2 + u3.z * w3;
            a3 += u0.w * w0 + u1.w * w1 + u2.w * w2 + u3.w * w3;
        }
        for (; e < cl; ++e) {
            int s = sidx[e]; float ww = sw[e];
            float4 u = *(const float4*)(y + (size_t)(nb + s) * 512 + c);
            a0 += u.x * ww; a1 += u.y * ww; a2 += u.z * ww; a3 += u.w * ww;
        }
        for (int e2 = 128; e2 < cnt; ++e2) {   // safety fallback (never in practice)
            int s = rev[o + e2]; float ww = dinv[nb + s];
            float4 u = *(const float4*)(y + (size_t)(nb + s) * 512 + c);
            a0 += u.x * ww; a1 += u.y * ww; a2 += u.z * ww; a3 += u.w * ww;
        }
    } else if (i == 1) {
        float4 v = *(const float4*)(dep1 + (size_t)b * 512 + c);
        a0 = v.x; a1 = v.y; a2 = v.z; a3 = v.w;
    }
    float dn = dinv[n], sn = dn * dn;
    float4 vs = *(const float4*)(y + (size_t)n * 512 + c);
    float z0 = a0 * dn + vs.x * sn + bias[c];
    float z1 = a1 * dn + vs.y * sn + bias[c + 1];
    float z2 = a2 * dn + vs.z * sn + bias[c + 2];
    float z3 = a3 * dn + vs.w * sn + bias[c + 3];
    ushort4 hv;
    hv.x = f2bf(fmaxf(z0, 0.f));
    hv.y = f2bf(fmaxf(z1, 0.f));
    hv.z = f2bf(fmaxf(z2, 0.f));
    hv.w = f2bf(fmaxf(z3, 0.f));
    *(ushort4*)(oX + (size_t)n * 512 + c) = hv;
}

// ---------- 9) final aggregation M=128, no relu, fp32 out ----------
__global__ __launch_bounds__(128) void agg128f_kernel(const float* __restrict__ y,
                                                      const float* __restrict__ dinv,
                                                      const int* __restrict__ offs,
                                                      const int* __restrict__ indeg,
                                                      const u16* __restrict__ rev,
                                                      const float* __restrict__ bias,
                                                      const float* __restrict__ dep1,
                                                      float* __restrict__ out) {
    int bx = blockIdx.x;
    int x = bx & 7, q = bx >> 3;
    int bb = q / 1000;
    int i = q - bb * 1000;
    int b = x + (bb << 3);
    int n = b * Ss + i;
    int nb = n - i;
    int tid = threadIdx.x, c = tid;

    __shared__ int   sidx[128];
    __shared__ float sw[128];
    int cnt = 0, o = 0;
    if (i >= 2) { cnt = indeg[n]; o = offs[n]; }
    int cl = cnt < 128 ? cnt : 128;
    if (tid < cl) {
        int s = rev[o + tid];
        sidx[tid] = s;
        sw[tid] = dinv[nb + s];
    }
    __syncthreads();

    float a = 0.f;
    if (i >= 2) {
        a = y[(size_t)nb * 128 + c] * dinv[nb];
        int e = 0;
        for (; e + 4 <= cl; e += 4) {
            int s0 = sidx[e], s1 = sidx[e + 1], s2 = sidx[e + 2], s3 = sidx[e + 3];
            float w0 = sw[e], w1 = sw[e + 1], w2 = sw[e + 2], w3 = sw[e + 3];
            float u0 = y[(size_t)(nb + s0) * 128 + c];
            float u1 = y[(size_t)(nb + s1) * 128 + c];
            float u2 = y[(size_t)(nb + s2) * 128 + c];
            float u3 = y[(size_t)(nb + s3) * 128 + c];
            a += u0 * w0 + u1 * w1 + u2 * w2 + u3 * w3;
        }
        for (; e < cl; ++e) a += y[(size_t)(nb + sidx[e]) * 128 + c] * sw[e];
        for (int e2 = 128; e2 < cnt; ++e2) {
            int s = rev[o + e2];
            a += y[(size_t)(nb + s) * 128 + c] * dinv[nb + s];
        }
    } else if (i == 1) {
        a = dep1[(size_t)b * 128 + c];
    }
    float dn = dinv[n];
    out[(size_t)n * 128 + c] = a * dn + y[(size_t)n * 128 + c] * (dn * dn) + bias[c];
}

// ---------- workspace layout (bytes); unchanged footprint, O_ALO now unused ----------
constexpr size_t O_INDEG  = 0;                       // 256000
constexpr size_t O_CURSOR = 256000;                  // 256000; reused post-fill_rev:
constexpr size_t O_DEP1A  = 256000;                  //   64*512*4 = 131072
constexpr size_t O_DEP1B  = 387072;                  //   64*128*4 = 32768
constexpr size_t O_OFFS   = 512000;                  // 256016
constexpr size_t O_DINV   = 768256;                  // 256000
constexpr size_t O_KNN    = 1024256;                 // 893824
constexpr size_t O_REV    = 1918080;                 // 893824
constexpr size_t O_WT0H   = 2811904;                 // 131072
constexpr size_t O_WT0L   = 2942976;
constexpr size_t O_WT1H   = 3074048;                 // 524288
constexpr size_t O_WT1L   = 3598336;
constexpr size_t O_WT2H   = 4122624;                 // 131072
constexpr size_t O_WT2L   = 4253696;
constexpr size_t O_X      = 4384768;                 // 64000*512*2 = 65536000 (bf16 acts)
constexpr size_t O_Y      = 135456768;               // 131072000

extern "C" void kernel_launch(void* const* d_in, const int* in_sizes, int n_in,
                              void* d_out, int out_size, void* d_ws, size_t ws_size,
                              hipStream_t stream) {
    const float* inputs = (const float*)d_in[0];
    const float* scor   = (const float*)d_in[1];
    const float* Wc     = (const float*)d_in[2];
    const float* bc     = (const float*)d_in[3];
    const float* Ws     = (const float*)d_in[4];
    const float* bs     = (const float*)d_in[5];
    const float* W0     = (const float*)d_in[6];
    const float* b0     = (const float*)d_in[7];
    const float* W1     = (const float*)d_in[8];
    const float* b1     = (const float*)d_in[9];
    const float* W2     = (const float*)d_in[10];
    const float* b2     = (const float*)d_in[11];

    char* w = (char*)d_ws;
    int*   indeg  = (int*)(w + O_INDEG);
    int*   cursor = (int*)(w + O_CURSOR);
    float* dep1a  = (float*)(w + O_DEP1A);
    float* dep1b  = (float*)(w + O_DEP1B);
    int*   offs   = (int*)(w + O_OFFS);
    float* dinv   = (float*)(w + O_DINV);
    u16*   knn    = (u16*)(w + O_KNN);
    u16*   rev    = (u16*)(w + O_REV);
    u16*   wt0h   = (u16*)(w + O_WT0H);
    u16*   wt0l   = (u16*)(w + O_WT0L);
    u16*   wt1h   = (u16*)(w + O_WT1H);
    u16*   wt1l   = (u16*)(w + O_WT1L);
    u16*   wt2h   = (u16*)(w + O_WT2H);
    u16*   wt2l   = (u16*)(w + O_WT2L);
    u16*   xbf    = (u16*)(w + O_X);
    float* y      = (float*)(w + O_Y);

    hipMemsetAsync(w + O_INDEG, 0, 512000, stream);  // indeg + cursor

    knn_kernel<<<dim3(Bb, 16), 256, 0, stream>>>(inputs, knn, indeg);
    deg_dinv_kernel<<<250, 256, 0, stream>>>(indeg, dinv);
    scan_kernel<<<1, 1024, 0, stream>>>(indeg, offs);
    fill_rev_kernel<<<dim3(Bb, 4), 256, 0, stream>>>(knn, offs, cursor, rev);

    embed_kernel<<<NN * Dd / 256, 256, 0, stream>>>(inputs, scor, Wc, bc, Ws, bs, xbf);

    transp_split_kernel<<<(Dd * Hh + 255) / 256, 256, 0, stream>>>(W0, wt0h, wt0l, Dd, Hh);
    transp_split_kernel<<<(Hh * Hh + 255) / 256, 256, 0, stream>>>(W1, wt1h, wt1l, Hh, Hh);
    transp_split_kernel<<<(Hh * Dd + 255) / 256, 256, 0, stream>>>(W2, wt2h, wt2l, Hh, Dd);

    // layer 0: [N,128] @ [128,512]
    gemm_kernel<<<dim3(Hh / 128, NN / 128), 256, 0, stream>>>(xbf, wt0h, wt0l, y, Dd, Hh);
    dep1_kernel<<<dim3(Bb, 4), 1024, 0, stream>>>(y, dinv, dep1a, Hh);
    agg512_kernel<<<NN, 128, 0, stream>>>(y, dinv, offs, indeg, rev, b0, dep1a, xbf);
    // layer 1: [N,512] @ [512,512]
    gemm_kernel<<<dim3(Hh / 128, NN / 128), 256, 0, stream>>>(xbf, wt1h, wt1l, y, Hh, Hh);
    dep1_kernel<<<dim3(Bb, 4), 1024, 0, stream>>>(y, dinv, dep1a, Hh);
    agg512_kernel<<<NN, 128, 0, stream>>>(y, dinv, offs, indeg, rev, b1, dep1a, xbf);
    // layer 2: [N,512] @ [512,128]
    gemm_kernel<<<dim3(Dd / 128, NN / 128), 256, 0, stream>>>(xbf, wt2h, wt2l, y, Hh, Dd);
    dep1_kernel<<<dim3(Bb, 1), 1024, 0, stream>>>(y, dinv, dep1b, Dd);
    agg128f_kernel<<<NN, 128, 0, stream>>>(y, dinv, offs, indeg, rev, b2, dep1b, (float*)d_out);
}

// Round 7
// 544.422 us; speedup vs baseline: 2.5772x; 1.1548x over previous
//
#include <hip/hip_runtime.h>

typedef unsigned short u16;
typedef unsigned int u32;
typedef unsigned long long u64;
using short8 = __attribute__((ext_vector_type(8))) short;
using f32x4  = __attribute__((ext_vector_type(4))) float;

constexpr int Bb = 64, Ss = 1000, Dd = 128, Hh = 512;
constexpr int NN = Bb * Ss;           // 64000 nodes
constexpr int NSRC = Ss - 2;          // 998 kNN source nodes per batch

// ---------- helpers ----------
__device__ __forceinline__ float bf2f(u16 h) {
    u32 u = ((u32)h) << 16;
    return __builtin_bit_cast(float, u);
}
__device__ __forceinline__ u16 f2bf(float v) {  // RNE, finite inputs only
    u32 u = __builtin_bit_cast(u32, v);
    u32 r = (u + 0x7FFFu + ((u >> 16) & 1u)) >> 16;
    return (u16)r;
}
__device__ __forceinline__ void split2(float v, u16& h, u16& l) {
    h = f2bf(v);
    float fh = bf2f(h);
    l = f2bf(v - fh);
}

// ---------- 1) kNN: two-phase, branchless d^2 chain + exact (d,j) re-rank ----------
__global__ __launch_bounds__(256) void knn_kernel(const float* __restrict__ inputs,
                                                  u16* __restrict__ knn,
                                                  int* __restrict__ indeg) {
    __shared__ float2 pts[Ss];
    __shared__ float  mg[64][28];
    __shared__ u64    lst[64][24];
    __shared__ int    cnt[64];
    __shared__ float  t2max[64];

    int b = blockIdx.x;
    const float* base = inputs + (size_t)b * Ss * 2;
    for (int t = threadIdx.x; t < Ss; t += 256) {
        float2 p;
        p.x = base[2 * t];
        p.y = base[2 * t + 1];
        pts[t] = p;
    }
    __syncthreads();

    int tid = threadIdx.x;
    int ln = tid >> 2;                  // local node 0..63
    int part = tid & 3;                 // candidate quarter 0..3
    int i = 2 + blockIdx.y * 64 + ln;
    bool valid = (i < Ss);
    int j0 = part * 250, j1 = j0 + 250;
    float xi = 0.f, yi = 0.f;
    if (valid) { xi = pts[i].x; yi = pts[i].y; }
    const float INF = __builtin_inff();

    // ---- phase 1: branchless sorted-7 chain on d^2 ----
    if (valid) {
        float bd[7];
#pragma unroll
        for (int k = 0; k < 7; ++k) bd[k] = INF;
        for (int j = j0; j < j1; ++j) {
            float2 p = pts[j];
            float dx = __fsub_rn(xi, p.x);            // exact fp32 RN mirror
            float dy = __fsub_rn(yi, p.y);
            float d2 = __fadd_rn(__fmul_rn(dx, dx), __fmul_rn(dy, dy));
            d2 = (j == i) ? INF : d2;                 // exclude self
            float v = d2;
#pragma unroll
            for (int k = 0; k < 7; ++k) {             // insert, eject old max
                float lo = fminf(v, bd[k]);
                float hi = fmaxf(v, bd[k]);
                bd[k] = lo;
                v = hi;
            }
        }
#pragma unroll
        for (int k = 0; k < 7; ++k) mg[ln][part * 7 + k] = bd[k];
    }
    __syncthreads();

    // ---- merge 28 -> tau2; derive T2max; reset count ----
    if (part == 0 && valid) {
        float m[7];
#pragma unroll
        for (int k = 0; k < 7; ++k) m[k] = INF;
        for (int t = 0; t < 28; ++t) {
            float v = mg[ln][t];
#pragma unroll
            for (int k = 0; k < 7; ++k) {
                float lo = fminf(v, m[k]);
                float hi = fmaxf(v, m[k]);
                m[k] = lo;
                v = hi;
            }
        }
        float tau2 = m[6];
        float tau = __fsqrt_rn(tau2);
        float g = tau2;                                // sqrt_rn(g) == tau by construction
        for (int it = 0; it < 8; ++it) {               // widen to sqrt-collision boundary
            float gn = __builtin_bit_cast(float, __builtin_bit_cast(u32, g) + 1u);
            if (__fsqrt_rn(gn) <= tau) g = gn; else break;
        }
        t2max[ln] = g;
        cnt[ln] = 0;
    }
    __syncthreads();

    // ---- phase 2: threshold rescan, collect (d, j) keys ----
    if (valid) {
        float T = t2max[ln];
        for (int j = j0; j < j1; ++j) {
            float2 p = pts[j];
            float dx = __fsub_rn(xi, p.x);
            float dy = __fsub_rn(yi, p.y);
            float d2 = __fadd_rn(__fmul_rn(dx, dx), __fmul_rn(dy, dy));
            d2 = (j == i) ? INF : d2;
            if (d2 <= T) {
                float d = __fsqrt_rn(d2);
                u64 key = (((u64)__builtin_bit_cast(u32, d)) << 32) | (u32)j;
                int p2 = atomicAdd(&cnt[ln], 1);
                if (p2 < 24) lst[ln][p2] = key;
            }
        }
    }
    __syncthreads();

    // ---- final: select 7 smallest (d, j) keys -> knn + indeg ----
    if (part == 0 && valid) {
        int c = cnt[ln]; if (c > 24) c = 24;           // c >= 7 by construction
        u16* kp = knn + ((size_t)b * NSRC + (i - 2)) * 7;
#pragma unroll
        for (int k = 0; k < 7; ++k) {
            u64 best = ~0ULL; int bp = -1;
            for (int t = 0; t < c; ++t) {
                u64 v = lst[ln][t];
                if (v < best) { best = v; bp = t; }
            }
            int j = 0;
            if (bp >= 0) { lst[ln][bp] = ~0ULL; j = (int)(u32)best; }
            kp[k] = (u16)j;
            if (j >= 2) atomicAdd(&indeg[b * Ss + j], 1);
        }
    }
}

// ---------- 2) degree -> dinv ----------
__global__ void deg_dinv_kernel(const int* __restrict__ indeg, float* __restrict__ dinv) {
    int n = blockIdx.x * 256 + threadIdx.x;
    if (n >= NN) return;
    int i = n % Ss;
    float deg = (i == 0) ? 1.0f : (i == 1) ? (float)(Ss - 1) : (float)(indeg[n] + 2);
    dinv[n] = 1.0f / __fsqrt_rn(deg);
}

// ---------- 3) coalesced 3-phase scan: indeg -> CSR offsets ----------
__global__ __launch_bounds__(1024) void scan1_kernel(const int* __restrict__ indeg,
                                                     int* __restrict__ offs,
                                                     int* __restrict__ bsum) {
    __shared__ int sh[1024];
    int t = threadIdx.x;
    int idx = blockIdx.x * 1024 + t;
    int v = (idx < NN) ? indeg[idx] : 0;
    sh[t] = v;
    __syncthreads();
    for (int off = 1; off < 1024; off <<= 1) {      // Hillis-Steele inclusive
        int u = (t >= off) ? sh[t - off] : 0;
        __syncthreads();
        sh[t] += u;
        __syncthreads();
    }
    if (idx < NN) offs[idx] = sh[t] - v;            // exclusive prefix
    if (t == 1023) bsum[blockIdx.x] = sh[1023];
}

__global__ void scan2_kernel(int* __restrict__ bsum) {
    if (threadIdx.x == 0) {
        int run = 0;
        for (int k = 0; k < 63; ++k) { int v = bsum[k]; bsum[k] = run; run += v; }
        bsum[63] = run;                              // grand total
    }
}

__global__ __launch_bounds__(1024) void scan3_kernel(int* __restrict__ offs,
                                                     const int* __restrict__ bsum) {
    int idx = blockIdx.x * 1024 + threadIdx.x;
    if (idx < NN) offs[idx] += bsum[blockIdx.x];
    if (idx == 0) offs[NN] = bsum[63];
}

// ---------- 4) scatter reverse adjacency (src local index per dst) ----------
__global__ __launch_bounds__(256) void fill_rev_kernel(const u16* __restrict__ knn,
                                                       const int* __restrict__ offs,
                                                       int* __restrict__ cursor,
                                                       u16* __restrict__ rev) {
    if (threadIdx.x >= 250) return;
    int b = blockIdx.x;
    int i = 2 + blockIdx.y * 250 + threadIdx.x;
    if (i >= Ss) return;
    const u16* kp = knn + ((size_t)b * NSRC + (i - 2)) * 7;
#pragma unroll
    for (int k = 0; k < 7; ++k) {
        int d = kp[k];
        if (d >= 2) {
            int n = b * Ss + d;
            int p = atomicAdd(&cursor[n], 1);
            rev[offs[n] + p] = (u16)i;       // store local src index
        }
    }
}

// ---------- 5) embedding: x = inputs@Wc+bc + scor@Ws+bs -> single bf16 ----------
__global__ __launch_bounds__(256) void embed_kernel(const float* __restrict__ inputs,
                                                    const float* __restrict__ scor,
                                                    const float* __restrict__ Wc,
                                                    const float* __restrict__ bc,
                                                    const float* __restrict__ Ws,
                                                    const float* __restrict__ bs,
                                                    u16* __restrict__ xbf) {
    int gid = blockIdx.x * 256 + threadIdx.x;
    if (gid >= NN * Dd) return;
    int n = gid >> 7, c = gid & 127;
    float i0 = inputs[2 * n], i1 = inputs[2 * n + 1], sc = scor[n];
    float t1 = i0 * Wc[c] + i1 * Wc[Dd + c] + bc[c];
    float t2 = sc * Ws[c] + bs[c];
    xbf[gid] = f2bf(t1 + t2);
}

// ---------- 6) weight transpose + split (weights stay hi+lo) ----------
__global__ void transp_split_kernel(const float* __restrict__ src,
                                    u16* __restrict__ dhi, u16* __restrict__ dlo,
                                    int R, int C) {
    int gid = blockIdx.x * 256 + threadIdx.x;
    if (gid >= R * C) return;
    int r = gid / C, c = gid - r * C;
    u16 h, l;
    split2(src[gid], h, l);
    dhi[c * R + r] = h;
    dlo[c * R + r] = l;
}

// ---------- 7) MFMA GEMM: C = A(bf16) @ (Whi+Wlo), 2-MFMA scheme ----------
// LDS 48 KB -> 3 blocks/CU. grid: (Ncols/128, M/128).
__global__ __launch_bounds__(256) void gemm_kernel(const u16* __restrict__ A,
                                                   const u16* __restrict__ Whi,
                                                   const u16* __restrict__ Wlo,
                                                   float* __restrict__ C,
                                                   int K, int Ncols) {
    __shared__ __align__(16) u16 lA[128][64];
    __shared__ __align__(16) u16 lWh[128][64];
    __shared__ __align__(16) u16 lWl[128][64];

    int row0 = blockIdx.y * 128;
    int col0 = blockIdx.x * 128;
    int tid = threadIdx.x;
    int lane = tid & 63, wid = tid >> 6;
    int wm = (wid >> 1) * 64, wn = (wid & 1) * 64;
    int lanelo = lane & 15, quad = lane >> 4;

    f32x4 acc[4][4] = {};

    int scb = tid & 7;          // col-block (8 bf16 each) 0..7
    int sr  = tid >> 3;         // 0..31

    for (int k0 = 0; k0 < K; k0 += 64) {
#pragma unroll
        for (int rr = 0; rr < 4; ++rr) {
            int r = sr + rr * 32;
            uint4 va = *(const uint4*)(A + (size_t)(row0 + r) * K + k0 + scb * 8);
            *(uint4*)&lA[r][(scb ^ (r & 7)) * 8] = va;   // XOR swizzle
        }
#pragma unroll
        for (int rr = 0; rr < 4; ++rr) {
            int r = sr + rr * 32;
            size_t gofs = (size_t)(col0 + r) * K + k0 + scb * 8;
            uint4 vh = *(const uint4*)(Whi + gofs);
            uint4 vl = *(const uint4*)(Wlo + gofs);
            int cc = (scb ^ (r & 7)) * 8;
            *(uint4*)&lWh[r][cc] = vh;
            *(uint4*)&lWl[r][cc] = vl;
        }
        __syncthreads();

#pragma unroll
        for (int kk = 0; kk < 64; kk += 32) {
            short8 af[4], bh[4], bl[4];
            int cbb = (kk >> 3) + quad;
#pragma unroll
            for (int mt = 0; mt < 4; ++mt) {
                int r = wm + mt * 16 + lanelo;
                af[mt] = *(const short8*)&lA[r][((cbb ^ (r & 7))) * 8];
            }
#pragma unroll
            for (int nt = 0; nt < 4; ++nt) {
                int r = wn + nt * 16 + lanelo;
                int cc = (cbb ^ (r & 7)) * 8;
                bh[nt] = *(const short8*)&lWh[r][cc];
                bl[nt] = *(const short8*)&lWl[r][cc];
            }
#pragma unroll
            for (int mt = 0; mt < 4; ++mt)
#pragma unroll
                for (int nt = 0; nt < 4; ++nt) {
                    acc[mt][nt] = __builtin_amdgcn_mfma_f32_16x16x32_bf16(
                        af[mt], bh[nt], acc[mt][nt], 0, 0, 0);
                    acc[mt][nt] = __builtin_amdgcn_mfma_f32_16x16x32_bf16(
                        af[mt], bl[nt], acc[mt][nt], 0, 0, 0);
                }
        }
        __syncthreads();
    }

#pragma unroll
    for (int mt = 0; mt < 4; ++mt)
#pragma unroll
        for (int nt = 0; nt < 4; ++nt)
#pragma unroll
            for (int r = 0; r < 4; ++r) {
                int row = row0 + wm + mt * 16 + quad * 4 + r;
                int col = col0 + wn + nt * 16 + lanelo;
                C[(size_t)row * Ncols + col] = acc[mt][nt][r];
            }
}

// ---------- 7b) depot-1 batch sum: out[b][c] = sum_{j>=2} y[b,j,c]*dinv[b,j] ----------
__global__ __launch_bounds__(1024) void dep1_kernel(const float* __restrict__ y,
                                                    const float* __restrict__ dinv,
                                                    float* __restrict__ outb,
                                                    int M) {
    int b = blockIdx.x;
    int co = blockIdx.y * 128;
    int tid = threadIdx.x;
    int c4 = tid & 31;       // quad-channel 0..31 (128 channels)
    int es = tid >> 5;       // edge slot 0..31
    const float* yb = y + (size_t)b * Ss * M + co + c4 * 4;
    const float* dv = dinv + b * Ss;
    float a0 = 0.f, a1 = 0.f, a2 = 0.f, a3 = 0.f;
    for (int j = 2 + es; j < Ss; j += 32) {
        float w = dv[j];
        const float* p = yb + (size_t)j * M;
        float4 u = *(const float4*)p;
        a0 += u.x * w; a1 += u.y * w; a2 += u.z * w; a3 += u.w * w;
    }
    __shared__ float4 red[1024];
    float4 mv; mv.x = a0; mv.y = a1; mv.z = a2; mv.w = a3;
    red[tid] = mv;
    __syncthreads();
#pragma unroll
    for (int s = 16; s > 0; s >>= 1) {
        if (es < s) {
            float4 o = red[tid + (s << 5)];
            float4 m = red[tid];
            m.x += o.x; m.y += o.y; m.z += o.z; m.w += o.w;
            red[tid] = m;
        }
        __syncthreads();
    }
    if (es == 0) *(float4*)(outb + (size_t)b * M + co + c4 * 4) = red[c4];
}

// ---------- 8) aggregation M=512 + bias + relu -> single bf16 ----------
__global__ __launch_bounds__(128) void agg512_kernel(const float* __restrict__ y,
                                                     const float* __restrict__ dinv,
                                                     const int* __restrict__ offs,
                                                     const int* __restrict__ indeg,
                                                     const u16* __restrict__ rev,
                                                     const float* __restrict__ bias,
                                                     const float* __restrict__ dep1,
                                                     u16* __restrict__ oX) {
    int bx = blockIdx.x;
    int x = bx & 7, q = bx >> 3;
    int bb = q / 1000;
    int i = q - bb * 1000;
    int b = x + (bb << 3);
    int n = b * Ss + i;
    int nb = n - i;
    int tid = threadIdx.x, c = tid * 4;

    __shared__ int   sidx[128];
    __shared__ float sw[128];
    int cnt = 0, o = 0;
    if (i >= 2) { cnt = indeg[n]; o = offs[n]; }
    int cl = cnt < 128 ? cnt : 128;
    if (tid < cl) {
        int s = rev[o + tid];
        sidx[tid] = s;
        sw[tid] = dinv[nb + s];
    }
    __syncthreads();

    float a0 = 0.f, a1 = 0.f, a2 = 0.f, a3 = 0.f;
    if (i >= 2) {
        float w = dinv[nb];  // == 1.0 (deg[0]=1)
        float4 v = *(const float4*)(y + (size_t)nb * 512 + c);
        a0 = v.x * w; a1 = v.y * w; a2 = v.z * w; a3 = v.w * w;
        int e = 0;
        for (; e + 4 <= cl; e += 4) {
            int s0 = sidx[e], s1 = sidx[e + 1], s2 = sidx[e + 2], s3 = sidx[e + 3];
            float w0 = sw[e], w1 = sw[e + 1], w2 = sw[e + 2], w3 = sw[e + 3];
            float4 u0 = *(const float4*)(y + (size_t)(nb + s0) * 512 + c);
            float4 u1 = *(const float4*)(y + (size_t)(nb + s1) * 512 + c);
            float4 u2 = *(const float4*)(y + (size_t)(nb + s2) * 512 + c);
            float4 u3 = *(const float4*)(y + (size_t)(nb + s3) * 512 + c);
            a0 += u0.x * w0 + u1.x * w1 + u2.x * w2 + u3.x * w3;
            a1 += u0.y * w0 + u1.y * w1 + u2.y * w2 + u3.y * w3;
            a2 += u0.z * w0 + u1.z * w1 + u2.z * w2 + u3.z * w3;
            a3 += u0.w * w0 + u1.w * w1 + u2.w * w2 + u3.w * w3;
        }
        for (; e < cl; ++e) {
            int s = sidx[e]; float ww = sw[e];
            float4 u = *(const float4*)(y + (size_t)(nb + s) * 512 + c);
            a0 += u.x * ww; a1 += u.y * ww; a2 += u.z * ww; a3 += u.w * ww;
        }
        for (int e2 = 128; e2 < cnt; ++e2) {   // safety fallback (never in practice)
            int s = rev[o + e2]; float ww = dinv[nb + s];
            float4 u = *(const float4*)(y + (size_t)(nb + s) * 512 + c);
            a0 += u.x * ww; a1 += u.y * ww; a2 += u.z * ww; a3 += u.w * ww;
        }
    } else if (i == 1) {
        float4 v = *(const float4*)(dep1 + (size_t)b * 512 + c);
        a0 = v.x; a1 = v.y; a2 = v.z; a3 = v.w;
    }
    float dn = dinv[n], sn = dn * dn;
    float4 vs = *(const float4*)(y + (size_t)n * 512 + c);
    float z0 = a0 * dn + vs.x * sn + bias[c];
    float z1 = a1 * dn + vs.y * sn + bias[c + 1];
    float z2 = a2 * dn + vs.z * sn + bias[c + 2];
    float z3 = a3 * dn + vs.w * sn + bias[c + 3];
    ushort4 hv;
    hv.x = f2bf(fmaxf(z0, 0.f));
    hv.y = f2bf(fmaxf(z1, 0.f));
    hv.z = f2bf(fmaxf(z2, 0.f));
    hv.w = f2bf(fmaxf(z3, 0.f));
    *(ushort4*)(oX + (size_t)n * 512 + c) = hv;
}

// ---------- 9) final aggregation M=128, no relu, fp32 out ----------
__global__ __launch_bounds__(128) void agg128f_kernel(const float* __restrict__ y,
                                                      const float* __restrict__ dinv,
                                                      const int* __restrict__ offs,
                                                      const int* __restrict__ indeg,
                                                      const u16* __restrict__ rev,
                                                      const float* __restrict__ bias,
                                                      const float* __restrict__ dep1,
                                                      float* __restrict__ out) {
    int bx = blockIdx.x;
    int x = bx & 7, q = bx >> 3;
    int bb = q / 1000;
    int i = q - bb * 1000;
    int b = x + (bb << 3);
    int n = b * Ss + i;
    int nb = n - i;
    int tid = threadIdx.x, c = tid;

    __shared__ int   sidx[128];
    __shared__ float sw[128];
    int cnt = 0, o = 0;
    if (i >= 2) { cnt = indeg[n]; o = offs[n]; }
    int cl = cnt < 128 ? cnt : 128;
    if (tid < cl) {
        int s = rev[o + tid];
        sidx[tid] = s;
        sw[tid] = dinv[nb + s];
    }
    __syncthreads();

    float a = 0.f;
    if (i >= 2) {
        a = y[(size_t)nb * 128 + c] * dinv[nb];
        int e = 0;
        for (; e + 4 <= cl; e += 4) {
            int s0 = sidx[e], s1 = sidx[e + 1], s2 = sidx[e + 2], s3 = sidx[e + 3];
            float w0 = sw[e], w1 = sw[e + 1], w2 = sw[e + 2], w3 = sw[e + 3];
            float u0 = y[(size_t)(nb + s0) * 128 + c];
            float u1 = y[(size_t)(nb + s1) * 128 + c];
            float u2 = y[(size_t)(nb + s2) * 128 + c];
            float u3 = y[(size_t)(nb + s3) * 128 + c];
            a += u0 * w0 + u1 * w1 + u2 * w2 + u3 * w3;
        }
        for (; e < cl; ++e) a += y[(size_t)(nb + sidx[e]) * 128 + c] * sw[e];
        for (int e2 = 128; e2 < cnt; ++e2) {
            int s = rev[o + e2];
            a += y[(size_t)(nb + s) * 128 + c] * dinv[nb + s];
        }
    } else if (i == 1) {
        a = dep1[(size_t)b * 128 + c];
    }
    float dn = dinv[n];
    out[(size_t)n * 128 + c] = a * dn + y[(size_t)n * 128 + c] * (dn * dn) + bias[c];
}

// ---------- workspace layout (bytes) ----------
constexpr size_t O_INDEG  = 0;                       // 256000
constexpr size_t O_CURSOR = 256000;                  // 256000; reused post-fill_rev:
constexpr size_t O_DEP1A  = 256000;                  //   64*512*4 = 131072
constexpr size_t O_DEP1B  = 387072;                  //   64*128*4 = 32768
constexpr size_t O_OFFS   = 512000;                  // 256016
constexpr size_t O_DINV   = 768256;                  // 256000
constexpr size_t O_KNN    = 1024256;                 // 893824
constexpr size_t O_REV    = 1918080;                 // 893824
constexpr size_t O_WT0H   = 2811904;                 // 131072
constexpr size_t O_WT0L   = 2942976;
constexpr size_t O_WT1H   = 3074048;                 // 524288
constexpr size_t O_WT1L   = 3598336;
constexpr size_t O_WT2H   = 4122624;                 // 131072
constexpr size_t O_WT2L   = 4253696;
constexpr size_t O_X      = 4384768;                 // 64000*512*2 = 65536000 (bf16 acts)
constexpr size_t O_Y      = 135456768;               // 131072000
constexpr size_t O_BSUM   = 266528768;               // 64*4 = 256; total 266529024

extern "C" void kernel_launch(void* const* d_in, const int* in_sizes, int n_in,
                              void* d_out, int out_size, void* d_ws, size_t ws_size,
                              hipStream_t stream) {
    const float* inputs = (const float*)d_in[0];
    const float* scor   = (const float*)d_in[1];
    const float* Wc     = (const float*)d_in[2];
    const float* bc     = (const float*)d_in[3];
    const float* Ws     = (const float*)d_in[4];
    const float* bs     = (const float*)d_in[5];
    const float* W0     = (const float*)d_in[6];
    const float* b0     = (const float*)d_in[7];
    const float* W1     = (const float*)d_in[8];
    const float* b1     = (const float*)d_in[9];
    const float* W2     = (const float*)d_in[10];
    const float* b2     = (const float*)d_in[11];

    char* w = (char*)d_ws;
    int*   indeg  = (int*)(w + O_INDEG);
    int*   cursor = (int*)(w + O_CURSOR);
    float* dep1a  = (float*)(w + O_DEP1A);
    float* dep1b  = (float*)(w + O_DEP1B);
    int*   offs   = (int*)(w + O_OFFS);
    float* dinv   = (float*)(w + O_DINV);
    u16*   knn    = (u16*)(w + O_KNN);
    u16*   rev    = (u16*)(w + O_REV);
    u16*   wt0h   = (u16*)(w + O_WT0H);
    u16*   wt0l   = (u16*)(w + O_WT0L);
    u16*   wt1h   = (u16*)(w + O_WT1H);
    u16*   wt1l   = (u16*)(w + O_WT1L);
    u16*   wt2h   = (u16*)(w + O_WT2H);
    u16*   wt2l   = (u16*)(w + O_WT2L);
    u16*   xbf    = (u16*)(w + O_X);
    float* y      = (float*)(w + O_Y);
    int*   bsum   = (int*)(w + O_BSUM);

    hipMemsetAsync(w + O_INDEG, 0, 512000, stream);  // indeg + cursor

    knn_kernel<<<dim3(Bb, 16), 256, 0, stream>>>(inputs, knn, indeg);
    deg_dinv_kernel<<<250, 256, 0, stream>>>(indeg, dinv);
    scan1_kernel<<<63, 1024, 0, stream>>>(indeg, offs, bsum);
    scan2_kernel<<<1, 64, 0, stream>>>(bsum);
    scan3_kernel<<<63, 1024, 0, stream>>>(offs, bsum);
    fill_rev_kernel<<<dim3(Bb, 4), 256, 0, stream>>>(knn, offs, cursor, rev);

    embed_kernel<<<NN * Dd / 256, 256, 0, stream>>>(inputs, scor, Wc, bc, Ws, bs, xbf);

    transp_split_kernel<<<(Dd * Hh + 255) / 256, 256, 0, stream>>>(W0, wt0h, wt0l, Dd, Hh);
    transp_split_kernel<<<(Hh * Hh + 255) / 256, 256, 0, stream>>>(W1, wt1h, wt1l, Hh, Hh);
    transp_split_kernel<<<(Hh * Dd + 255) / 256, 256, 0, stream>>>(W2, wt2h, wt2l, Hh, Dd);

    // layer 0: [N,128] @ [128,512]
    gemm_kernel<<<dim3(Hh / 128, NN / 128), 256, 0, stream>>>(xbf, wt0h, wt0l, y, Dd, Hh);
    dep1_kernel<<<dim3(Bb, 4), 1024, 0, stream>>>(y, dinv, dep1a, Hh);
    agg512_kernel<<<NN, 128, 0, stream>>>(y, dinv, offs, indeg, rev, b0, dep1a, xbf);
    // layer 1: [N,512] @ [512,512]
    gemm_kernel<<<dim3(Hh / 128, NN / 128), 256, 0, stream>>>(xbf, wt1h, wt1l, y, Hh, Hh);
    dep1_kernel<<<dim3(Bb, 4), 1024, 0, stream>>>(y, dinv, dep1a, Hh);
    agg512_kernel<<<NN, 128, 0, stream>>>(y, dinv, offs, indeg, rev, b1, dep1a, xbf);
    // layer 2: [N,512] @ [512,128]
    gemm_kernel<<<dim3(Dd / 128, NN / 128), 256, 0, stream>>>(xbf, wt2h, wt2l, y, Hh, Dd);
    dep1_kernel<<<dim3(Bb, 1), 1024, 0, stream>>>(y, dinv, dep1b, Dd);
    agg128f_kernel<<<NN, 128, 0, stream>>>(y, dinv, offs, indeg, rev, b2, dep1b, (float*)d_out);
}

// Round 8
// 523.431 us; speedup vs baseline: 2.6805x; 1.0401x over previous
//
#include <hip/hip_runtime.h>

typedef unsigned short u16;
typedef unsigned int u32;
typedef unsigned long long u64;
using short8 = __attribute__((ext_vector_type(8))) short;
using f32x4  = __attribute__((ext_vector_type(4))) float;

constexpr int Bb = 64, Ss = 1000, Dd = 128, Hh = 512;
constexpr int NN = Bb * Ss;           // 64000 nodes
constexpr int NSRC = Ss - 2;          // 998 kNN source nodes per batch

// ---------- helpers ----------
__device__ __forceinline__ float bf2f(u16 h) {
    u32 u = ((u32)h) << 16;
    return __builtin_bit_cast(float, u);
}
__device__ __forceinline__ u16 f2bf(float v) {  // RNE, finite inputs only
    u32 u = __builtin_bit_cast(u32, v);
    u32 r = (u + 0x7FFFu + ((u >> 16) & 1u)) >> 16;
    return (u16)r;
}
__device__ __forceinline__ void split2(float v, u16& h, u16& l) {
    h = f2bf(v);
    float fh = bf2f(h);
    l = f2bf(v - fh);
}

// branchless insert of v into ascending bd[0..6] (drops the max).
// bd[k]' = med3(v, bd[k-1], bd[k]) — independent ops, no serial chain.
__device__ __forceinline__ void ins7(float (&bd)[7], float v) {
#pragma unroll
    for (int k = 6; k >= 1; --k)
        bd[k] = __builtin_amdgcn_fmed3f(v, bd[k - 1], bd[k]);
    bd[0] = fminf(v, bd[0]);
}

// ---------- 1) kNN: two-phase, med3 d^2 network + exact (d,j) re-rank ----------
// 32 nodes x 8 parts per block; grid (64, 32).
__global__ __launch_bounds__(256) void knn_kernel(const float* __restrict__ inputs,
                                                  u16* __restrict__ knn,
                                                  int* __restrict__ indeg) {
    __shared__ float2 pts[Ss];
    __shared__ float  mg[32][56];
    __shared__ u64    lst[32][24];
    __shared__ int    cnt[32];
    __shared__ float  t2max[32];

    int b = blockIdx.x;
    const float* base = inputs + (size_t)b * Ss * 2;
    for (int t = threadIdx.x; t < Ss; t += 256) {
        float2 p;
        p.x = base[2 * t];
        p.y = base[2 * t + 1];
        pts[t] = p;
    }
    __syncthreads();

    int tid = threadIdx.x;
    int ln = tid >> 3;                  // local node 0..31
    int part = tid & 7;                 // candidate eighth 0..7
    int i = 2 + blockIdx.y * 32 + ln;
    bool valid = (i < Ss);
    int j0 = part * 125, j1 = j0 + 125;
    float xi = 0.f, yi = 0.f;
    if (valid) { xi = pts[i].x; yi = pts[i].y; }
    const float INF = __builtin_inff();

    // ---- phase 1: 7-smallest d^2 via med3 network ----
    if (valid) {
        float bd[7];
#pragma unroll
        for (int k = 0; k < 7; ++k) bd[k] = INF;
        for (int j = j0; j < j1; ++j) {
            float2 p = pts[j];
            float dx = __fsub_rn(xi, p.x);            // exact fp32 RN mirror
            float dy = __fsub_rn(yi, p.y);
            float d2 = __fadd_rn(__fmul_rn(dx, dx), __fmul_rn(dy, dy));
            d2 = (j == i) ? INF : d2;                 // exclude self
            ins7(bd, d2);
        }
#pragma unroll
        for (int k = 0; k < 7; ++k) mg[ln][part * 7 + k] = bd[k];
    }
    __syncthreads();

    // ---- merge 56 -> tau2; derive T2max; reset count ----
    if (part == 0 && valid) {
        float m[7];
#pragma unroll
        for (int k = 0; k < 7; ++k) m[k] = INF;
        for (int t = 0; t < 56; ++t) ins7(m, mg[ln][t]);
        float tau2 = m[6];
        float tau = __fsqrt_rn(tau2);
        float g = tau2;                                // sqrt_rn(g) == tau by construction
        for (int it = 0; it < 8; ++it) {               // widen to sqrt-collision boundary
            float gn = __builtin_bit_cast(float, __builtin_bit_cast(u32, g) + 1u);
            if (__fsqrt_rn(gn) <= tau) g = gn; else break;
        }
        t2max[ln] = g;
        cnt[ln] = 0;
    }
    __syncthreads();

    // ---- phase 2: threshold rescan, collect (d, j) keys ----
    if (valid) {
        float T = t2max[ln];
        for (int j = j0; j < j1; ++j) {
            float2 p = pts[j];
            float dx = __fsub_rn(xi, p.x);
            float dy = __fsub_rn(yi, p.y);
            float d2 = __fadd_rn(__fmul_rn(dx, dx), __fmul_rn(dy, dy));
            d2 = (j == i) ? INF : d2;
            if (d2 <= T) {
                float d = __fsqrt_rn(d2);
                u64 key = (((u64)__builtin_bit_cast(u32, d)) << 32) | (u32)j;
                int p2 = atomicAdd(&cnt[ln], 1);
                if (p2 < 24) lst[ln][p2] = key;
            }
        }
    }
    __syncthreads();

    // ---- final: select 7 smallest (d, j) keys -> knn + indeg ----
    if (part == 0 && valid) {
        int c = cnt[ln]; if (c > 24) c = 24;           // c >= 7 by construction
        u16* kp = knn + ((size_t)b * NSRC + (i - 2)) * 7;
#pragma unroll
        for (int k = 0; k < 7; ++k) {
            u64 best = ~0ULL; int bp = -1;
            for (int t = 0; t < c; ++t) {
                u64 v = lst[ln][t];
                if (v < best) { best = v; bp = t; }
            }
            int j = 0;
            if (bp >= 0) { lst[ln][bp] = ~0ULL; j = (int)(u32)best; }
            kp[k] = (u16)j;
            if (j >= 2) atomicAdd(&indeg[b * Ss + j], 1);
        }
    }
}

// ---------- 2) degree -> dinv ----------
__global__ void deg_dinv_kernel(const int* __restrict__ indeg, float* __restrict__ dinv) {
    int n = blockIdx.x * 256 + threadIdx.x;
    if (n >= NN) return;
    int i = n % Ss;
    float deg = (i == 0) ? 1.0f : (i == 1) ? (float)(Ss - 1) : (float)(indeg[n] + 2);
    dinv[n] = 1.0f / __fsqrt_rn(deg);
}

// ---------- 3) coalesced 3-phase scan: indeg -> CSR offsets ----------
__global__ __launch_bounds__(1024) void scan1_kernel(const int* __restrict__ indeg,
                                                     int* __restrict__ offs,
                                                     int* __restrict__ bsum) {
    __shared__ int sh[1024];
    int t = threadIdx.x;
    int idx = blockIdx.x * 1024 + t;
    int v = (idx < NN) ? indeg[idx] : 0;
    sh[t] = v;
    __syncthreads();
    for (int off = 1; off < 1024; off <<= 1) {      // Hillis-Steele inclusive
        int u = (t >= off) ? sh[t - off] : 0;
        __syncthreads();
        sh[t] += u;
        __syncthreads();
    }
    if (idx < NN) offs[idx] = sh[t] - v;            // exclusive prefix
    if (t == 1023) bsum[blockIdx.x] = sh[1023];
}

__global__ void scan2_kernel(int* __restrict__ bsum) {
    if (threadIdx.x == 0) {
        int run = 0;
        for (int k = 0; k < 63; ++k) { int v = bsum[k]; bsum[k] = run; run += v; }
        bsum[63] = run;                              // grand total
    }
}

__global__ __launch_bounds__(1024) void scan3_kernel(int* __restrict__ offs,
                                                     const int* __restrict__ bsum) {
    int idx = blockIdx.x * 1024 + threadIdx.x;
    if (idx < NN) offs[idx] += bsum[blockIdx.x];
    if (idx == 0) offs[NN] = bsum[63];
}

// ---------- 4) scatter reverse adjacency (src local index per dst) ----------
__global__ __launch_bounds__(256) void fill_rev_kernel(const u16* __restrict__ knn,
                                                       const int* __restrict__ offs,
                                                       int* __restrict__ cursor,
                                                       u16* __restrict__ rev) {
    if (threadIdx.x >= 250) return;
    int b = blockIdx.x;
    int i = 2 + blockIdx.y * 250 + threadIdx.x;
    if (i >= Ss) return;
    const u16* kp = knn + ((size_t)b * NSRC + (i - 2)) * 7;
#pragma unroll
    for (int k = 0; k < 7; ++k) {
        int d = kp[k];
        if (d >= 2) {
            int n = b * Ss + d;
            int p = atomicAdd(&cursor[n], 1);
            rev[offs[n] + p] = (u16)i;       // store local src index
        }
    }
}

// ---------- 5) embedding: x = inputs@Wc+bc + scor@Ws+bs -> single bf16 ----------
__global__ __launch_bounds__(256) void embed_kernel(const float* __restrict__ inputs,
                                                    const float* __restrict__ scor,
                                                    const float* __restrict__ Wc,
                                                    const float* __restrict__ bc,
                                                    const float* __restrict__ Ws,
                                                    const float* __restrict__ bs,
                                                    u16* __restrict__ xbf) {
    int gid = blockIdx.x * 256 + threadIdx.x;
    if (gid >= NN * Dd) return;
    int n = gid >> 7, c = gid & 127;
    float i0 = inputs[2 * n], i1 = inputs[2 * n + 1], sc = scor[n];
    float t1 = i0 * Wc[c] + i1 * Wc[Dd + c] + bc[c];
    float t2 = sc * Ws[c] + bs[c];
    xbf[gid] = f2bf(t1 + t2);
}

// ---------- 6) weight transpose + split (weights stay hi+lo) ----------
__global__ void transp_split_kernel(const float* __restrict__ src,
                                    u16* __restrict__ dhi, u16* __restrict__ dlo,
                                    int R, int C) {
    int gid = blockIdx.x * 256 + threadIdx.x;
    if (gid >= R * C) return;
    int r = gid / C, c = gid - r * C;
    u16 h, l;
    split2(src[gid], h, l);
    dhi[c * R + r] = h;
    dlo[c * R + r] = l;
}

// ---------- 7) MFMA GEMM: C = A(bf16) @ (Whi+Wlo), 2-MFMA scheme ----------
// LDS 48 KB -> 3 blocks/CU. grid: (Ncols/128, M/128).
__global__ __launch_bounds__(256) void gemm_kernel(const u16* __restrict__ A,
                                                   const u16* __restrict__ Whi,
                                                   const u16* __restrict__ Wlo,
                                                   float* __restrict__ C,
                                                   int K, int Ncols) {
    __shared__ __align__(16) u16 lA[128][64];
    __shared__ __align__(16) u16 lWh[128][64];
    __shared__ __align__(16) u16 lWl[128][64];

    int row0 = blockIdx.y * 128;
    int col0 = blockIdx.x * 128;
    int tid = threadIdx.x;
    int lane = tid & 63, wid = tid >> 6;
    int wm = (wid >> 1) * 64, wn = (wid & 1) * 64;
    int lanelo = lane & 15, quad = lane >> 4;

    f32x4 acc[4][4] = {};

    int scb = tid & 7;          // col-block (8 bf16 each) 0..7
    int sr  = tid >> 3;         // 0..31

    for (int k0 = 0; k0 < K; k0 += 64) {
#pragma unroll
        for (int rr = 0; rr < 4; ++rr) {
            int r = sr + rr * 32;
            uint4 va = *(const uint4*)(A + (size_t)(row0 + r) * K + k0 + scb * 8);
            *(uint4*)&lA[r][(scb ^ (r & 7)) * 8] = va;   // XOR swizzle
        }
#pragma unroll
        for (int rr = 0; rr < 4; ++rr) {
            int r = sr + rr * 32;
            size_t gofs = (size_t)(col0 + r) * K + k0 + scb * 8;
            uint4 vh = *(const uint4*)(Whi + gofs);
            uint4 vl = *(const uint4*)(Wlo + gofs);
            int cc = (scb ^ (r & 7)) * 8;
            *(uint4*)&lWh[r][cc] = vh;
            *(uint4*)&lWl[r][cc] = vl;
        }
        __syncthreads();

#pragma unroll
        for (int kk = 0; kk < 64; kk += 32) {
            short8 af[4], bh[4], bl[4];
            int cbb = (kk >> 3) + quad;
#pragma unroll
            for (int mt = 0; mt < 4; ++mt) {
                int r = wm + mt * 16 + lanelo;
                af[mt] = *(const short8*)&lA[r][((cbb ^ (r & 7))) * 8];
            }
#pragma unroll
            for (int nt = 0; nt < 4; ++nt) {
                int r = wn + nt * 16 + lanelo;
                int cc = (cbb ^ (r & 7)) * 8;
                bh[nt] = *(const short8*)&lWh[r][cc];
                bl[nt] = *(const short8*)&lWl[r][cc];
            }
#pragma unroll
            for (int mt = 0; mt < 4; ++mt)
#pragma unroll
                for (int nt = 0; nt < 4; ++nt) {
                    acc[mt][nt] = __builtin_amdgcn_mfma_f32_16x16x32_bf16(
                        af[mt], bh[nt], acc[mt][nt], 0, 0, 0);
                    acc[mt][nt] = __builtin_amdgcn_mfma_f32_16x16x32_bf16(
                        af[mt], bl[nt], acc[mt][nt], 0, 0, 0);
                }
        }
        __syncthreads();
    }

#pragma unroll
    for (int mt = 0; mt < 4; ++mt)
#pragma unroll
        for (int nt = 0; nt < 4; ++nt)
#pragma unroll
            for (int r = 0; r < 4; ++r) {
                int row = row0 + wm + mt * 16 + quad * 4 + r;
                int col = col0 + wn + nt * 16 + lanelo;
                C[(size_t)row * Ncols + col] = acc[mt][nt][r];
            }
}

// ---------- 7b) depot-1 batch sum: out[b][c] = sum_{j>=2} y[b,j,c]*dinv[b,j] ----------
__global__ __launch_bounds__(1024) void dep1_kernel(const float* __restrict__ y,
                                                    const float* __restrict__ dinv,
                                                    float* __restrict__ outb,
                                                    int M) {
    int b = blockIdx.x;
    int co = blockIdx.y * 128;
    int tid = threadIdx.x;
    int c4 = tid & 31;       // quad-channel 0..31 (128 channels)
    int es = tid >> 5;       // edge slot 0..31
    const float* yb = y + (size_t)b * Ss * M + co + c4 * 4;
    const float* dv = dinv + b * Ss;
    float a0 = 0.f, a1 = 0.f, a2 = 0.f, a3 = 0.f;
    for (int j = 2 + es; j < Ss; j += 32) {
        float w = dv[j];
        const float* p = yb + (size_t)j * M;
        float4 u = *(const float4*)p;
        a0 += u.x * w; a1 += u.y * w; a2 += u.z * w; a3 += u.w * w;
    }
    __shared__ float4 red[1024];
    float4 mv; mv.x = a0; mv.y = a1; mv.z = a2; mv.w = a3;
    red[tid] = mv;
    __syncthreads();
#pragma unroll
    for (int s = 16; s > 0; s >>= 1) {
        if (es < s) {
            float4 o = red[tid + (s << 5)];
            float4 m = red[tid];
            m.x += o.x; m.y += o.y; m.z += o.z; m.w += o.w;
            red[tid] = m;
        }
        __syncthreads();
    }
    if (es == 0) *(float4*)(outb + (size_t)b * M + co + c4 * 4) = red[c4];
}

// ---------- 8) aggregation M=512 + bias + relu -> single bf16 ----------
__global__ __launch_bounds__(128) void agg512_kernel(const float* __restrict__ y,
                                                     const float* __restrict__ dinv,
                                                     const int* __restrict__ offs,
                                                     const int* __restrict__ indeg,
                                                     const u16* __restrict__ rev,
                                                     const float* __restrict__ bias,
                                                     const float* __restrict__ dep1,
                                                     u16* __restrict__ oX) {
    int bx = blockIdx.x;
    int x = bx & 7, q = bx >> 3;
    int bb = q / 1000;
    int i = q - bb * 1000;
    int b = x + (bb << 3);
    int n = b * Ss + i;
    int nb = n - i;
    int tid = threadIdx.x, c = tid * 4;

    __shared__ int   sidx[128];
    __shared__ float sw[128];
    int cnt = 0, o = 0;
    if (i >= 2) { cnt = indeg[n]; o = offs[n]; }
    int cl = cnt < 128 ? cnt : 128;
    if (tid < cl) {
        int s = rev[o + tid];
        sidx[tid] = s;
        sw[tid] = dinv[nb + s];
    }
    __syncthreads();

    float a0 = 0.f, a1 = 0.f, a2 = 0.f, a3 = 0.f;
    if (i >= 2) {
        float w = dinv[nb];  // == 1.0 (deg[0]=1)
        float4 v = *(const float4*)(y + (size_t)nb * 512 + c);
        a0 = v.x * w; a1 = v.y * w; a2 = v.z * w; a3 = v.w * w;
        int e = 0;
        for (; e + 4 <= cl; e += 4) {
            int s0 = sidx[e], s1 = sidx[e + 1], s2 = sidx[e + 2], s3 = sidx[e + 3];
            float w0 = sw[e], w1 = sw[e + 1], w2 = sw[e + 2], w3 = sw[e + 3];
            float4 u0 = *(const float4*)(y + (size_t)(nb + s0) * 512 + c);
            float4 u1 = *(const float4*)(y + (size_t)(nb + s1) * 512 + c);
            float4 u2 = *(const float4*)(y + (size_t)(nb + s2) * 512 + c);
            float4 u3 = *(const float4*)(y + (size_t)(nb + s3) * 512 + c);
            a0 += u0.x * w0 + u1.x * w1 + u2.x * w2 + u3.x * w3;
            a1 += u0.y * w0 + u1.y * w1 + u2.y * w2 + u3.y * w3;
            a2 += u0.z * w0 + u1.z * w1 + u2.z * w2 + u3.z * w3;
            a3 += u0.w * w0 + u1.w * w1 + u2.w * w2 + u3.w * w3;
        }
        for (; e < cl; ++e) {
            int s = sidx[e]; float ww = sw[e];
            float4 u = *(const float4*)(y + (size_t)(nb + s) * 512 + c);
            a0 += u.x * ww; a1 += u.y * ww; a2 += u.z * ww; a3 += u.w * ww;
        }
        for (int e2 = 128; e2 < cnt; ++e2) {   // safety fallback (never in practice)
            int s = rev[o + e2]; float ww = dinv[nb + s];
            float4 u = *(const float4*)(y + (size_t)(nb + s) * 512 + c);
            a0 += u.x * ww; a1 += u.y * ww; a2 += u.z * ww; a3 += u.w * ww;
        }
    } else if (i == 1) {
        float4 v = *(const float4*)(dep1 + (size_t)b * 512 + c);
        a0 = v.x; a1 = v.y; a2 = v.z; a3 = v.w;
    }
    float dn = dinv[n], sn = dn * dn;
    float4 vs = *(const float4*)(y + (size_t)n * 512 + c);
    float z0 = a0 * dn + vs.x * sn + bias[c];
    float z1 = a1 * dn + vs.y * sn + bias[c + 1];
    float z2 = a2 * dn + vs.z * sn + bias[c + 2];
    float z3 = a3 * dn + vs.w * sn + bias[c + 3];
    ushort4 hv;
    hv.x = f2bf(fmaxf(z0, 0.f));
    hv.y = f2bf(fmaxf(z1, 0.f));
    hv.z = f2bf(fmaxf(z2, 0.f));
    hv.w = f2bf(fmaxf(z3, 0.f));
    *(ushort4*)(oX + (size_t)n * 512 + c) = hv;
}

// ---------- 9) final aggregation M=128, no relu, fp32 out ----------
__global__ __launch_bounds__(128) void agg128f_kernel(const float* __restrict__ y,
                                                      const float* __restrict__ dinv,
                                                      const int* __restrict__ offs,
                                                      const int* __restrict__ indeg,
                                                      const u16* __restrict__ rev,
                                                      const float* __restrict__ bias,
                                                      const float* __restrict__ dep1,
                                                      float* __restrict__ out) {
    int bx = blockIdx.x;
    int x = bx & 7, q = bx >> 3;
    int bb = q / 1000;
    int i = q - bb * 1000;
    int b = x + (bb << 3);
    int n = b * Ss + i;
    int nb = n - i;
    int tid = threadIdx.x, c = tid;

    __shared__ int   sidx[128];
    __shared__ float sw[128];
    int cnt = 0, o = 0;
    if (i >= 2) { cnt = indeg[n]; o = offs[n]; }
    int cl = cnt < 128 ? cnt : 128;
    if (tid < cl) {
        int s = rev[o + tid];
        sidx[tid] = s;
        sw[tid] = dinv[nb + s];
    }
    __syncthreads();

    float a = 0.f;
    if (i >= 2) {
        a = y[(size_t)nb * 128 + c] * dinv[nb];
        int e = 0;
        for (; e + 4 <= cl; e += 4) {
            int s0 = sidx[e], s1 = sidx[e + 1], s2 = sidx[e + 2], s3 = sidx[e + 3];
            float w0 = sw[e], w1 = sw[e + 1], w2 = sw[e + 2], w3 = sw[e + 3];
            float u0 = y[(size_t)(nb + s0) * 128 + c];
            float u1 = y[(size_t)(nb + s1) * 128 + c];
            float u2 = y[(size_t)(nb + s2) * 128 + c];
            float u3 = y[(size_t)(nb + s3) * 128 + c];
            a += u0 * w0 + u1 * w1 + u2 * w2 + u3 * w3;
        }
        for (; e < cl; ++e) a += y[(size_t)(nb + sidx[e]) * 128 + c] * sw[e];
        for (int e2 = 128; e2 < cnt; ++e2) {
            int s = rev[o + e2];
            a += y[(size_t)(nb + s) * 128 + c] * dinv[nb + s];
        }
    } else if (i == 1) {
        a = dep1[(size_t)b * 128 + c];
    }
    float dn = dinv[n];
    out[(size_t)n * 128 + c] = a * dn + y[(size_t)n * 128 + c] * (dn * dn) + bias[c];
}

// ---------- workspace layout (bytes) ----------
constexpr size_t O_INDEG  = 0;                       // 256000
constexpr size_t O_CURSOR = 256000;                  // 256000; reused post-fill_rev:
constexpr size_t O_DEP1A  = 256000;                  //   64*512*4 = 131072
constexpr size_t O_DEP1B  = 387072;                  //   64*128*4 = 32768
constexpr size_t O_OFFS   = 512000;                  // 256016
constexpr size_t O_DINV   = 768256;                  // 256000
constexpr size_t O_KNN    = 1024256;                 // 893824
constexpr size_t O_REV    = 1918080;                 // 893824
constexpr size_t O_WT0H   = 2811904;                 // 131072
constexpr size_t O_WT0L   = 2942976;
constexpr size_t O_WT1H   = 3074048;                 // 524288
constexpr size_t O_WT1L   = 3598336;
constexpr size_t O_WT2H   = 4122624;                 // 131072
constexpr size_t O_WT2L   = 4253696;
constexpr size_t O_X      = 4384768;                 // 64000*512*2 = 65536000 (bf16 acts)
constexpr size_t O_Y      = 135456768;               // 131072000
constexpr size_t O_BSUM   = 266528768;               // 64*4 = 256; total 266529024

extern "C" void kernel_launch(void* const* d_in, const int* in_sizes, int n_in,
                              void* d_out, int out_size, void* d_ws, size_t ws_size,
                              hipStream_t stream) {
    const float* inputs = (const float*)d_in[0];
    const float* scor   = (const float*)d_in[1];
    const float* Wc     = (const float*)d_in[2];
    const float* bc     = (const float*)d_in[3];
    const float* Ws     = (const float*)d_in[4];
    const float* bs     = (const float*)d_in[5];
    const float* W0     = (const float*)d_in[6];
    const float* b0     = (const float*)d_in[7];
    const float* W1     = (const float*)d_in[8];
    const float* b1     = (const float*)d_in[9];
    const float* W2     = (const float*)d_in[10];
    const float* b2     = (const float*)d_in[11];

    char* w = (char*)d_ws;
    int*   indeg  = (int*)(w + O_INDEG);
    int*   cursor = (int*)(w + O_CURSOR);
    float* dep1a  = (float*)(w + O_DEP1A);
    float* dep1b  = (float*)(w + O_DEP1B);
    int*   offs   = (int*)(w + O_OFFS);
    float* dinv   = (float*)(w + O_DINV);
    u16*   knn    = (u16*)(w + O_KNN);
    u16*   rev    = (u16*)(w + O_REV);
    u16*   wt0h   = (u16*)(w + O_WT0H);
    u16*   wt0l   = (u16*)(w + O_WT0L);
    u16*   wt1h   = (u16*)(w + O_WT1H);
    u16*   wt1l   = (u16*)(w + O_WT1L);
    u16*   wt2h   = (u16*)(w + O_WT2H);
    u16*   wt2l   = (u16*)(w + O_WT2L);
    u16*   xbf    = (u16*)(w + O_X);
    float* y      = (float*)(w + O_Y);
    int*   bsum   = (int*)(w + O_BSUM);

    hipMemsetAsync(w + O_INDEG, 0, 512000, stream);  // indeg + cursor

    knn_kernel<<<dim3(Bb, 32), 256, 0, stream>>>(inputs, knn, indeg);
    deg_dinv_kernel<<<250, 256, 0, stream>>>(indeg, dinv);
    scan1_kernel<<<63, 1024, 0, stream>>>(indeg, offs, bsum);
    scan2_kernel<<<1, 64, 0, stream>>>(bsum);
    scan3_kernel<<<63, 1024, 0, stream>>>(offs, bsum);
    fill_rev_kernel<<<dim3(Bb, 4), 256, 0, stream>>>(knn, offs, cursor, rev);

    embed_kernel<<<NN * Dd / 256, 256, 0, stream>>>(inputs, scor, Wc, bc, Ws, bs, xbf);

    transp_split_kernel<<<(Dd * Hh + 255) / 256, 256, 0, stream>>>(W0, wt0h, wt0l, Dd, Hh);
    transp_split_kernel<<<(Hh * Hh + 255) / 256, 256, 0, stream>>>(W1, wt1h, wt1l, Hh, Hh);
    transp_split_kernel<<<(Hh * Dd + 255) / 256, 256, 0, stream>>>(W2, wt2h, wt2l, Hh, Dd);

    // layer 0: [N,128] @ [128,512]
    gemm_kernel<<<dim3(Hh / 128, NN / 128), 256, 0, stream>>>(xbf, wt0h, wt0l, y, Dd, Hh);
    dep1_kernel<<<dim3(Bb, 4), 1024, 0, stream>>>(y, dinv, dep1a, Hh);
    agg512_kernel<<<NN, 128, 0, stream>>>(y, dinv, offs, indeg, rev, b0, dep1a, xbf);
    // layer 1: [N,512] @ [512,512]
    gemm_kernel<<<dim3(Hh / 128, NN / 128), 256, 0, stream>>>(xbf, wt1h, wt1l, y, Hh, Hh);
    dep1_kernel<<<dim3(Bb, 4), 1024, 0, stream>>>(y, dinv, dep1a, Hh);
    agg512_kernel<<<NN, 128, 0, stream>>>(y, dinv, offs, indeg, rev, b1, dep1a, xbf);
    // layer 2: [N,512] @ [512,128]
    gemm_kernel<<<dim3(Dd / 128, NN / 128), 256, 0, stream>>>(xbf, wt2h, wt2l, y, Hh, Dd);
    dep1_kernel<<<dim3(Bb, 1), 1024, 0, stream>>>(y, dinv, dep1b, Dd);
    agg128f_kernel<<<NN, 128, 0, stream>>>(y, dinv, offs, indeg, rev, b2, dep1b, (float*)d_out);
}

// Round 9
// 487.622 us; speedup vs baseline: 2.8773x; 1.0734x over previous
//
#include <hip/hip_runtime.h>

typedef unsigned short u16;
typedef unsigned int u32;
typedef unsigned long long u64;
using short8 = __attribute__((ext_vector_type(8))) short;
using f32x4  = __attribute__((ext_vector_type(4))) float;

constexpr int Bb = 64, Ss = 1000, Dd = 128, Hh = 512;
constexpr int NN = Bb * Ss;           // 64000 nodes
constexpr int NSRC = Ss - 2;          // 998 kNN source nodes per batch

// ---------- helpers ----------
__device__ __forceinline__ float bf2f(u16 h) {
    u32 u = ((u32)h) << 16;
    return __builtin_bit_cast(float, u);
}
__device__ __forceinline__ u16 f2bf(float v) {  // RNE, finite inputs only
    u32 u = __builtin_bit_cast(u32, v);
    u32 r = (u + 0x7FFFu + ((u >> 16) & 1u)) >> 16;
    return (u16)r;
}
__device__ __forceinline__ void split2(float v, u16& h, u16& l) {
    h = f2bf(v);
    float fh = bf2f(h);
    l = f2bf(v - fh);
}
__device__ __forceinline__ float4 bf4(ushort4 v) {
    float4 r;
    r.x = bf2f(v.x); r.y = bf2f(v.y); r.z = bf2f(v.z); r.w = bf2f(v.w);
    return r;
}

// branchless insert of v into ascending bd[0..6] (drops the max).
__device__ __forceinline__ void ins7(float (&bd)[7], float v) {
#pragma unroll
    for (int k = 6; k >= 1; --k)
        bd[k] = __builtin_amdgcn_fmed3f(v, bd[k - 1], bd[k]);
    bd[0] = fminf(v, bd[0]);
}

// ---------- 1) kNN: two-phase, med3 d^2 network + exact (d,j) re-rank ----------
__global__ __launch_bounds__(256) void knn_kernel(const float* __restrict__ inputs,
                                                  u16* __restrict__ knn,
                                                  int* __restrict__ indeg) {
    __shared__ float2 pts[Ss];
    __shared__ float  mg[32][56];
    __shared__ u64    lst[32][24];
    __shared__ int    cnt[32];
    __shared__ float  t2max[32];

    int b = blockIdx.x;
    const float* base = inputs + (size_t)b * Ss * 2;
    for (int t = threadIdx.x; t < Ss; t += 256) {
        float2 p;
        p.x = base[2 * t];
        p.y = base[2 * t + 1];
        pts[t] = p;
    }
    __syncthreads();

    int tid = threadIdx.x;
    int ln = tid >> 3;                  // local node 0..31
    int part = tid & 7;                 // candidate eighth 0..7
    int i = 2 + blockIdx.y * 32 + ln;
    bool valid = (i < Ss);
    int j0 = part * 125, j1 = j0 + 125;
    float xi = 0.f, yi = 0.f;
    if (valid) { xi = pts[i].x; yi = pts[i].y; }
    const float INF = __builtin_inff();

    if (valid) {
        float bd[7];
#pragma unroll
        for (int k = 0; k < 7; ++k) bd[k] = INF;
        for (int j = j0; j < j1; ++j) {
            float2 p = pts[j];
            float dx = __fsub_rn(xi, p.x);            // exact fp32 RN mirror
            float dy = __fsub_rn(yi, p.y);
            float d2 = __fadd_rn(__fmul_rn(dx, dx), __fmul_rn(dy, dy));
            d2 = (j == i) ? INF : d2;                 // exclude self
            ins7(bd, d2);
        }
#pragma unroll
        for (int k = 0; k < 7; ++k) mg[ln][part * 7 + k] = bd[k];
    }
    __syncthreads();

    if (part == 0 && valid) {
        float m[7];
#pragma unroll
        for (int k = 0; k < 7; ++k) m[k] = INF;
        for (int t = 0; t < 56; ++t) ins7(m, mg[ln][t]);
        float tau2 = m[6];
        float tau = __fsqrt_rn(tau2);
        float g = tau2;
        for (int it = 0; it < 8; ++it) {               // widen to sqrt-collision boundary
            float gn = __builtin_bit_cast(float, __builtin_bit_cast(u32, g) + 1u);
            if (__fsqrt_rn(gn) <= tau) g = gn; else break;
        }
        t2max[ln] = g;
        cnt[ln] = 0;
    }
    __syncthreads();

    if (valid) {
        float T = t2max[ln];
        for (int j = j0; j < j1; ++j) {
            float2 p = pts[j];
            float dx = __fsub_rn(xi, p.x);
            float dy = __fsub_rn(yi, p.y);
            float d2 = __fadd_rn(__fmul_rn(dx, dx), __fmul_rn(dy, dy));
            d2 = (j == i) ? INF : d2;
            if (d2 <= T) {
                float d = __fsqrt_rn(d2);
                u64 key = (((u64)__builtin_bit_cast(u32, d)) << 32) | (u32)j;
                int p2 = atomicAdd(&cnt[ln], 1);
                if (p2 < 24) lst[ln][p2] = key;
            }
        }
    }
    __syncthreads();

    if (part == 0 && valid) {
        int c = cnt[ln]; if (c > 24) c = 24;           // c >= 7 by construction
        u16* kp = knn + ((size_t)b * NSRC + (i - 2)) * 7;
#pragma unroll
        for (int k = 0; k < 7; ++k) {
            u64 best = ~0ULL; int bp = -1;
            for (int t = 0; t < c; ++t) {
                u64 v = lst[ln][t];
                if (v < best) { best = v; bp = t; }
            }
            int j = 0;
            if (bp >= 0) { lst[ln][bp] = ~0ULL; j = (int)(u32)best; }
            kp[k] = (u16)j;
            if (j >= 2) atomicAdd(&indeg[b * Ss + j], 1);
        }
    }
}

// ---------- 2) degree -> dinv ----------
__global__ void deg_dinv_kernel(const int* __restrict__ indeg, float* __restrict__ dinv) {
    int n = blockIdx.x * 256 + threadIdx.x;
    if (n >= NN) return;
    int i = n % Ss;
    float deg = (i == 0) ? 1.0f : (i == 1) ? (float)(Ss - 1) : (float)(indeg[n] + 2);
    dinv[n] = 1.0f / __fsqrt_rn(deg);
}

// ---------- 3) coalesced 3-phase scan: indeg -> CSR offsets ----------
__global__ __launch_bounds__(1024) void scan1_kernel(const int* __restrict__ indeg,
                                                     int* __restrict__ offs,
                                                     int* __restrict__ bsum) {
    __shared__ int sh[1024];
    int t = threadIdx.x;
    int idx = blockIdx.x * 1024 + t;
    int v = (idx < NN) ? indeg[idx] : 0;
    sh[t] = v;
    __syncthreads();
    for (int off = 1; off < 1024; off <<= 1) {
        int u = (t >= off) ? sh[t - off] : 0;
        __syncthreads();
        sh[t] += u;
        __syncthreads();
    }
    if (idx < NN) offs[idx] = sh[t] - v;            // exclusive prefix
    if (t == 1023) bsum[blockIdx.x] = sh[1023];
}

__global__ void scan2_kernel(int* __restrict__ bsum) {
    if (threadIdx.x == 0) {
        int run = 0;
        for (int k = 0; k < 63; ++k) { int v = bsum[k]; bsum[k] = run; run += v; }
        bsum[63] = run;
    }
}

__global__ __launch_bounds__(1024) void scan3_kernel(int* __restrict__ offs,
                                                     const int* __restrict__ bsum) {
    int idx = blockIdx.x * 1024 + threadIdx.x;
    if (idx < NN) offs[idx] += bsum[blockIdx.x];
    if (idx == 0) offs[NN] = bsum[63];
}

// ---------- 4) scatter reverse adjacency ----------
__global__ __launch_bounds__(256) void fill_rev_kernel(const u16* __restrict__ knn,
                                                       const int* __restrict__ offs,
                                                       int* __restrict__ cursor,
                                                       u16* __restrict__ rev) {
    if (threadIdx.x >= 250) return;
    int b = blockIdx.x;
    int i = 2 + blockIdx.y * 250 + threadIdx.x;
    if (i >= Ss) return;
    const u16* kp = knn + ((size_t)b * NSRC + (i - 2)) * 7;
#pragma unroll
    for (int k = 0; k < 7; ++k) {
        int d = kp[k];
        if (d >= 2) {
            int n = b * Ss + d;
            int p = atomicAdd(&cursor[n], 1);
            rev[offs[n] + p] = (u16)i;
        }
    }
}

// ---------- 5) embedding -> single bf16 ----------
__global__ __launch_bounds__(256) void embed_kernel(const float* __restrict__ inputs,
                                                    const float* __restrict__ scor,
                                                    const float* __restrict__ Wc,
                                                    const float* __restrict__ bc,
                                                    const float* __restrict__ Ws,
                                                    const float* __restrict__ bs,
                                                    u16* __restrict__ xbf) {
    int gid = blockIdx.x * 256 + threadIdx.x;
    if (gid >= NN * Dd) return;
    int n = gid >> 7, c = gid & 127;
    float i0 = inputs[2 * n], i1 = inputs[2 * n + 1], sc = scor[n];
    float t1 = i0 * Wc[c] + i1 * Wc[Dd + c] + bc[c];
    float t2 = sc * Ws[c] + bs[c];
    xbf[gid] = f2bf(t1 + t2);
}

// ---------- 6) weight transpose + split (weights stay hi+lo) ----------
__global__ void transp_split_kernel(const float* __restrict__ src,
                                    u16* __restrict__ dhi, u16* __restrict__ dlo,
                                    int R, int C) {
    int gid = blockIdx.x * 256 + threadIdx.x;
    if (gid >= R * C) return;
    int r = gid / C, c = gid - r * C;
    u16 h, l;
    split2(src[gid], h, l);
    dhi[c * R + r] = h;
    dlo[c * R + r] = l;
}

// ---------- 7) MFMA GEMM: Y(bf16) = A(bf16) @ (Whi+Wlo), 2-MFMA scheme ----------
__global__ __launch_bounds__(256) void gemm_kernel(const u16* __restrict__ A,
                                                   const u16* __restrict__ Whi,
                                                   const u16* __restrict__ Wlo,
                                                   u16* __restrict__ Y,
                                                   int K, int Ncols) {
    __shared__ __align__(16) u16 lA[128][64];
    __shared__ __align__(16) u16 lWh[128][64];
    __shared__ __align__(16) u16 lWl[128][64];

    int row0 = blockIdx.y * 128;
    int col0 = blockIdx.x * 128;
    int tid = threadIdx.x;
    int lane = tid & 63, wid = tid >> 6;
    int wm = (wid >> 1) * 64, wn = (wid & 1) * 64;
    int lanelo = lane & 15, quad = lane >> 4;

    f32x4 acc[4][4] = {};

    int scb = tid & 7;          // col-block (8 bf16 each) 0..7
    int sr  = tid >> 3;         // 0..31

    for (int k0 = 0; k0 < K; k0 += 64) {
#pragma unroll
        for (int rr = 0; rr < 4; ++rr) {
            int r = sr + rr * 32;
            uint4 va = *(const uint4*)(A + (size_t)(row0 + r) * K + k0 + scb * 8);
            *(uint4*)&lA[r][(scb ^ (r & 7)) * 8] = va;   // XOR swizzle
        }
#pragma unroll
        for (int rr = 0; rr < 4; ++rr) {
            int r = sr + rr * 32;
            size_t gofs = (size_t)(col0 + r) * K + k0 + scb * 8;
            uint4 vh = *(const uint4*)(Whi + gofs);
            uint4 vl = *(const uint4*)(Wlo + gofs);
            int cc = (scb ^ (r & 7)) * 8;
            *(uint4*)&lWh[r][cc] = vh;
            *(uint4*)&lWl[r][cc] = vl;
        }
        __syncthreads();

#pragma unroll
        for (int kk = 0; kk < 64; kk += 32) {
            short8 af[4], bh[4], bl[4];
            int cbb = (kk >> 3) + quad;
#pragma unroll
            for (int mt = 0; mt < 4; ++mt) {
                int r = wm + mt * 16 + lanelo;
                af[mt] = *(const short8*)&lA[r][((cbb ^ (r & 7))) * 8];
            }
#pragma unroll
            for (int nt = 0; nt < 4; ++nt) {
                int r = wn + nt * 16 + lanelo;
                int cc = (cbb ^ (r & 7)) * 8;
                bh[nt] = *(const short8*)&lWh[r][cc];
                bl[nt] = *(const short8*)&lWl[r][cc];
            }
#pragma unroll
            for (int mt = 0; mt < 4; ++mt)
#pragma unroll
                for (int nt = 0; nt < 4; ++nt) {
                    acc[mt][nt] = __builtin_amdgcn_mfma_f32_16x16x32_bf16(
                        af[mt], bh[nt], acc[mt][nt], 0, 0, 0);
                    acc[mt][nt] = __builtin_amdgcn_mfma_f32_16x16x32_bf16(
                        af[mt], bl[nt], acc[mt][nt], 0, 0, 0);
                }
        }
        __syncthreads();
    }

#pragma unroll
    for (int mt = 0; mt < 4; ++mt)
#pragma unroll
        for (int nt = 0; nt < 4; ++nt)
#pragma unroll
            for (int r = 0; r < 4; ++r) {
                int row = row0 + wm + mt * 16 + quad * 4 + r;
                int col = col0 + wn + nt * 16 + lanelo;
                Y[(size_t)row * Ncols + col] = f2bf(acc[mt][nt][r]);
            }
}

// ---------- 7b) depot-1 partial sums: dq[q][b][c] = sum_{j in quarter q} y[b,j,c]*dinv[b,j] ----------
// grid (64, 4, M/128), block 1024 = 32 ch-quads x 32 edge slots.
__global__ __launch_bounds__(1024) void dep1_kernel(const u16* __restrict__ y,
                                                    const float* __restrict__ dinv,
                                                    float* __restrict__ dq,
                                                    int M) {
    int b = blockIdx.x;
    int qq = blockIdx.y;                 // quarter 0..3
    int co = blockIdx.z * 128;
    int tid = threadIdx.x;
    int c4 = tid & 31;
    int es = tid >> 5;
    int j0 = 2 + qq * 250;
    int j1 = j0 + 250; if (j1 > Ss) j1 = Ss;
    const u16* yb = y + (size_t)b * Ss * M + co + c4 * 4;
    const float* dv = dinv + b * Ss;
    float a0 = 0.f, a1 = 0.f, a2 = 0.f, a3 = 0.f;
    for (int j = j0 + es; j < j1; j += 32) {
        float w = dv[j];
        float4 u = bf4(*(const ushort4*)(yb + (size_t)j * M));
        a0 += u.x * w; a1 += u.y * w; a2 += u.z * w; a3 += u.w * w;
    }
    __shared__ float4 red[1024];
    float4 mv; mv.x = a0; mv.y = a1; mv.z = a2; mv.w = a3;
    red[tid] = mv;
    __syncthreads();
#pragma unroll
    for (int s = 16; s > 0; s >>= 1) {
        if (es < s) {
            float4 o = red[tid + (s << 5)];
            float4 m = red[tid];
            m.x += o.x; m.y += o.y; m.z += o.z; m.w += o.w;
            red[tid] = m;
        }
        __syncthreads();
    }
    if (es == 0)
        *(float4*)(dq + ((size_t)qq * Bb + b) * M + co + c4 * 4) = red[c4];
}

// ---------- 8) aggregation M=512 + bias + relu -> single bf16 ----------
__global__ __launch_bounds__(128) void agg512_kernel(const u16* __restrict__ y,
                                                     const float* __restrict__ dinv,
                                                     const int* __restrict__ offs,
                                                     const int* __restrict__ indeg,
                                                     const u16* __restrict__ rev,
                                                     const float* __restrict__ bias,
                                                     const float* __restrict__ dep1,
                                                     u16* __restrict__ oX) {
    int bx = blockIdx.x;
    int x = bx & 7, q = bx >> 3;
    int bb = q / 1000;
    int i = q - bb * 1000;
    int b = x + (bb << 3);
    int n = b * Ss + i;
    int nb = n - i;
    int tid = threadIdx.x, c = tid * 4;

    __shared__ int   sidx[128];
    __shared__ float sw[128];
    int cnt = 0, o = 0;
    if (i >= 2) { cnt = indeg[n]; o = offs[n]; }
    int cl = cnt < 128 ? cnt : 128;
    if (tid < cl) {
        int s = rev[o + tid];
        sidx[tid] = s;
        sw[tid] = dinv[nb + s];
    }
    __syncthreads();

    float a0 = 0.f, a1 = 0.f, a2 = 0.f, a3 = 0.f;
    if (i >= 2) {
        float w = dinv[nb];  // == 1.0 (deg[0]=1)
        float4 v = bf4(*(const ushort4*)(y + (size_t)nb * 512 + c));
        a0 = v.x * w; a1 = v.y * w; a2 = v.z * w; a3 = v.w * w;
        int e = 0;
        for (; e + 4 <= cl; e += 4) {
            int s0 = sidx[e], s1 = sidx[e + 1], s2 = sidx[e + 2], s3 = sidx[e + 3];
            float w0 = sw[e], w1 = sw[e + 1], w2 = sw[e + 2], w3 = sw[e + 3];
            float4 u0 = bf4(*(const ushort4*)(y + (size_t)(nb + s0) * 512 + c));
            float4 u1 = bf4(*(const ushort4*)(y + (size_t)(nb + s1) * 512 + c));
            float4 u2 = bf4(*(const ushort4*)(y + (size_t)(nb + s2) * 512 + c));
            float4 u3 = bf4(*(const ushort4*)(y + (size_t)(nb + s3) * 512 + c));
            a0 += u0.x * w0 + u1.x * w1 + u2.x * w2 + u3.x * w3;
            a1 += u0.y * w0 + u1.y * w1 + u2.y * w2 + u3.y * w3;
            a2 += u0.z * w0 + u1.z * w1 + u2.z * w2 + u3.z * w3;
            a3 += u0.w * w0 + u1.w * w1 + u2.w * w2 + u3.w * w3;
        }
        for (; e < cl; ++e) {
            int s = sidx[e]; float ww = sw[e];
            float4 u = bf4(*(const ushort4*)(y + (size_t)(nb + s) * 512 + c));
            a0 += u.x * ww; a1 += u.y * ww; a2 += u.z * ww; a3 += u.w * ww;
        }
        for (int e2 = 128; e2 < cnt; ++e2) {   // safety fallback (never in practice)
            int s = rev[o + e2]; float ww = dinv[nb + s];
            float4 u = bf4(*(const ushort4*)(y + (size_t)(nb + s) * 512 + c));
            a0 += u.x * ww; a1 += u.y * ww; a2 += u.z * ww; a3 += u.w * ww;
        }
    } else if (i == 1) {
        const float* dp = dep1 + (size_t)b * 512 + c;
#pragma unroll
        for (int qq = 0; qq < 4; ++qq) {
            float4 v = *(const float4*)(dp + (size_t)qq * Bb * 512);
            a0 += v.x; a1 += v.y; a2 += v.z; a3 += v.w;
        }
    }
    float dn = dinv[n], sn = dn * dn;
    float4 vs = bf4(*(const ushort4*)(y + (size_t)n * 512 + c));
    float z0 = a0 * dn + vs.x * sn + bias[c];
    float z1 = a1 * dn + vs.y * sn + bias[c + 1];
    float z2 = a2 * dn + vs.z * sn + bias[c + 2];
    float z3 = a3 * dn + vs.w * sn + bias[c + 3];
    ushort4 hv;
    hv.x = f2bf(fmaxf(z0, 0.f));
    hv.y = f2bf(fmaxf(z1, 0.f));
    hv.z = f2bf(fmaxf(z2, 0.f));
    hv.w = f2bf(fmaxf(z3, 0.f));
    *(ushort4*)(oX + (size_t)n * 512 + c) = hv;
}

// ---------- 9) final aggregation M=128, no relu, fp32 out ----------
__global__ __launch_bounds__(128) void agg128f_kernel(const u16* __restrict__ y,
                                                      const float* __restrict__ dinv,
                                                      const int* __restrict__ offs,
                                                      const int* __restrict__ indeg,
                                                      const u16* __restrict__ rev,
                                                      const float* __restrict__ bias,
                                                      const float* __restrict__ dep1,
                                                      float* __restrict__ out) {
    int bx = blockIdx.x;
    int x = bx & 7, q = bx >> 3;
    int bb = q / 1000;
    int i = q - bb * 1000;
    int b = x + (bb << 3);
    int n = b * Ss + i;
    int nb = n - i;
    int tid = threadIdx.x, c = tid;

    __shared__ int   sidx[128];
    __shared__ float sw[128];
    int cnt = 0, o = 0;
    if (i >= 2) { cnt = indeg[n]; o = offs[n]; }
    int cl = cnt < 128 ? cnt : 128;
    if (tid < cl) {
        int s = rev[o + tid];
        sidx[tid] = s;
        sw[tid] = dinv[nb + s];
    }
    __syncthreads();

    float a = 0.f;
    if (i >= 2) {
        a = bf2f(y[(size_t)nb * 128 + c]) * dinv[nb];
        int e = 0;
        for (; e + 4 <= cl; e += 4) {
            int s0 = sidx[e], s1 = sidx[e + 1], s2 = sidx[e + 2], s3 = sidx[e + 3];
            float w0 = sw[e], w1 = sw[e + 1], w2 = sw[e + 2], w3 = sw[e + 3];
            float u0 = bf2f(y[(size_t)(nb + s0) * 128 + c]);
            float u1 = bf2f(y[(size_t)(nb + s1) * 128 + c]);
            float u2 = bf2f(y[(size_t)(nb + s2) * 128 + c]);
            float u3 = bf2f(y[(size_t)(nb + s3) * 128 + c]);
            a += u0 * w0 + u1 * w1 + u2 * w2 + u3 * w3;
        }
        for (; e < cl; ++e) a += bf2f(y[(size_t)(nb + sidx[e]) * 128 + c]) * sw[e];
        for (int e2 = 128; e2 < cnt; ++e2) {
            int s = rev[o + e2];
            a += bf2f(y[(size_t)(nb + s) * 128 + c]) * dinv[nb + s];
        }
    } else if (i == 1) {
#pragma unroll
        for (int qq = 0; qq < 4; ++qq)
            a += dep1[((size_t)qq * Bb + b) * 128 + c];
    }
    float dn = dinv[n];
    out[(size_t)n * 128 + c] = a * dn + bf2f(y[(size_t)n * 128 + c]) * (dn * dn) + bias[c];
}

// ---------- workspace layout (bytes); total ~201.6 MB ----------
constexpr size_t O_INDEG  = 0;                       // 256000
constexpr size_t O_CURSOR = 256000;                  // 256000
constexpr size_t O_OFFS   = 512000;                  // 256016
constexpr size_t O_DINV   = 768256;                  // 256000
constexpr size_t O_KNN    = 1024256;                 // 893824
constexpr size_t O_REV    = 1918080;                 // 893824
constexpr size_t O_WT0H   = 2811904;                 // 131072
constexpr size_t O_WT0L   = 2942976;
constexpr size_t O_WT1H   = 3074048;                 // 524288
constexpr size_t O_WT1L   = 3598336;
constexpr size_t O_WT2H   = 4122624;                 // 131072
constexpr size_t O_WT2L   = 4253696;
constexpr size_t O_X      = 4384768;                 // 64000*512*2 = 65536000 (bf16 acts)
constexpr size_t O_Y      = 69920768;                // 64000*512*2 = 65536000 (bf16 y)
constexpr size_t O_DEP1A  = 135456768;               // 4*64*512*4 = 524288
constexpr size_t O_DEP1B  = 135981056;               // 4*64*128*4 = 131072
constexpr size_t O_BSUM   = 136112128;               // 256

extern "C" void kernel_launch(void* const* d_in, const int* in_sizes, int n_in,
                              void* d_out, int out_size, void* d_ws, size_t ws_size,
                              hipStream_t stream) {
    const float* inputs = (const float*)d_in[0];
    const float* scor   = (const float*)d_in[1];
    const float* Wc     = (const float*)d_in[2];
    const float* bc     = (const float*)d_in[3];
    const float* Ws     = (const float*)d_in[4];
    const float* bs     = (const float*)d_in[5];
    const float* W0     = (const float*)d_in[6];
    const float* b0     = (const float*)d_in[7];
    const float* W1     = (const float*)d_in[8];
    const float* b1     = (const float*)d_in[9];
    const float* W2     = (const float*)d_in[10];
    const float* b2     = (const float*)d_in[11];

    char* w = (char*)d_ws;
    int*   indeg  = (int*)(w + O_INDEG);
    int*   cursor = (int*)(w + O_CURSOR);
    int*   offs   = (int*)(w + O_OFFS);
    float* dinv   = (float*)(w + O_DINV);
    u16*   knn    = (u16*)(w + O_KNN);
    u16*   rev    = (u16*)(w + O_REV);
    u16*   wt0h   = (u16*)(w + O_WT0H);
    u16*   wt0l   = (u16*)(w + O_WT0L);
    u16*   wt1h   = (u16*)(w + O_WT1H);
    u16*   wt1l   = (u16*)(w + O_WT1L);
    u16*   wt2h   = (u16*)(w + O_WT2H);
    u16*   wt2l   = (u16*)(w + O_WT2L);
    u16*   xbf    = (u16*)(w + O_X);
    u16*   ybf    = (u16*)(w + O_Y);
    float* dep1a  = (float*)(w + O_DEP1A);
    float* dep1b  = (float*)(w + O_DEP1B);
    int*   bsum   = (int*)(w + O_BSUM);

    hipMemsetAsync(w + O_INDEG, 0, 512000, stream);  // indeg + cursor

    knn_kernel<<<dim3(Bb, 32), 256, 0, stream>>>(inputs, knn, indeg);
    deg_dinv_kernel<<<250, 256, 0, stream>>>(indeg, dinv);
    scan1_kernel<<<63, 1024, 0, stream>>>(indeg, offs, bsum);
    scan2_kernel<<<1, 64, 0, stream>>>(bsum);
    scan3_kernel<<<63, 1024, 0, stream>>>(offs, bsum);
    fill_rev_kernel<<<dim3(Bb, 4), 256, 0, stream>>>(knn, offs, cursor, rev);

    embed_kernel<<<NN * Dd / 256, 256, 0, stream>>>(inputs, scor, Wc, bc, Ws, bs, xbf);

    transp_split_kernel<<<(Dd * Hh + 255) / 256, 256, 0, stream>>>(W0, wt0h, wt0l, Dd, Hh);
    transp_split_kernel<<<(Hh * Hh + 255) / 256, 256, 0, stream>>>(W1, wt1h, wt1l, Hh, Hh);
    transp_split_kernel<<<(Hh * Dd + 255) / 256, 256, 0, stream>>>(W2, wt2h, wt2l, Hh, Dd);

    // layer 0: [N,128] @ [128,512]
    gemm_kernel<<<dim3(Hh / 128, NN / 128), 256, 0, stream>>>(xbf, wt0h, wt0l, ybf, Dd, Hh);
    dep1_kernel<<<dim3(Bb, 4, 4), 1024, 0, stream>>>(ybf, dinv, dep1a, Hh);
    agg512_kernel<<<NN, 128, 0, stream>>>(ybf, dinv, offs, indeg, rev, b0, dep1a, xbf);
    // layer 1: [N,512] @ [512,512]
    gemm_kernel<<<dim3(Hh / 128, NN / 128), 256, 0, stream>>>(xbf, wt1h, wt1l, ybf, Hh, Hh);
    dep1_kernel<<<dim3(Bb, 4, 4), 1024, 0, stream>>>(ybf, dinv, dep1a, Hh);
    agg512_kernel<<<NN, 128, 0, stream>>>(ybf, dinv, offs, indeg, rev, b1, dep1a, xbf);
    // layer 2: [N,512] @ [512,128]
    gemm_kernel<<<dim3(Dd / 128, NN / 128), 256, 0, stream>>>(xbf, wt2h, wt2l, ybf, Hh, Dd);
    dep1_kernel<<<dim3(Bb, 4, 1), 1024, 0, stream>>>(ybf, dinv, dep1b, Dd);
    agg128f_kernel<<<NN, 128, 0, stream>>>(ybf, dinv, offs, indeg, rev, b2, dep1b, (float*)d_out);
}

// Round 10
// 459.900 us; speedup vs baseline: 3.0508x; 1.0603x over previous
//
#include <hip/hip_runtime.h>

typedef unsigned short u16;
typedef unsigned int u32;
typedef unsigned long long u64;
using short8 = __attribute__((ext_vector_type(8))) short;
using f32x4  = __attribute__((ext_vector_type(4))) float;

constexpr int Bb = 64, Ss = 1000, Dd = 128, Hh = 512;
constexpr int NN = Bb * Ss;           // 64000 nodes
constexpr int NSRC = Ss - 2;          // 998 kNN source nodes per batch

// ---------- helpers ----------
__device__ __forceinline__ float bf2f(u16 h) {
    u32 u = ((u32)h) << 16;
    return __builtin_bit_cast(float, u);
}
__device__ __forceinline__ u16 f2bf(float v) {  // RNE, finite inputs only
    u32 u = __builtin_bit_cast(u32, v);
    u32 r = (u + 0x7FFFu + ((u >> 16) & 1u)) >> 16;
    return (u16)r;
}
__device__ __forceinline__ float4 bf4(ushort4 v) {
    float4 r;
    r.x = bf2f(v.x); r.y = bf2f(v.y); r.z = bf2f(v.z); r.w = bf2f(v.w);
    return r;
}

// branchless insert of v into ascending bd[0..6] (drops the max).
__device__ __forceinline__ void ins7(float (&bd)[7], float v) {
#pragma unroll
    for (int k = 6; k >= 1; --k)
        bd[k] = __builtin_amdgcn_fmed3f(v, bd[k - 1], bd[k]);
    bd[0] = fminf(v, bd[0]);
}

// ---------- 1) kNN: two-phase, med3 d^2 network + exact (d,j) re-rank ----------
__global__ __launch_bounds__(256) void knn_kernel(const float* __restrict__ inputs,
                                                  u16* __restrict__ knn,
                                                  int* __restrict__ indeg) {
    __shared__ float2 pts[Ss];
    __shared__ float  mg[32][56];
    __shared__ u64    lst[32][24];
    __shared__ int    cnt[32];
    __shared__ float  t2max[32];

    int b = blockIdx.x;
    const float* base = inputs + (size_t)b * Ss * 2;
    for (int t = threadIdx.x; t < Ss; t += 256) {
        float2 p;
        p.x = base[2 * t];
        p.y = base[2 * t + 1];
        pts[t] = p;
    }
    __syncthreads();

    int tid = threadIdx.x;
    int ln = tid >> 3;                  // local node 0..31
    int part = tid & 7;                 // candidate eighth 0..7
    int i = 2 + blockIdx.y * 32 + ln;
    bool valid = (i < Ss);
    int j0 = part * 125, j1 = j0 + 125;
    float xi = 0.f, yi = 0.f;
    if (valid) { xi = pts[i].x; yi = pts[i].y; }
    const float INF = __builtin_inff();

    if (valid) {
        float bd[7];
#pragma unroll
        for (int k = 0; k < 7; ++k) bd[k] = INF;
        for (int j = j0; j < j1; ++j) {
            float2 p = pts[j];
            float dx = __fsub_rn(xi, p.x);            // exact fp32 RN mirror
            float dy = __fsub_rn(yi, p.y);
            float d2 = __fadd_rn(__fmul_rn(dx, dx), __fmul_rn(dy, dy));
            d2 = (j == i) ? INF : d2;                 // exclude self
            ins7(bd, d2);
        }
#pragma unroll
        for (int k = 0; k < 7; ++k) mg[ln][part * 7 + k] = bd[k];
    }
    __syncthreads();

    if (part == 0 && valid) {
        float m[7];
#pragma unroll
        for (int k = 0; k < 7; ++k) m[k] = INF;
        for (int t = 0; t < 56; ++t) ins7(m, mg[ln][t]);
        float tau2 = m[6];
        float tau = __fsqrt_rn(tau2);
        float g = tau2;
        for (int it = 0; it < 8; ++it) {               // widen to sqrt-collision boundary
            float gn = __builtin_bit_cast(float, __builtin_bit_cast(u32, g) + 1u);
            if (__fsqrt_rn(gn) <= tau) g = gn; else break;
        }
        t2max[ln] = g;
        cnt[ln] = 0;
    }
    __syncthreads();

    if (valid) {
        float T = t2max[ln];
        for (int j = j0; j < j1; ++j) {
            float2 p = pts[j];
            float dx = __fsub_rn(xi, p.x);
            float dy = __fsub_rn(yi, p.y);
            float d2 = __fadd_rn(__fmul_rn(dx, dx), __fmul_rn(dy, dy));
            d2 = (j == i) ? INF : d2;
            if (d2 <= T) {
                float d = __fsqrt_rn(d2);
                u64 key = (((u64)__builtin_bit_cast(u32, d)) << 32) | (u32)j;
                int p2 = atomicAdd(&cnt[ln], 1);
                if (p2 < 24) lst[ln][p2] = key;
            }
        }
    }
    __syncthreads();

    if (part == 0 && valid) {
        int c = cnt[ln]; if (c > 24) c = 24;           // c >= 7 by construction
        u16* kp = knn + ((size_t)b * NSRC + (i - 2)) * 7;
#pragma unroll
        for (int k = 0; k < 7; ++k) {
            u64 best = ~0ULL; int bp = -1;
            for (int t = 0; t < c; ++t) {
                u64 v = lst[ln][t];
                if (v < best) { best = v; bp = t; }
            }
            int j = 0;
            if (bp >= 0) { lst[ln][bp] = ~0ULL; j = (int)(u32)best; }
            kp[k] = (u16)j;
            if (j >= 2) atomicAdd(&indeg[b * Ss + j], 1);
        }
    }
}

// ---------- 2) degree -> dinv ----------
__global__ void deg_dinv_kernel(const int* __restrict__ indeg, float* __restrict__ dinv) {
    int n = blockIdx.x * 256 + threadIdx.x;
    if (n >= NN) return;
    int i = n % Ss;
    float deg = (i == 0) ? 1.0f : (i == 1) ? (float)(Ss - 1) : (float)(indeg[n] + 2);
    dinv[n] = 1.0f / __fsqrt_rn(deg);
}

// ---------- 3) coalesced 3-phase scan: indeg -> CSR offsets ----------
__global__ __launch_bounds__(1024) void scan1_kernel(const int* __restrict__ indeg,
                                                     int* __restrict__ offs,
                                                     int* __restrict__ bsum) {
    __shared__ int sh[1024];
    int t = threadIdx.x;
    int idx = blockIdx.x * 1024 + t;
    int v = (idx < NN) ? indeg[idx] : 0;
    sh[t] = v;
    __syncthreads();
    for (int off = 1; off < 1024; off <<= 1) {
        int u = (t >= off) ? sh[t - off] : 0;
        __syncthreads();
        sh[t] += u;
        __syncthreads();
    }
    if (idx < NN) offs[idx] = sh[t] - v;            // exclusive prefix
    if (t == 1023) bsum[blockIdx.x] = sh[1023];
}

__global__ void scan2_kernel(int* __restrict__ bsum) {
    if (threadIdx.x == 0) {
        int run = 0;
        for (int k = 0; k < 63; ++k) { int v = bsum[k]; bsum[k] = run; run += v; }
        bsum[63] = run;
    }
}

__global__ __launch_bounds__(1024) void scan3_kernel(int* __restrict__ offs,
                                                     const int* __restrict__ bsum) {
    int idx = blockIdx.x * 1024 + threadIdx.x;
    if (idx < NN) offs[idx] += bsum[blockIdx.x];
    if (idx == 0) offs[NN] = bsum[63];
}

// ---------- 4) scatter reverse adjacency ----------
__global__ __launch_bounds__(256) void fill_rev_kernel(const u16* __restrict__ knn,
                                                       const int* __restrict__ offs,
                                                       int* __restrict__ cursor,
                                                       u16* __restrict__ rev) {
    if (threadIdx.x >= 250) return;
    int b = blockIdx.x;
    int i = 2 + blockIdx.y * 250 + threadIdx.x;
    if (i >= Ss) return;
    const u16* kp = knn + ((size_t)b * NSRC + (i - 2)) * 7;
#pragma unroll
    for (int k = 0; k < 7; ++k) {
        int d = kp[k];
        if (d >= 2) {
            int n = b * Ss + d;
            int p = atomicAdd(&cursor[n], 1);
            rev[offs[n] + p] = (u16)i;
        }
    }
}

// ---------- 5) embedding -> single bf16 ----------
__global__ __launch_bounds__(256) void embed_kernel(const float* __restrict__ inputs,
                                                    const float* __restrict__ scor,
                                                    const float* __restrict__ Wc,
                                                    const float* __restrict__ bc,
                                                    const float* __restrict__ Ws,
                                                    const float* __restrict__ bs,
                                                    u16* __restrict__ xbf) {
    int gid = blockIdx.x * 256 + threadIdx.x;
    if (gid >= NN * Dd) return;
    int n = gid >> 7, c = gid & 127;
    float i0 = inputs[2 * n], i1 = inputs[2 * n + 1], sc = scor[n];
    float t1 = i0 * Wc[c] + i1 * Wc[Dd + c] + bc[c];
    float t2 = sc * Ws[c] + bs[c];
    xbf[gid] = f2bf(t1 + t2);
}

// ---------- 6) weight transpose -> single bf16: Wt[n][k] = bf16(W[k][n]) ----------
__global__ void transp_kernel(const float* __restrict__ src,
                              u16* __restrict__ dst, int R, int C) {
    int gid = blockIdx.x * 256 + threadIdx.x;
    if (gid >= R * C) return;
    int r = gid / C, c = gid - r * C;
    dst[c * R + r] = f2bf(src[gid]);
}

// ---------- 7) MFMA GEMM: Y(bf16) = A(bf16) @ W(bf16)^T, 1-MFMA ----------
// LDS 32 KB. grid: (Ncols/128, M/128).
__global__ __launch_bounds__(256) void gemm_kernel(const u16* __restrict__ A,
                                                   const u16* __restrict__ W,
                                                   u16* __restrict__ Y,
                                                   int K, int Ncols) {
    __shared__ __align__(16) u16 lA[128][64];
    __shared__ __align__(16) u16 lW[128][64];

    int row0 = blockIdx.y * 128;
    int col0 = blockIdx.x * 128;
    int tid = threadIdx.x;
    int lane = tid & 63, wid = tid >> 6;
    int wm = (wid >> 1) * 64, wn = (wid & 1) * 64;
    int lanelo = lane & 15, quad = lane >> 4;

    f32x4 acc[4][4] = {};

    int scb = tid & 7;          // col-block (8 bf16 each) 0..7
    int sr  = tid >> 3;         // 0..31

    for (int k0 = 0; k0 < K; k0 += 64) {
#pragma unroll
        for (int rr = 0; rr < 4; ++rr) {
            int r = sr + rr * 32;
            uint4 va = *(const uint4*)(A + (size_t)(row0 + r) * K + k0 + scb * 8);
            *(uint4*)&lA[r][(scb ^ (r & 7)) * 8] = va;   // XOR swizzle
        }
#pragma unroll
        for (int rr = 0; rr < 4; ++rr) {
            int r = sr + rr * 32;
            uint4 vw = *(const uint4*)(W + (size_t)(col0 + r) * K + k0 + scb * 8);
            *(uint4*)&lW[r][(scb ^ (r & 7)) * 8] = vw;
        }
        __syncthreads();

#pragma unroll
        for (int kk = 0; kk < 64; kk += 32) {
            short8 af[4], bw[4];
            int cbb = (kk >> 3) + quad;
#pragma unroll
            for (int mt = 0; mt < 4; ++mt) {
                int r = wm + mt * 16 + lanelo;
                af[mt] = *(const short8*)&lA[r][((cbb ^ (r & 7))) * 8];
            }
#pragma unroll
            for (int nt = 0; nt < 4; ++nt) {
                int r = wn + nt * 16 + lanelo;
                bw[nt] = *(const short8*)&lW[r][((cbb ^ (r & 7))) * 8];
            }
#pragma unroll
            for (int mt = 0; mt < 4; ++mt)
#pragma unroll
                for (int nt = 0; nt < 4; ++nt)
                    acc[mt][nt] = __builtin_amdgcn_mfma_f32_16x16x32_bf16(
                        af[mt], bw[nt], acc[mt][nt], 0, 0, 0);
        }
        __syncthreads();
    }

#pragma unroll
    for (int mt = 0; mt < 4; ++mt)
#pragma unroll
        for (int nt = 0; nt < 4; ++nt)
#pragma unroll
            for (int r = 0; r < 4; ++r) {
                int row = row0 + wm + mt * 16 + quad * 4 + r;
                int col = col0 + wn + nt * 16 + lanelo;
                Y[(size_t)row * Ncols + col] = f2bf(acc[mt][nt][r]);
            }
}

// ---------- 7b) depot-1 partial sums: dq[q][b][c] = sum_{j in quarter q} y[b,j,c]*dinv[b,j] ----------
__global__ __launch_bounds__(1024) void dep1_kernel(const u16* __restrict__ y,
                                                    const float* __restrict__ dinv,
                                                    float* __restrict__ dq,
                                                    int M) {
    int b = blockIdx.x;
    int qq = blockIdx.y;                 // quarter 0..3
    int co = blockIdx.z * 128;
    int tid = threadIdx.x;
    int c4 = tid & 31;
    int es = tid >> 5;
    int j0 = 2 + qq * 250;
    int j1 = j0 + 250; if (j1 > Ss) j1 = Ss;
    const u16* yb = y + (size_t)b * Ss * M + co + c4 * 4;
    const float* dv = dinv + b * Ss;
    float a0 = 0.f, a1 = 0.f, a2 = 0.f, a3 = 0.f;
    for (int j = j0 + es; j < j1; j += 32) {
        float w = dv[j];
        float4 u = bf4(*(const ushort4*)(yb + (size_t)j * M));
        a0 += u.x * w; a1 += u.y * w; a2 += u.z * w; a3 += u.w * w;
    }
    __shared__ float4 red[1024];
    float4 mv; mv.x = a0; mv.y = a1; mv.z = a2; mv.w = a3;
    red[tid] = mv;
    __syncthreads();
#pragma unroll
    for (int s = 16; s > 0; s >>= 1) {
        if (es < s) {
            float4 o = red[tid + (s << 5)];
            float4 m = red[tid];
            m.x += o.x; m.y += o.y; m.z += o.z; m.w += o.w;
            red[tid] = m;
        }
        __syncthreads();
    }
    if (es == 0)
        *(float4*)(dq + ((size_t)qq * Bb + b) * M + co + c4 * 4) = red[c4];
}

// ---------- 8) aggregation M=512 + bias + relu -> single bf16 ----------
__global__ __launch_bounds__(128) void agg512_kernel(const u16* __restrict__ y,
                                                     const float* __restrict__ dinv,
                                                     const int* __restrict__ offs,
                                                     const int* __restrict__ indeg,
                                                     const u16* __restrict__ rev,
                                                     const float* __restrict__ bias,
                                                     const float* __restrict__ dep1,
                                                     u16* __restrict__ oX) {
    int bx = blockIdx.x;
    int x = bx & 7, q = bx >> 3;
    int bb = q / 1000;
    int i = q - bb * 1000;
    int b = x + (bb << 3);
    int n = b * Ss + i;
    int nb = n - i;
    int tid = threadIdx.x, c = tid * 4;

    __shared__ int   sidx[128];
    __shared__ float sw[128];
    int cnt = 0, o = 0;
    if (i >= 2) { cnt = indeg[n]; o = offs[n]; }
    int cl = cnt < 128 ? cnt : 128;
    if (tid < cl) {
        int s = rev[o + tid];
        sidx[tid] = s;
        sw[tid] = dinv[nb + s];
    }
    __syncthreads();

    float a0 = 0.f, a1 = 0.f, a2 = 0.f, a3 = 0.f;
    if (i >= 2) {
        float w = dinv[nb];  // == 1.0 (deg[0]=1)
        float4 v = bf4(*(const ushort4*)(y + (size_t)nb * 512 + c));
        a0 = v.x * w; a1 = v.y * w; a2 = v.z * w; a3 = v.w * w;
        int e = 0;
        for (; e + 4 <= cl; e += 4) {
            int s0 = sidx[e], s1 = sidx[e + 1], s2 = sidx[e + 2], s3 = sidx[e + 3];
            float w0 = sw[e], w1 = sw[e + 1], w2 = sw[e + 2], w3 = sw[e + 3];
            float4 u0 = bf4(*(const ushort4*)(y + (size_t)(nb + s0) * 512 + c));
            float4 u1 = bf4(*(const ushort4*)(y + (size_t)(nb + s1) * 512 + c));
            float4 u2 = bf4(*(const ushort4*)(y + (size_t)(nb + s2) * 512 + c));
            float4 u3 = bf4(*(const ushort4*)(y + (size_t)(nb + s3) * 512 + c));
            a0 += u0.x * w0 + u1.x * w1 + u2.x * w2 + u3.x * w3;
            a1 += u0.y * w0 + u1.y * w1 + u2.y * w2 + u3.y * w3;
            a2 += u0.z * w0 + u1.z * w1 + u2.z * w2 + u3.z * w3;
            a3 += u0.w * w0 + u1.w * w1 + u2.w * w2 + u3.w * w3;
        }
        for (; e < cl; ++e) {
            int s = sidx[e]; float ww = sw[e];
            float4 u = bf4(*(const ushort4*)(y + (size_t)(nb + s) * 512 + c));
            a0 += u.x * ww; a1 += u.y * ww; a2 += u.z * ww; a3 += u.w * ww;
        }
        for (int e2 = 128; e2 < cnt; ++e2) {   // safety fallback (never in practice)
            int s = rev[o + e2]; float ww = dinv[nb + s];
            float4 u = bf4(*(const ushort4*)(y + (size_t)(nb + s) * 512 + c));
            a0 += u.x * ww; a1 += u.y * ww; a2 += u.z * ww; a3 += u.w * ww;
        }
    } else if (i == 1) {
        const float* dp = dep1 + (size_t)b * 512 + c;
#pragma unroll
        for (int qq = 0; qq < 4; ++qq) {
            float4 v = *(const float4*)(dp + (size_t)qq * Bb * 512);
            a0 += v.x; a1 += v.y; a2 += v.z; a3 += v.w;
        }
    }
    float dn = dinv[n], sn = dn * dn;
    float4 vs = bf4(*(const ushort4*)(y + (size_t)n * 512 + c));
    float z0 = a0 * dn + vs.x * sn + bias[c];
    float z1 = a1 * dn + vs.y * sn + bias[c + 1];
    float z2 = a2 * dn + vs.z * sn + bias[c + 2];
    float z3 = a3 * dn + vs.w * sn + bias[c + 3];
    ushort4 hv;
    hv.x = f2bf(fmaxf(z0, 0.f));
    hv.y = f2bf(fmaxf(z1, 0.f));
    hv.z = f2bf(fmaxf(z2, 0.f));
    hv.w = f2bf(fmaxf(z3, 0.f));
    *(ushort4*)(oX + (size_t)n * 512 + c) = hv;
}

// ---------- 9) final aggregation M=128, no relu, fp32 out ----------
__global__ __launch_bounds__(128) void agg128f_kernel(const u16* __restrict__ y,
                                                      const float* __restrict__ dinv,
                                                      const int* __restrict__ offs,
                                                      const int* __restrict__ indeg,
                                                      const u16* __restrict__ rev,
                                                      const float* __restrict__ bias,
                                                      const float* __restrict__ dep1,
                                                      float* __restrict__ out) {
    int bx = blockIdx.x;
    int x = bx & 7, q = bx >> 3;
    int bb = q / 1000;
    int i = q - bb * 1000;
    int b = x + (bb << 3);
    int n = b * Ss + i;
    int nb = n - i;
    int tid = threadIdx.x, c = tid;

    __shared__ int   sidx[128];
    __shared__ float sw[128];
    int cnt = 0, o = 0;
    if (i >= 2) { cnt = indeg[n]; o = offs[n]; }
    int cl = cnt < 128 ? cnt : 128;
    if (tid < cl) {
        int s = rev[o + tid];
        sidx[tid] = s;
        sw[tid] = dinv[nb + s];
    }
    __syncthreads();

    float a = 0.f;
    if (i >= 2) {
        a = bf2f(y[(size_t)nb * 128 + c]) * dinv[nb];
        int e = 0;
        for (; e + 4 <= cl; e += 4) {
            int s0 = sidx[e], s1 = sidx[e + 1], s2 = sidx[e + 2], s3 = sidx[e + 3];
            float w0 = sw[e], w1 = sw[e + 1], w2 = sw[e + 2], w3 = sw[e + 3];
            float u0 = bf2f(y[(size_t)(nb + s0) * 128 + c]);
            float u1 = bf2f(y[(size_t)(nb + s1) * 128 + c]);
            float u2 = bf2f(y[(size_t)(nb + s2) * 128 + c]);
            float u3 = bf2f(y[(size_t)(nb + s3) * 128 + c]);
            a += u0 * w0 + u1 * w1 + u2 * w2 + u3 * w3;
        }
        for (; e < cl; ++e) a += bf2f(y[(size_t)(nb + sidx[e]) * 128 + c]) * sw[e];
        for (int e2 = 128; e2 < cnt; ++e2) {
            int s = rev[o + e2];
            a += bf2f(y[(size_t)(nb + s) * 128 + c]) * dinv[nb + s];
        }
    } else if (i == 1) {
#pragma unroll
        for (int qq = 0; qq < 4; ++qq)
            a += dep1[((size_t)qq * Bb + b) * 128 + c];
    }
    float dn = dinv[n];
    out[(size_t)n * 128 + c] = a * dn + bf2f(y[(size_t)n * 128 + c]) * (dn * dn) + bias[c];
}

// ---------- workspace layout (bytes); total ~134.9 MB ----------
constexpr size_t O_INDEG  = 0;                       // 256000
constexpr size_t O_CURSOR = 256000;                  // 256000
constexpr size_t O_OFFS   = 512000;                  // 256016
constexpr size_t O_DINV   = 768256;                  // 256000
constexpr size_t O_KNN    = 1024256;                 // 893824
constexpr size_t O_REV    = 1918080;                 // 893824
constexpr size_t O_WT0    = 2811904;                 // 512*128*2 = 131072
constexpr size_t O_WT1    = 2942976;                 // 512*512*2 = 524288
constexpr size_t O_WT2    = 3467264;                 // 128*512*2 = 131072
constexpr size_t O_X      = 3598336;                 // 64000*512*2 = 65536000 (bf16 acts)
constexpr size_t O_Y      = 69134336;                // 65536000 (bf16 y)
constexpr size_t O_DEP1A  = 134670336;               // 4*64*512*4 = 524288
constexpr size_t O_DEP1B  = 135194624;               // 4*64*128*4 = 131072
constexpr size_t O_BSUM   = 135325696;               // 256

extern "C" void kernel_launch(void* const* d_in, const int* in_sizes, int n_in,
                              void* d_out, int out_size, void* d_ws, size_t ws_size,
                              hipStream_t stream) {
    const float* inputs = (const float*)d_in[0];
    const float* scor   = (const float*)d_in[1];
    const float* Wc     = (const float*)d_in[2];
    const float* bc     = (const float*)d_in[3];
    const float* Ws     = (const float*)d_in[4];
    const float* bs     = (const float*)d_in[5];
    const float* W0     = (const float*)d_in[6];
    const float* b0     = (const float*)d_in[7];
    const float* W1     = (const float*)d_in[8];
    const float* b1     = (const float*)d_in[9];
    const float* W2     = (const float*)d_in[10];
    const float* b2     = (const float*)d_in[11];

    char* w = (char*)d_ws;
    int*   indeg  = (int*)(w + O_INDEG);
    int*   cursor = (int*)(w + O_CURSOR);
    int*   offs   = (int*)(w + O_OFFS);
    float* dinv   = (float*)(w + O_DINV);
    u16*   knn    = (u16*)(w + O_KNN);
    u16*   rev    = (u16*)(w + O_REV);
    u16*   wt0    = (u16*)(w + O_WT0);
    u16*   wt1    = (u16*)(w + O_WT1);
    u16*   wt2    = (u16*)(w + O_WT2);
    u16*   xbf    = (u16*)(w + O_X);
    u16*   ybf    = (u16*)(w + O_Y);
    float* dep1a  = (float*)(w + O_DEP1A);
    float* dep1b  = (float*)(w + O_DEP1B);
    int*   bsum   = (int*)(w + O_BSUM);

    hipMemsetAsync(w + O_INDEG, 0, 512000, stream);  // indeg + cursor

    knn_kernel<<<dim3(Bb, 32), 256, 0, stream>>>(inputs, knn, indeg);
    deg_dinv_kernel<<<250, 256, 0, stream>>>(indeg, dinv);
    scan1_kernel<<<63, 1024, 0, stream>>>(indeg, offs, bsum);
    scan2_kernel<<<1, 64, 0, stream>>>(bsum);
    scan3_kernel<<<63, 1024, 0, stream>>>(offs, bsum);
    fill_rev_kernel<<<dim3(Bb, 4), 256, 0, stream>>>(knn, offs, cursor, rev);

    embed_kernel<<<NN * Dd / 256, 256, 0, stream>>>(inputs, scor, Wc, bc, Ws, bs, xbf);

    transp_kernel<<<(Dd * Hh + 255) / 256, 256, 0, stream>>>(W0, wt0, Dd, Hh);
    transp_kernel<<<(Hh * Hh + 255) / 256, 256, 0, stream>>>(W1, wt1, Hh, Hh);
    transp_kernel<<<(Hh * Dd + 255) / 256, 256, 0, stream>>>(W2, wt2, Hh, Dd);

    // layer 0: [N,128] @ [128,512]
    gemm_kernel<<<dim3(Hh / 128, NN / 128), 256, 0, stream>>>(xbf, wt0, ybf, Dd, Hh);
    dep1_kernel<<<dim3(Bb, 4, 4), 1024, 0, stream>>>(ybf, dinv, dep1a, Hh);
    agg512_kernel<<<NN, 128, 0, stream>>>(ybf, dinv, offs, indeg, rev, b0, dep1a, xbf);
    // layer 1: [N,512] @ [512,512]
    gemm_kernel<<<dim3(Hh / 128, NN / 128), 256, 0, stream>>>(xbf, wt1, ybf, Hh, Hh);
    dep1_kernel<<<dim3(Bb, 4, 4), 1024, 0, stream>>>(ybf, dinv, dep1a, Hh);
    agg512_kernel<<<NN, 128, 0, stream>>>(ybf, dinv, offs, indeg, rev, b1, dep1a, xbf);
    // layer 2: [N,512] @ [512,128]
    gemm_kernel<<<dim3(Dd / 128, NN / 128), 256, 0, stream>>>(xbf, wt2, ybf, Hh, Dd);
    dep1_kernel<<<dim3(Bb, 4, 1), 1024, 0, stream>>>(ybf, dinv, dep1b, Dd);
    agg128f_kernel<<<NN, 128, 0, stream>>>(ybf, dinv, offs, indeg, rev, b2, dep1b, (float*)d_out);
}